// Round 2
// baseline (1950.969 us; speedup 1.0000x reference)
//
#include <hip/hip_runtime.h>

#define EPSF 1e-8f
constexpr int ED = 4;   // nodes per wave in node kernel

typedef __attribute__((ext_vector_type(8))) short short8;
typedef __attribute__((ext_vector_type(4))) float float4v;

// ---- fp32 -> bf16 hi/lo split (RNE) ---------------------------------------
__device__ __forceinline__ unsigned bfhi_bits(float x) {
    unsigned u = __float_as_uint(x);
    return (u + 0x7fffu + ((u >> 16) & 1u)) >> 16;
}
__device__ __forceinline__ float bits2f(unsigned b) { return __uint_as_float(b << 16); }
__device__ __forceinline__ void split_bf(float x, unsigned short& h, unsigned short& l) {
    unsigned hb = bfhi_bits(x);
    h = (unsigned short)hb;
    l = (unsigned short)bfhi_bits(x - bits2f(hb));
}

// ---------------------------------------------------------------------------
// Pack W[NO][K] fp32 (row-major) into MFMA B-fragment order, bf16 hi/lo.
// ---------------------------------------------------------------------------
__global__ void pack_w(const float* __restrict__ W, unsigned short* __restrict__ hi,
                       unsigned short* __restrict__ lo, int NO, int K, int steps) {
    const int gid = blockIdx.x * 256 + threadIdx.x;
    const int total = (NO >> 4) * steps * 512;
    if (gid >= total) return;
    const int j = gid & 7, l = (gid >> 3) & 63, rest = gid >> 9;
    const int t = rest % steps, nt = rest / steps;
    const int n = nt * 16 + (l & 15);
    const int k = t * 32 + ((l >> 4) << 3) + j;
    const float x = (k < K) ? W[(size_t)n * K + k] : 0.f;
    unsigned short h, lw;
    split_bf(x, h, lw);
    hi[gid] = h; lo[gid] = lw;
}

// ---------------------------------------------------------------------------
// 3-pass split-bf16 MFMA K-loop (validated R4/R5).
// ---------------------------------------------------------------------------
template<int STEPS, int NTPW, int ASTR>
__device__ __forceinline__ void kloop(const unsigned short* PAh, const unsigned short* PAl,
    const unsigned short* __restrict__ wph, const unsigned short* __restrict__ wpl,
    float4v* acc, int lane, int wave)
{
    const int m = lane & 15, q = lane >> 4;
    for (int t = 0; t < STEPS; ++t) {
        const int k0 = t * 32 + q * 8;
        const short8 ah = *(const short8*)(PAh + m * ASTR + k0);
        const short8 al = *(const short8*)(PAl + m * ASTR + k0);
        #pragma unroll
        for (int i = 0; i < NTPW; ++i) {
            const int nt = wave * NTPW + i;
            const size_t off = ((size_t)(nt * STEPS + t) * 64 + lane) * 8;
            const short8 bh = *(const short8*)(wph + off);
            const short8 bl = *(const short8*)(wpl + off);
            acc[i] = __builtin_amdgcn_mfma_f32_16x16x32_bf16(ah, bh, acc[i], 0, 0, 0);
            acc[i] = __builtin_amdgcn_mfma_f32_16x16x32_bf16(al, bh, acc[i], 0, 0, 0);
            acc[i] = __builtin_amdgcn_mfma_f32_16x16x32_bf16(ah, bl, acc[i], 0, 0, 0);
        }
    }
}

// ---------------------------------------------------------------------------
// Edge kernel: 16 edges / block, 256 threads (4 waves).
// Strides padded for LDS banking: SA=360 shorts (720 B -> m*20 mod 32, ~2-way),
// SBs=168 shorts (336 B, same).  Old 352/160 gave m*16 mod 32 -> 8-way conflict.
// B2 (52 f32/edge) aliases PA cols [160,264): dead after m1 kloop (m2/m3 read
// PA cols [0,160) only).  Requires a barrier between m1 kloop and B2 write.
// B0 (fp32 V-concat) aliases the PB region (disjoint live ranges).
// LDS total 40448 B -> 4 blocks/CU (was 43008 -> 3 blocks/CU).
// Aggregation in fp64 atomics: order-invariant to fp32 precision -> graph
// replays deterministic.
// ---------------------------------------------------------------------------
constexpr int SA  = 360;
constexpr int SBs = 168;
constexpr int SB1 = 100;

__global__ __launch_bounds__(256)
void edge_kernel(const float* __restrict__ s, const float* __restrict__ v,
                 const int* __restrict__ eidx,
                 const float* __restrict__ es, const float* __restrict__ ev,
                 const float* __restrict__ m1_wh, const float* __restrict__ m1_wsb,
                 const float* __restrict__ m1_wv,
                 const float* __restrict__ m2_wh, const float* __restrict__ m2_wsb,
                 const float* __restrict__ m2_wv,
                 const float* __restrict__ m3_wh, const float* __restrict__ m3_wsb,
                 const float* __restrict__ m3_wv,
                 const unsigned short* __restrict__ p1h, const unsigned short* __restrict__ p1l,
                 const unsigned short* __restrict__ p2h, const unsigned short* __restrict__ p2l,
                 const unsigned short* __restrict__ p3h, const unsigned short* __restrict__ p3l,
                 double* __restrict__ agg_s, double* __restrict__ agg_v,
                 float* __restrict__ cnt, int E)
{
    __shared__ __align__(16) unsigned short PAh[16 * SA], PAl[16 * SA];
    __shared__ __align__(16) unsigned short PBmem[2 * 16 * SBs];
    __shared__ __align__(16) float B1[16 * SB1];
    __shared__ int ssrc[16], sgd[16], sdst[16], seid[16];

    unsigned short* PBh = PBmem;
    unsigned short* PBl = PBmem + 16 * SBs;
    float* B0 = (float*)PBmem;          // aliases PB: dead before PB is written

    const int tid = threadIdx.x, lane = tid & 63, wave = tid >> 6;
    const int e = tid & 15, q16 = tid >> 4;
    const int e0 = blockIdx.x * 16;

    // B2 row for edge ee: floats at PAh byte offset ee*720+320 (cols 160..264)
    #define B2ROW(ee) ((float*)PAh + (ee) * 180 + 80)

    // E1: indices
    if (tid < 16) {
        const int eg = e0 + tid;
        const bool ok = (eg < E);
        const int ee = ok ? eg : (E - 1);
        seid[tid] = ee;
        ssrc[tid] = eidx[ee];
        const int d = eidx[E + ee];
        sgd[tid] = d;
        sdst[tid] = ok ? d : -1;
    }
    __syncthreads();

    // E2a: S-concat gather -> PA[0,288) as short8 b128 writes (8 floats/task)
    #pragma unroll
    for (int it = 0; it < 3; ++it) {
        const int c = q16 + 16 * it;
        if (c < 36) {
            const float* srcp; int col;
            if (c < 16)      { srcp = s  + (size_t)ssrc[e] * 128 + 8 * c;       col = 8 * c; }
            else if (c < 20) { srcp = es + (size_t)seid[e] * 32 + 8 * (c - 16); col = 128 + 8 * (c - 16); }
            else             { srcp = s  + (size_t)sgd[e]  * 128 + 8 * (c - 20); col = 160 + 8 * (c - 20); }
            const float4 x = ((const float4*)srcp)[0];
            const float4 y = ((const float4*)srcp)[1];
            short8 hv, lv; unsigned short h, l;
            split_bf(x.x, h, l); hv[0] = h; lv[0] = l;
            split_bf(x.y, h, l); hv[1] = h; lv[1] = l;
            split_bf(x.z, h, l); hv[2] = h; lv[2] = l;
            split_bf(x.w, h, l); hv[3] = h; lv[3] = l;
            split_bf(y.x, h, l); hv[4] = h; lv[4] = l;
            split_bf(y.y, h, l); hv[5] = h; lv[5] = l;
            split_bf(y.z, h, l); hv[6] = h; lv[6] = l;
            split_bf(y.w, h, l); hv[7] = h; lv[7] = l;
            *(short8*)(PAh + e * SA + col) = hv;
            *(short8*)(PAl + e * SA + col) = lv;
        }
    }
    // zero-pad PA cols [320,352)  (col 320 is later overwritten by vn1[32])
    #pragma unroll
    for (int it = 0; it < 2; ++it) {
        const int col = 320 + q16 + 16 * it;
        PAh[e * SA + col] = 0; PAl[e * SA + col] = 0;
    }
    // E2b: V-concat gather -> B0 (fp32, cols c*3+t, 99 used)
    {
        if (q16 < 12) {
            const float4 x = ((const float4*)(v + (size_t)ssrc[e] * 48))[q16];
            *(float4*)(B0 + e * SB1 + 4 * q16) = x;
        } else if (q16 == 12) {
            const float* qv = ev + (size_t)seid[e] * 3;
            float* p = B0 + e * SB1 + 48;
            p[0] = qv[0]; p[1] = qv[1]; p[2] = qv[2];
        }
        if (q16 < 12) {
            const float4 x = ((const float4*)(v + (size_t)sgd[e] * 48))[q16];
            float* p = B0 + e * SB1 + 51 + 4 * q16;
            p[0] = x.x; p[1] = x.y; p[2] = x.z; p[3] = x.w;
        }
    }
    __syncthreads();

    // E3+E4 fused: vh1 = m1_wh @ Vcat -> B1; vn1 -> PA[288,321)
    #pragma unroll
    for (int it = 0; it < 3; ++it) {
        const int h = q16 + 16 * it;
        if (h < 33) {
            const float* wrow = m1_wh + h * 33;
            const float* vb = B0 + e * SB1;
            float a0 = 0.f, a1 = 0.f, a2 = 0.f;
            for (int c = 0; c < 33; ++c) {
                const float w = wrow[c];
                a0 = fmaf(vb[c * 3 + 0], w, a0);
                a1 = fmaf(vb[c * 3 + 1], w, a1);
                a2 = fmaf(vb[c * 3 + 2], w, a2);
            }
            float* o = B1 + e * SB1 + h * 3;
            o[0] = a0; o[1] = a1; o[2] = a2;
            const float vn = sqrtf(fmaxf(a0 * a0 + a1 * a1 + a2 * a2, EPSF));
            unsigned short hh, ll; split_bf(vn, hh, ll);
            PAh[e * SA + 288 + h] = hh; PAl[e * SA + 288 + h] = ll;
        }
    }
    __syncthreads();

    // E5: m1 MFMA (K=352) -> barrier (PA reads done) -> relu -> PB[0,128);
    //     vout1 -> B2 (aliases PA cols [160,264))
    {
        float4v acc[2] = {{0,0,0,0},{0,0,0,0}};
        kloop<11, 2, SA>(PAh, PAl, p1h, p1l, acc, lane, wave);
        __syncthreads();   // all waves done reading PA before B2 overlays it
        const int q = lane >> 4;
        #pragma unroll
        for (int i = 0; i < 2; ++i) {
            const int n = (wave * 2 + i) * 16 + (lane & 15);
            const float bias = m1_wsb[n];
            #pragma unroll
            for (int r = 0; r < 4; ++r) {
                const int m = q * 4 + r;
                const float x = fmaxf(acc[i][r] + bias, 0.f);
                unsigned short h, l; split_bf(x, h, l);
                PBh[m * SBs + n] = h; PBl[m * SBs + n] = l;
            }
        }
    }
    {   // vout1: o = q16 (VO=16), all threads active
        const int o = q16;
        float a0 = 0.f, a1 = 0.f, a2 = 0.f;
        for (int h = 0; h < 33; ++h) {
            const float w = m1_wv[o * 33 + h];
            const float* p = B1 + e * SB1 + h * 3;
            a0 = fmaf(p[0], w, a0); a1 = fmaf(p[1], w, a1); a2 = fmaf(p[2], w, a2);
        }
        const float nrm = sqrtf(fmaxf(a0 * a0 + a1 * a1 + a2 * a2, EPSF));
        const float sg = 1.f / (1.f + __expf(-nrm));
        float* p2 = B2ROW(e) + o * 3;
        p2[0] = a0 * sg; p2[1] = a1 * sg; p2[2] = a2 * sg;
    }
    __syncthreads();

    // E6+E7 fused: vh2 -> B1; vn2 -> PB[128,144); zero PB[144,160)
    {
        const int h = q16;
        float a0 = 0.f, a1 = 0.f, a2 = 0.f;
        for (int c = 0; c < 16; ++c) {
            const float w = m2_wh[h * 16 + c];
            const float* p = B2ROW(e) + c * 3;
            a0 = fmaf(p[0], w, a0); a1 = fmaf(p[1], w, a1); a2 = fmaf(p[2], w, a2);
        }
        float* o = B1 + e * SB1 + h * 3;
        o[0] = a0; o[1] = a1; o[2] = a2;
        const float vn = sqrtf(fmaxf(a0 * a0 + a1 * a1 + a2 * a2, EPSF));
        unsigned short hh, ll; split_bf(vn, hh, ll);
        PBh[e * SBs + 128 + h] = hh; PBl[e * SBs + 128 + h] = ll;
        PBh[e * SBs + 144 + h] = 0;  PBl[e * SBs + 144 + h] = 0;
    }
    __syncthreads();

    // E8: m2 MFMA (K=160) -> relu -> PA[0,128); vout2 -> B2
    {
        float4v acc[2] = {{0,0,0,0},{0,0,0,0}};
        kloop<5, 2, SBs>(PBh, PBl, p2h, p2l, acc, lane, wave);
        const int q = lane >> 4;
        #pragma unroll
        for (int i = 0; i < 2; ++i) {
            const int n = (wave * 2 + i) * 16 + (lane & 15);
            const float bias = m2_wsb[n];
            #pragma unroll
            for (int r = 0; r < 4; ++r) {
                const int m = q * 4 + r;
                const float x = fmaxf(acc[i][r] + bias, 0.f);
                unsigned short h, l; split_bf(x, h, l);
                PAh[m * SA + n] = h; PAl[m * SA + n] = l;
            }
        }
    }
    {   // vout2
        const int o = q16;
        float a0 = 0.f, a1 = 0.f, a2 = 0.f;
        for (int h = 0; h < 16; ++h) {
            const float w = m2_wv[o * 16 + h];
            const float* p = B1 + e * SB1 + h * 3;
            a0 = fmaf(p[0], w, a0); a1 = fmaf(p[1], w, a1); a2 = fmaf(p[2], w, a2);
        }
        const float nrm = sqrtf(fmaxf(a0 * a0 + a1 * a1 + a2 * a2, EPSF));
        const float sg = 1.f / (1.f + __expf(-nrm));
        float* p2 = B2ROW(e) + o * 3;
        p2[0] = a0 * sg; p2[1] = a1 * sg; p2[2] = a2 * sg;
    }
    __syncthreads();

    // E9+E10 fused: vh3 -> B1; vn3 -> PA[128,144); zero PA[144,160)
    {
        const int h = q16;
        float a0 = 0.f, a1 = 0.f, a2 = 0.f;
        for (int c = 0; c < 16; ++c) {
            const float w = m3_wh[h * 16 + c];
            const float* p = B2ROW(e) + c * 3;
            a0 = fmaf(p[0], w, a0); a1 = fmaf(p[1], w, a1); a2 = fmaf(p[2], w, a2);
        }
        float* o = B1 + e * SB1 + h * 3;
        o[0] = a0; o[1] = a1; o[2] = a2;
        const float vn = sqrtf(fmaxf(a0 * a0 + a1 * a1 + a2 * a2, EPSF));
        unsigned short hh, ll; split_bf(vn, hh, ll);
        PAh[e * SA + 128 + h] = hh; PAl[e * SA + 128 + h] = ll;
        PAh[e * SA + 144 + h] = 0;  PAl[e * SA + 144 + h] = 0;
    }
    __syncthreads();

    // E11: m3 MFMA (K=160, no act, reads PA[0,160) only) + vout3 -> B2
    float4v acc3[2] = {{0,0,0,0},{0,0,0,0}};
    kloop<5, 2, SA>(PAh, PAl, p3h, p3l, acc3, lane, wave);
    {
        const int o = q16;
        float a0 = 0.f, a1 = 0.f, a2 = 0.f;
        for (int h = 0; h < 16; ++h) {
            const float w = m3_wv[o * 16 + h];
            const float* p = B1 + e * SB1 + h * 3;
            a0 = fmaf(p[0], w, a0); a1 = fmaf(p[1], w, a1); a2 = fmaf(p[2], w, a2);
        }
        float* p2 = B2ROW(e) + o * 3;
        p2[0] = a0; p2[1] = a1; p2[2] = a2;
    }
    __syncthreads();

    // E12: scatter-add (fp64 atomics -> order-invariant aggregation)
    {
        const int q = lane >> 4;
        #pragma unroll
        for (int i = 0; i < 2; ++i) {
            const int n = (wave * 2 + i) * 16 + (lane & 15);
            const float bias = m3_wsb[n];
            #pragma unroll
            for (int r = 0; r < 4; ++r) {
                const int m = q * 4 + r;
                const int d = sdst[m];
                if (d >= 0) atomicAdd(&agg_s[(size_t)d * 128 + n], (double)(acc3[i][r] + bias));
            }
        }
    }
    #pragma unroll
    for (int it = 0; it < 3; ++it) {
        const int j = q16 + 16 * it;     // j < 48 exactly
        const int d = sdst[e];
        if (d >= 0) atomicAdd(&agg_v[(size_t)d * 48 + j], (double)B2ROW(e)[j]);
    }
    if (tid < 16 && sdst[tid] >= 0) atomicAdd(&cnt[sdst[tid]], 1.0f);
    #undef B2ROW
}

// ===========================================================================
// R3/R5's proven fp32-VALU node path (verbatim)
// ===========================================================================
template<int VI, int H, int SIcat, int KP, int SO, int VO, bool ACT,
         int SSTR, int VSTR, int HSTR, int SOSTR, int VOSTR>
__device__ __forceinline__ void gvp4(
    float* S, const float* V, float* VH, float* SOb, float* VOb,
    const float* __restrict__ wh, const float* __restrict__ wswP,
    const float* __restrict__ wsb, const float* __restrict__ wv, int lane)
{
    static_assert(SO % 64 == 0 && KP % 4 == 0, "shape");
    for (int idx = lane; idx < H * 3; idx += 64) {
        const int h = idx / 3, t = idx - h * 3;
        const float* w = wh + h * VI;
        float acc[ED] = {0.f, 0.f, 0.f, 0.f};
        for (int c = 0; c < VI; ++c) {
            const float wc = w[c];
            #pragma unroll
            for (int e = 0; e < ED; ++e) acc[e] = fmaf(V[e * VSTR + c * 3 + t], wc, acc[e]);
        }
        #pragma unroll
        for (int e = 0; e < ED; ++e) VH[e * HSTR + idx] = acc[e];
    }
    __syncthreads();
    for (int h = lane; h < H; h += 64) {
        #pragma unroll
        for (int e = 0; e < ED; ++e) {
            const float a = VH[e * HSTR + h * 3 + 0], b = VH[e * HSTR + h * 3 + 1],
                        c = VH[e * HSTR + h * 3 + 2];
            S[e * SSTR + SIcat + h] = sqrtf(fmaxf(a * a + b * b + c * c, EPSF));
        }
    }
    __syncthreads();
    constexpr int OF = SO / 64;
    {
        float acc[OF][ED];
        #pragma unroll
        for (int of = 0; of < OF; ++of) {
            const float bias = wsb[lane + of * 64];
            #pragma unroll
            for (int e = 0; e < ED; ++e) acc[of][e] = bias;
        }
        for (int k = 0; k < KP; k += 4) {
            float4 sv[ED];
            #pragma unroll
            for (int e = 0; e < ED; ++e) sv[e] = *(const float4*)&S[e * SSTR + k];
            #pragma unroll
            for (int of = 0; of < OF; ++of) {
                const float4 w = *(const float4*)&wswP[(size_t)(lane + of * 64) * KP + k];
                #pragma unroll
                for (int e = 0; e < ED; ++e) {
                    acc[of][e] = fmaf(w.x, sv[e].x, acc[of][e]);
                    acc[of][e] = fmaf(w.y, sv[e].y, acc[of][e]);
                    acc[of][e] = fmaf(w.z, sv[e].z, acc[of][e]);
                    acc[of][e] = fmaf(w.w, sv[e].w, acc[of][e]);
                }
            }
        }
        #pragma unroll
        for (int of = 0; of < OF; ++of)
            #pragma unroll
            for (int e = 0; e < ED; ++e) {
                float a = acc[of][e];
                if (ACT) a = fmaxf(a, 0.f);
                SOb[e * SOSTR + lane + of * 64] = a;
            }
    }
    for (int idx = lane; idx < VO * 3; idx += 64) {
        const int o = idx / 3, t = idx - o * 3;
        const float* w = wv + o * H;
        float acc[ED] = {0.f, 0.f, 0.f, 0.f};
        for (int h = 0; h < H; ++h) {
            const float wc = w[h];
            #pragma unroll
            for (int e = 0; e < ED; ++e) acc[e] = fmaf(VH[e * HSTR + h * 3 + t], wc, acc[e]);
        }
        #pragma unroll
        for (int e = 0; e < ED; ++e) VOb[e * VOSTR + idx] = acc[e];
    }
    __syncthreads();
    if (ACT) {
        for (int o = lane; o < VO; o += 64) {
            #pragma unroll
            for (int e = 0; e < ED; ++e) {
                float* p = VOb + e * VOSTR + o * 3;
                const float a = p[0], b = p[1], c = p[2];
                const float nrm = sqrtf(fmaxf(a * a + b * b + c * c, EPSF));
                const float sg = 1.f / (1.f + __expf(-nrm));
                p[0] = a * sg; p[1] = b * sg; p[2] = c * sg;
            }
        }
        __syncthreads();
    }
}

template<int SSTR, int VSTR>
__device__ __forceinline__ void layer_norm4(float* S, float* V,
    const float* __restrict__ g, const float* __restrict__ b, float* red, int lane)
{
    #pragma unroll
    for (int e = 0; e < ED; ++e) {
        float x0 = S[e * SSTR + lane], x1 = S[e * SSTR + 64 + lane];
        float sum = x0 + x1;
        #pragma unroll
        for (int off = 32; off > 0; off >>= 1) sum += __shfl_xor(sum, off, 64);
        const float mu = sum * (1.f / 128.f);
        const float d0 = x0 - mu, d1 = x1 - mu;
        float vs = d0 * d0 + d1 * d1;
        #pragma unroll
        for (int off = 32; off > 0; off >>= 1) vs += __shfl_xor(vs, off, 64);
        const float rstd = rsqrtf(vs * (1.f / 128.f) + 1e-5f);
        S[e * SSTR + lane]      = d0 * rstd * g[lane]      + b[lane];
        S[e * SSTR + 64 + lane] = d1 * rstd * g[lane + 64] + b[lane + 64];

        if (lane < 16) {
            const float a = V[e * VSTR + lane * 3], bb = V[e * VSTR + lane * 3 + 1],
                        cc = V[e * VSTR + lane * 3 + 2];
            const float vn = fmaxf(a * a + bb * bb + cc * cc, EPSF);
            red[lane]      = vn;
            red[16 + lane] = (vn > 2.f * EPSF) ? 1.f : 0.f;
        }
        __syncthreads();
        float sn = 0.f, sm = 0.f;
        #pragma unroll
        for (int i = 0; i < 16; ++i) { sn += red[i] * red[16 + i]; sm += red[16 + i]; }
        const float rvm = rsqrtf(sn / (EPSF + sm) + EPSF);
        if (lane < 48) V[e * VSTR + lane] = red[16 + lane / 3] * V[e * VSTR + lane] * rvm;
        __syncthreads();
    }
}

__global__ __launch_bounds__(128)
void node_kernel(const float* __restrict__ s, const float* __restrict__ v,
                 const float* __restrict__ f1_wh, const float* __restrict__ f1_wsw,
                 const float* __restrict__ f1_wsb, const float* __restrict__ f1_wv,
                 const float* __restrict__ f2_wh, const float* __restrict__ f2_wsw,
                 const float* __restrict__ f2_wsb, const float* __restrict__ f2_wv,
                 const float* __restrict__ ln0_g, const float* __restrict__ ln0_b,
                 const float* __restrict__ ln1_g, const float* __restrict__ ln1_b,
                 const double* __restrict__ agg_s, const double* __restrict__ agg_v,
                 const float* __restrict__ cnt,
                 float* __restrict__ out, int N)
{
    __shared__ __align__(16) float nsm[2 * 4608];
    const int wave = threadIdx.x >> 6, lane = threadIdx.x & 63;
    float* S1  = nsm + wave * 4608;
    float* V1  = S1 + 640;
    float* FS  = S1 + 832;
    float* FV  = S1 + 3008;
    float* VHb = S1 + 3392;
    float* OS  = S1 + 3776;
    float* OV  = S1 + 4288;
    float* red = S1 + 4480;

    const int n0 = (blockIdx.x * 2 + wave) * ED;
    bool oks[ED];
    #pragma unroll
    for (int e = 0; e < ED; ++e) {
        const int ng = n0 + e;
        oks[e] = (ng < N);
        const int n = oks[e] ? ng : (N - 1);
        const double inv = 1.0 / (double)fmaxf(cnt[n], 1.f);
        if (lane < 32) {
            const float4 a = ((const float4*)(s + (size_t)n * 128))[lane];
            const double2 b0 = ((const double2*)(agg_s + (size_t)n * 128))[2 * lane];
            const double2 b1 = ((const double2*)(agg_s + (size_t)n * 128))[2 * lane + 1];
            float4 r;
            r.x = (float)((double)a.x + b0.x * inv);
            r.y = (float)((double)a.y + b0.y * inv);
            r.z = (float)((double)a.z + b1.x * inv);
            r.w = (float)((double)a.w + b1.y * inv);
            ((float4*)(S1 + e * 160))[lane] = r;
        }
        if (lane < 12) {
            const float4 a = ((const float4*)(v + (size_t)n * 48))[lane];
            const double2 b0 = ((const double2*)(agg_v + (size_t)n * 48))[2 * lane];
            const double2 b1 = ((const double2*)(agg_v + (size_t)n * 48))[2 * lane + 1];
            float4 r;
            r.x = (float)((double)a.x + b0.x * inv);
            r.y = (float)((double)a.y + b0.y * inv);
            r.z = (float)((double)a.z + b1.x * inv);
            r.w = (float)((double)a.w + b1.y * inv);
            ((float4*)(V1 + e * 48))[lane] = r;
        }
    }
    __syncthreads();

    layer_norm4<160, 48>(S1, V1, ln0_g, ln0_b, red, lane);

    gvp4<16, 32, 128, 160, 512, 32, true, 160, 48, 96, 544, 96>(
        S1, V1, VHb, FS, FV, f1_wh, f1_wsw, f1_wsb, f1_wv, lane);
    gvp4<32, 32, 512, 544, 128, 16, false, 544, 96, 96, 128, 48>(
        FS, FV, VHb, OS, OV, f2_wh, f2_wsw, f2_wsb, f2_wv, lane);

    #pragma unroll
    for (int e = 0; e < ED; ++e) {
        for (int i = lane; i < 128; i += 64) OS[e * 128 + i] += S1[e * 160 + i];
        if (lane < 48) OV[e * 48 + lane] += V1[e * 48 + lane];
    }
    __syncthreads();

    layer_norm4<128, 48>(OS, OV, ln1_g, ln1_b, red, lane);

    #pragma unroll
    for (int e = 0; e < ED; ++e) {
        if (!oks[e]) continue;
        const int n = n0 + e;
        if (lane < 32)
            ((float4*)(out + (size_t)n * 128))[lane] = ((const float4*)(OS + e * 128))[lane];
        if (lane < 12)
            ((float4*)(out + (size_t)N * 128 + (size_t)n * 48))[lane] =
                ((const float4*)(OV + e * 48))[lane];
    }
}

// ---------------------------------------------------------------------------
extern "C" void kernel_launch(void* const* d_in, const int* in_sizes, int n_in,
                              void* d_out, int out_size, void* d_ws, size_t ws_size,
                              hipStream_t stream)
{
    const float* s    = (const float*)d_in[0];
    const float* v    = (const float*)d_in[1];
    const int*   eidx = (const int*)d_in[2];
    const float* es   = (const float*)d_in[3];
    const float* ev   = (const float*)d_in[4];
    const float* m1_wh = (const float*)d_in[5];
    const float* m1_wsw = (const float*)d_in[6];
    const float* m1_wsb = (const float*)d_in[7];
    const float* m1_wv = (const float*)d_in[8];
    const float* m2_wh = (const float*)d_in[9];
    const float* m2_wsw = (const float*)d_in[10];
    const float* m2_wsb = (const float*)d_in[11];
    const float* m2_wv = (const float*)d_in[12];
    const float* m3_wh = (const float*)d_in[13];
    const float* m3_wsw = (const float*)d_in[14];
    const float* m3_wsb = (const float*)d_in[15];
    const float* m3_wv = (const float*)d_in[16];
    const float* f1_wh = (const float*)d_in[17];
    const float* f1_wsw = (const float*)d_in[18];
    const float* f1_wsb = (const float*)d_in[19];
    const float* f1_wv = (const float*)d_in[20];
    const float* f2_wh = (const float*)d_in[21];
    const float* f2_wsw = (const float*)d_in[22];
    const float* f2_wsb = (const float*)d_in[23];
    const float* f2_wv = (const float*)d_in[24];
    const float* ln0_g = (const float*)d_in[25];
    const float* ln0_b = (const float*)d_in[26];
    const float* ln1_g = (const float*)d_in[27];
    const float* ln1_b = (const float*)d_in[28];

    const int N = in_sizes[0] / 128;
    const int E = in_sizes[2] / 2;

    double* agg_s = (double*)d_ws;                     // N*128 f64
    double* agg_v = agg_s + (size_t)N * 128;           // N*48  f64
    float* cnt    = (float*)(agg_v + (size_t)N * 48);  // N     f32
    unsigned short* pk =
        (unsigned short*)(((uintptr_t)(cnt + N) + 15) & ~(uintptr_t)15);
    const int S_M1 = 45056, S_M23 = 20480;
    unsigned short* p1h = pk;            unsigned short* p1l = p1h + S_M1;
    unsigned short* p2h = p1l + S_M1;    unsigned short* p2l = p2h + S_M23;
    unsigned short* p3h = p2l + S_M23;   unsigned short* p3l = p3h + S_M23;

    hipMemsetAsync(d_ws, 0,
                   (size_t)N * 176 * sizeof(double) + (size_t)N * sizeof(float),
                   stream);

    pack_w<<<dim3((S_M1  + 255) / 256), dim3(256), 0, stream>>>(m1_wsw, p1h, p1l, 128, 321, 11);
    pack_w<<<dim3((S_M23 + 255) / 256), dim3(256), 0, stream>>>(m2_wsw, p2h, p2l, 128, 144, 5);
    pack_w<<<dim3((S_M23 + 255) / 256), dim3(256), 0, stream>>>(m3_wsw, p3h, p3l, 128, 144, 5);

    edge_kernel<<<dim3((E + 15) / 16), dim3(256), 0, stream>>>(
        s, v, eidx, es, ev,
        m1_wh, m1_wsb, m1_wv,
        m2_wh, m2_wsb, m2_wv,
        m3_wh, m3_wsb, m3_wv,
        p1h, p1l, p2h, p2l, p3h, p3l,
        agg_s, agg_v, cnt, E);

    node_kernel<<<dim3((N + 7) / 8), dim3(128), 0, stream>>>(
        s, v,
        f1_wh, f1_wsw, f1_wsb, f1_wv,
        f2_wh, f2_wsw, f2_wsb, f2_wv,
        ln0_g, ln0_b, ln1_g, ln1_b,
        agg_s, agg_v, cnt,
        (float*)d_out, N);
}

// Round 4
// 1577.033 us; speedup vs baseline: 1.2371x; 1.2371x over previous
//
#include <hip/hip_runtime.h>

#define EPSF 1e-8f
constexpr int ED = 4;   // nodes per wave in layer_norm4

typedef __attribute__((ext_vector_type(8))) short short8;
typedef __attribute__((ext_vector_type(4))) float float4v;

// ---- fp32 -> bf16 hi/lo split (RNE) ---------------------------------------
__device__ __forceinline__ unsigned bfhi_bits(float x) {
    unsigned u = __float_as_uint(x);
    return (u + 0x7fffu + ((u >> 16) & 1u)) >> 16;
}
__device__ __forceinline__ float bits2f(unsigned b) { return __uint_as_float(b << 16); }
__device__ __forceinline__ void split_bf(float x, unsigned short& h, unsigned short& l) {
    unsigned hb = bfhi_bits(x);
    h = (unsigned short)hb;
    l = (unsigned short)bfhi_bits(x - bits2f(hb));
}

// ---------------------------------------------------------------------------
// Pack W[NO][K] fp32 (row-major) into MFMA B-fragment order, bf16 hi/lo.
// ---------------------------------------------------------------------------
__global__ void pack_w(const float* __restrict__ W, unsigned short* __restrict__ hi,
                       unsigned short* __restrict__ lo, int NO, int K, int steps) {
    const int gid = blockIdx.x * 256 + threadIdx.x;
    const int total = (NO >> 4) * steps * 512;
    if (gid >= total) return;
    const int j = gid & 7, l = (gid >> 3) & 63, rest = gid >> 9;
    const int t = rest % steps, nt = rest / steps;
    const int n = nt * 16 + (l & 15);
    const int k = t * 32 + ((l >> 4) << 3) + j;
    const float x = (k < K) ? W[(size_t)n * K + k] : 0.f;
    unsigned short h, lw;
    split_bf(x, h, lw);
    hi[gid] = h; lo[gid] = lw;
}

// ---------------------------------------------------------------------------
// 3-pass split-bf16 MFMA K-loop (validated R4/R5).
// ---------------------------------------------------------------------------
template<int STEPS, int NTPW, int ASTR>
__device__ __forceinline__ void kloop(const unsigned short* PAh, const unsigned short* PAl,
    const unsigned short* __restrict__ wph, const unsigned short* __restrict__ wpl,
    float4v* acc, int lane, int wave)
{
    const int m = lane & 15, q = lane >> 4;
    for (int t = 0; t < STEPS; ++t) {
        const int k0 = t * 32 + q * 8;
        const short8 ah = *(const short8*)(PAh + m * ASTR + k0);
        const short8 al = *(const short8*)(PAl + m * ASTR + k0);
        #pragma unroll
        for (int i = 0; i < NTPW; ++i) {
            const int nt = wave * NTPW + i;
            const size_t off = ((size_t)(nt * STEPS + t) * 64 + lane) * 8;
            const short8 bh = *(const short8*)(wph + off);
            const short8 bl = *(const short8*)(wpl + off);
            acc[i] = __builtin_amdgcn_mfma_f32_16x16x32_bf16(ah, bh, acc[i], 0, 0, 0);
            acc[i] = __builtin_amdgcn_mfma_f32_16x16x32_bf16(al, bh, acc[i], 0, 0, 0);
            acc[i] = __builtin_amdgcn_mfma_f32_16x16x32_bf16(ah, bl, acc[i], 0, 0, 0);
        }
    }
}

// ---------------------------------------------------------------------------
// Edge kernel (green in R1/R2, verbatim): 16 edges / block, 256 threads.
// ---------------------------------------------------------------------------
constexpr int SA  = 360;
constexpr int SBs = 168;
constexpr int SB1 = 100;

__global__ __launch_bounds__(256)
void edge_kernel(const float* __restrict__ s, const float* __restrict__ v,
                 const int* __restrict__ eidx,
                 const float* __restrict__ es, const float* __restrict__ ev,
                 const float* __restrict__ m1_wh, const float* __restrict__ m1_wsb,
                 const float* __restrict__ m1_wv,
                 const float* __restrict__ m2_wh, const float* __restrict__ m2_wsb,
                 const float* __restrict__ m2_wv,
                 const float* __restrict__ m3_wh, const float* __restrict__ m3_wsb,
                 const float* __restrict__ m3_wv,
                 const unsigned short* __restrict__ p1h, const unsigned short* __restrict__ p1l,
                 const unsigned short* __restrict__ p2h, const unsigned short* __restrict__ p2l,
                 const unsigned short* __restrict__ p3h, const unsigned short* __restrict__ p3l,
                 double* __restrict__ agg_s, double* __restrict__ agg_v,
                 float* __restrict__ cnt, int E)
{
    __shared__ __align__(16) unsigned short PAh[16 * SA], PAl[16 * SA];
    __shared__ __align__(16) unsigned short PBmem[2 * 16 * SBs];
    __shared__ __align__(16) float B1[16 * SB1];
    __shared__ int ssrc[16], sgd[16], sdst[16], seid[16];

    unsigned short* PBh = PBmem;
    unsigned short* PBl = PBmem + 16 * SBs;
    float* B0 = (float*)PBmem;          // aliases PB: dead before PB is written

    const int tid = threadIdx.x, lane = tid & 63, wave = tid >> 6;
    const int e = tid & 15, q16 = tid >> 4;
    const int e0 = blockIdx.x * 16;

    #define B2ROW(ee) ((float*)PAh + (ee) * 180 + 80)

    if (tid < 16) {
        const int eg = e0 + tid;
        const bool ok = (eg < E);
        const int ee = ok ? eg : (E - 1);
        seid[tid] = ee;
        ssrc[tid] = eidx[ee];
        const int d = eidx[E + ee];
        sgd[tid] = d;
        sdst[tid] = ok ? d : -1;
    }
    __syncthreads();

    #pragma unroll
    for (int it = 0; it < 3; ++it) {
        const int c = q16 + 16 * it;
        if (c < 36) {
            const float* srcp; int col;
            if (c < 16)      { srcp = s  + (size_t)ssrc[e] * 128 + 8 * c;       col = 8 * c; }
            else if (c < 20) { srcp = es + (size_t)seid[e] * 32 + 8 * (c - 16); col = 128 + 8 * (c - 16); }
            else             { srcp = s  + (size_t)sgd[e]  * 128 + 8 * (c - 20); col = 160 + 8 * (c - 20); }
            const float4 x = ((const float4*)srcp)[0];
            const float4 y = ((const float4*)srcp)[1];
            short8 hv, lv; unsigned short h, l;
            split_bf(x.x, h, l); hv[0] = h; lv[0] = l;
            split_bf(x.y, h, l); hv[1] = h; lv[1] = l;
            split_bf(x.z, h, l); hv[2] = h; lv[2] = l;
            split_bf(x.w, h, l); hv[3] = h; lv[3] = l;
            split_bf(y.x, h, l); hv[4] = h; lv[4] = l;
            split_bf(y.y, h, l); hv[5] = h; lv[5] = l;
            split_bf(y.z, h, l); hv[6] = h; lv[6] = l;
            split_bf(y.w, h, l); hv[7] = h; lv[7] = l;
            *(short8*)(PAh + e * SA + col) = hv;
            *(short8*)(PAl + e * SA + col) = lv;
        }
    }
    #pragma unroll
    for (int it = 0; it < 2; ++it) {
        const int col = 320 + q16 + 16 * it;
        PAh[e * SA + col] = 0; PAl[e * SA + col] = 0;
    }
    {
        if (q16 < 12) {
            const float4 x = ((const float4*)(v + (size_t)ssrc[e] * 48))[q16];
            *(float4*)(B0 + e * SB1 + 4 * q16) = x;
        } else if (q16 == 12) {
            const float* qv = ev + (size_t)seid[e] * 3;
            float* p = B0 + e * SB1 + 48;
            p[0] = qv[0]; p[1] = qv[1]; p[2] = qv[2];
        }
        if (q16 < 12) {
            const float4 x = ((const float4*)(v + (size_t)sgd[e] * 48))[q16];
            float* p = B0 + e * SB1 + 51 + 4 * q16;
            p[0] = x.x; p[1] = x.y; p[2] = x.z; p[3] = x.w;
        }
    }
    __syncthreads();

    #pragma unroll
    for (int it = 0; it < 3; ++it) {
        const int h = q16 + 16 * it;
        if (h < 33) {
            const float* wrow = m1_wh + h * 33;
            const float* vb = B0 + e * SB1;
            float a0 = 0.f, a1 = 0.f, a2 = 0.f;
            for (int c = 0; c < 33; ++c) {
                const float w = wrow[c];
                a0 = fmaf(vb[c * 3 + 0], w, a0);
                a1 = fmaf(vb[c * 3 + 1], w, a1);
                a2 = fmaf(vb[c * 3 + 2], w, a2);
            }
            float* o = B1 + e * SB1 + h * 3;
            o[0] = a0; o[1] = a1; o[2] = a2;
            const float vn = sqrtf(fmaxf(a0 * a0 + a1 * a1 + a2 * a2, EPSF));
            unsigned short hh, ll; split_bf(vn, hh, ll);
            PAh[e * SA + 288 + h] = hh; PAl[e * SA + 288 + h] = ll;
        }
    }
    __syncthreads();

    {
        float4v acc[2] = {{0,0,0,0},{0,0,0,0}};
        kloop<11, 2, SA>(PAh, PAl, p1h, p1l, acc, lane, wave);
        __syncthreads();   // all waves done reading PA before B2 overlays it
        const int q = lane >> 4;
        #pragma unroll
        for (int i = 0; i < 2; ++i) {
            const int n = (wave * 2 + i) * 16 + (lane & 15);
            const float bias = m1_wsb[n];
            #pragma unroll
            for (int r = 0; r < 4; ++r) {
                const int m = q * 4 + r;
                const float x = fmaxf(acc[i][r] + bias, 0.f);
                unsigned short h, l; split_bf(x, h, l);
                PBh[m * SBs + n] = h; PBl[m * SBs + n] = l;
            }
        }
    }
    {
        const int o = q16;
        float a0 = 0.f, a1 = 0.f, a2 = 0.f;
        for (int h = 0; h < 33; ++h) {
            const float w = m1_wv[o * 33 + h];
            const float* p = B1 + e * SB1 + h * 3;
            a0 = fmaf(p[0], w, a0); a1 = fmaf(p[1], w, a1); a2 = fmaf(p[2], w, a2);
        }
        const float nrm = sqrtf(fmaxf(a0 * a0 + a1 * a1 + a2 * a2, EPSF));
        const float sg = 1.f / (1.f + __expf(-nrm));
        float* p2 = B2ROW(e) + o * 3;
        p2[0] = a0 * sg; p2[1] = a1 * sg; p2[2] = a2 * sg;
    }
    __syncthreads();

    {
        const int h = q16;
        float a0 = 0.f, a1 = 0.f, a2 = 0.f;
        for (int c = 0; c < 16; ++c) {
            const float w = m2_wh[h * 16 + c];
            const float* p = B2ROW(e) + c * 3;
            a0 = fmaf(p[0], w, a0); a1 = fmaf(p[1], w, a1); a2 = fmaf(p[2], w, a2);
        }
        float* o = B1 + e * SB1 + h * 3;
        o[0] = a0; o[1] = a1; o[2] = a2;
        const float vn = sqrtf(fmaxf(a0 * a0 + a1 * a1 + a2 * a2, EPSF));
        unsigned short hh, ll; split_bf(vn, hh, ll);
        PBh[e * SBs + 128 + h] = hh; PBl[e * SBs + 128 + h] = ll;
        PBh[e * SBs + 144 + h] = 0;  PBl[e * SBs + 144 + h] = 0;
    }
    __syncthreads();

    {
        float4v acc[2] = {{0,0,0,0},{0,0,0,0}};
        kloop<5, 2, SBs>(PBh, PBl, p2h, p2l, acc, lane, wave);
        const int q = lane >> 4;
        #pragma unroll
        for (int i = 0; i < 2; ++i) {
            const int n = (wave * 2 + i) * 16 + (lane & 15);
            const float bias = m2_wsb[n];
            #pragma unroll
            for (int r = 0; r < 4; ++r) {
                const int m = q * 4 + r;
                const float x = fmaxf(acc[i][r] + bias, 0.f);
                unsigned short h, l; split_bf(x, h, l);
                PAh[m * SA + n] = h; PAl[m * SA + n] = l;
            }
        }
    }
    {
        const int o = q16;
        float a0 = 0.f, a1 = 0.f, a2 = 0.f;
        for (int h = 0; h < 16; ++h) {
            const float w = m2_wv[o * 16 + h];
            const float* p = B1 + e * SB1 + h * 3;
            a0 = fmaf(p[0], w, a0); a1 = fmaf(p[1], w, a1); a2 = fmaf(p[2], w, a2);
        }
        const float nrm = sqrtf(fmaxf(a0 * a0 + a1 * a1 + a2 * a2, EPSF));
        const float sg = 1.f / (1.f + __expf(-nrm));
        float* p2 = B2ROW(e) + o * 3;
        p2[0] = a0 * sg; p2[1] = a1 * sg; p2[2] = a2 * sg;
    }
    __syncthreads();

    {
        const int h = q16;
        float a0 = 0.f, a1 = 0.f, a2 = 0.f;
        for (int c = 0; c < 16; ++c) {
            const float w = m3_wh[h * 16 + c];
            const float* p = B2ROW(e) + c * 3;
            a0 = fmaf(p[0], w, a0); a1 = fmaf(p[1], w, a1); a2 = fmaf(p[2], w, a2);
        }
        float* o = B1 + e * SB1 + h * 3;
        o[0] = a0; o[1] = a1; o[2] = a2;
        const float vn = sqrtf(fmaxf(a0 * a0 + a1 * a1 + a2 * a2, EPSF));
        unsigned short hh, ll; split_bf(vn, hh, ll);
        PAh[e * SA + 128 + h] = hh; PAl[e * SA + 128 + h] = ll;
        PAh[e * SA + 144 + h] = 0;  PAl[e * SA + 144 + h] = 0;
    }
    __syncthreads();

    float4v acc3[2] = {{0,0,0,0},{0,0,0,0}};
    kloop<5, 2, SA>(PAh, PAl, p3h, p3l, acc3, lane, wave);
    {
        const int o = q16;
        float a0 = 0.f, a1 = 0.f, a2 = 0.f;
        for (int h = 0; h < 16; ++h) {
            const float w = m3_wv[o * 16 + h];
            const float* p = B1 + e * SB1 + h * 3;
            a0 = fmaf(p[0], w, a0); a1 = fmaf(p[1], w, a1); a2 = fmaf(p[2], w, a2);
        }
        float* p2 = B2ROW(e) + o * 3;
        p2[0] = a0; p2[1] = a1; p2[2] = a2;
    }
    __syncthreads();

    {
        const int q = lane >> 4;
        #pragma unroll
        for (int i = 0; i < 2; ++i) {
            const int n = (wave * 2 + i) * 16 + (lane & 15);
            const float bias = m3_wsb[n];
            #pragma unroll
            for (int r = 0; r < 4; ++r) {
                const int m = q * 4 + r;
                const int d = sdst[m];
                if (d >= 0) atomicAdd(&agg_s[(size_t)d * 128 + n], (double)(acc3[i][r] + bias));
            }
        }
    }
    #pragma unroll
    for (int it = 0; it < 3; ++it) {
        const int j = q16 + 16 * it;
        const int d = sdst[e];
        if (d >= 0) atomicAdd(&agg_v[(size_t)d * 48 + j], (double)B2ROW(e)[j]);
    }
    if (tid < 16 && sdst[tid] >= 0) atomicAdd(&cnt[sdst[tid]], 1.0f);
    #undef B2ROW
}

// ===========================================================================
// layer_norm4 (proven, verbatim) — wave processes ED=4 nodes
// ===========================================================================
template<int SSTR, int VSTR>
__device__ __forceinline__ void layer_norm4(float* S, float* V,
    const float* __restrict__ g, const float* __restrict__ b, float* red, int lane)
{
    #pragma unroll
    for (int e = 0; e < ED; ++e) {
        float x0 = S[e * SSTR + lane], x1 = S[e * SSTR + 64 + lane];
        float sum = x0 + x1;
        #pragma unroll
        for (int off = 32; off > 0; off >>= 1) sum += __shfl_xor(sum, off, 64);
        const float mu = sum * (1.f / 128.f);
        const float d0 = x0 - mu, d1 = x1 - mu;
        float vs = d0 * d0 + d1 * d1;
        #pragma unroll
        for (int off = 32; off > 0; off >>= 1) vs += __shfl_xor(vs, off, 64);
        const float rstd = rsqrtf(vs * (1.f / 128.f) + 1e-5f);
        S[e * SSTR + lane]      = d0 * rstd * g[lane]      + b[lane];
        S[e * SSTR + 64 + lane] = d1 * rstd * g[lane + 64] + b[lane + 64];

        if (lane < 16) {
            const float a = V[e * VSTR + lane * 3], bb = V[e * VSTR + lane * 3 + 1],
                        cc = V[e * VSTR + lane * 3 + 2];
            const float vn = fmaxf(a * a + bb * bb + cc * cc, EPSF);
            red[lane]      = vn;
            red[16 + lane] = (vn > 2.f * EPSF) ? 1.f : 0.f;
        }
        __syncthreads();
        float sn = 0.f, sm = 0.f;
        #pragma unroll
        for (int i = 0; i < 16; ++i) { sn += red[i] * red[16 + i]; sm += red[16 + i]; }
        const float rvm = rsqrtf(sn / (EPSF + sm) + EPSF);
        if (lane < 48) V[e * VSTR + lane] = red[16 + lane / 3] * V[e * VSTR + lane] * rvm;
        __syncthreads();
    }
}

// ===========================================================================
// Node kernel: 8 nodes/block, 128 threads (2 waves).
// f1 (K=160 -> 512) via 3-pass bf16 MFMA; f2 (K=544 -> 128) in exact fp32
// (float4 GEMM, R1-proven pattern) so the LN1-facing output has no bf16 error.
// No buffer overlays. MFMA A rows 8-15 are unwritten (garbage) -> their C rows
// are discarded (MFMA row m depends only on A row m).
// LDS = 41.6 KB -> 3 blocks/CU.
// ===========================================================================
constexpr int NNS  = 164;  // S1f stride (f32)
constexpr int NNV  = 52;   // V1f stride (f32)
constexpr int NNH  = 98;   // VH/FV stride (f32)
constexpr int NA1n = 168;  // f1 A stride (shorts), K=160
constexpr int FSS  = 544;  // FS stride (f32): [relu(fs1) 512 | vn2 32]

__global__ __launch_bounds__(128)
void node_kernel(const float* __restrict__ s, const float* __restrict__ v,
                 const float* __restrict__ f1_wh, const float* __restrict__ f1_wsb,
                 const float* __restrict__ f1_wv,
                 const float* __restrict__ f2_wh, const float* __restrict__ f2_wsw,
                 const float* __restrict__ f2_wsb, const float* __restrict__ f2_wv,
                 const float* __restrict__ ln0_g, const float* __restrict__ ln0_b,
                 const float* __restrict__ ln1_g, const float* __restrict__ ln1_b,
                 const unsigned short* __restrict__ pf1h, const unsigned short* __restrict__ pf1l,
                 const double* __restrict__ agg_s, const double* __restrict__ agg_v,
                 const float* __restrict__ cnt,
                 float* __restrict__ out, int N)
{
    __shared__ __align__(16) unsigned short UBh[16 * NA1n], UBl[16 * NA1n];
    __shared__ __align__(16) float FS[8 * FSS];
    __shared__ __align__(16) float S1f[8 * NNS];
    __shared__ __align__(16) float V1f[8 * NNV];
    __shared__ __align__(16) float VH[8 * NNH];
    __shared__ __align__(16) float FV[8 * NNH];
    __shared__ float red[2 * 32];

    const int tid = threadIdx.x, lane = tid & 63, wave = tid >> 6;
    const int e = tid & 7, qq = tid >> 3;    // e: node 0-7, qq: 0-15
    const int n0 = blockIdx.x * 8;

    // P0: load s+agg_s/cnt, v+agg_v/cnt (fp64 agg -> deterministic)
    bool oks[ED];
    #pragma unroll
    for (int e4 = 0; e4 < ED; ++e4) {
        const int idx = wave * 4 + e4;
        const int ng = n0 + idx;
        oks[e4] = (ng < N);
        const int n = oks[e4] ? ng : (N - 1);
        const double inv = 1.0 / (double)fmaxf(cnt[n], 1.f);
        if (lane < 32) {
            const float4 a = ((const float4*)(s + (size_t)n * 128))[lane];
            const double2 b0 = ((const double2*)(agg_s + (size_t)n * 128))[2 * lane];
            const double2 b1 = ((const double2*)(agg_s + (size_t)n * 128))[2 * lane + 1];
            float4 r;
            r.x = (float)((double)a.x + b0.x * inv);
            r.y = (float)((double)a.y + b0.y * inv);
            r.z = (float)((double)a.z + b1.x * inv);
            r.w = (float)((double)a.w + b1.y * inv);
            ((float4*)(S1f + idx * NNS))[lane] = r;
        }
        if (lane < 12) {
            const float4 a = ((const float4*)(v + (size_t)n * 48))[lane];
            const double2 b0 = ((const double2*)(agg_v + (size_t)n * 48))[2 * lane];
            const double2 b1 = ((const double2*)(agg_v + (size_t)n * 48))[2 * lane + 1];
            float4 r;
            r.x = (float)((double)a.x + b0.x * inv);
            r.y = (float)((double)a.y + b0.y * inv);
            r.z = (float)((double)a.z + b1.x * inv);
            r.w = (float)((double)a.w + b1.y * inv);
            ((float4*)(V1f + idx * NNV))[lane] = r;
        }
    }
    __syncthreads();

    // P1: LN0 (2 waves x 4 nodes; internal barriers uniform)
    layer_norm4<NNS, NNV>(S1f + wave * 4 * NNS, V1f + wave * 4 * NNV,
                          ln0_g, ln0_b, red + wave * 32, lane);

    // P2: split s1 -> f1-A[0,128); vh1 -> VH; vn1 -> f1-A[128,160)
    {
        const float* sp = S1f + e * NNS + qq * 8;
        short8 hv, lv; unsigned short h, l;
        #pragma unroll
        for (int j = 0; j < 8; ++j) { split_bf(sp[j], h, l); hv[j] = h; lv[j] = l; }
        *(short8*)(UBh + e * NA1n + qq * 8) = hv;
        *(short8*)(UBl + e * NA1n + qq * 8) = lv;
    }
    #pragma unroll
    for (int hi = 0; hi < 2; ++hi) {
        const int h = qq + 16 * hi;
        const float* w = f1_wh + h * 16;
        const float* vb = V1f + e * NNV;
        float a0 = 0.f, a1 = 0.f, a2 = 0.f;
        for (int c = 0; c < 16; ++c) {
            const float wc = w[c];
            a0 = fmaf(vb[c * 3 + 0], wc, a0);
            a1 = fmaf(vb[c * 3 + 1], wc, a1);
            a2 = fmaf(vb[c * 3 + 2], wc, a2);
        }
        float* o = VH + e * NNH + h * 3;
        o[0] = a0; o[1] = a1; o[2] = a2;
        const float vn = sqrtf(fmaxf(a0 * a0 + a1 * a1 + a2 * a2, EPSF));
        unsigned short hh, ll; split_bf(vn, hh, ll);
        UBh[e * NA1n + 128 + h] = hh; UBl[e * NA1n + 128 + h] = ll;
    }
    __syncthreads();

    // P3: f1 MFMA (K=160, NO=512) -> relu -> FS[0,512) fp32 (rows m<8 only);
    //     fv1 (sigmoid-gated) -> FV
    {
        float4v acc1[16];
        #pragma unroll
        for (int i = 0; i < 16; ++i) acc1[i] = (float4v){0.f, 0.f, 0.f, 0.f};
        kloop<5, 16, NA1n>(UBh, UBl, pf1h, pf1l, acc1, lane, wave);
        const int q = lane >> 4;
        #pragma unroll
        for (int i = 0; i < 16; ++i) {
            const int n = (wave * 16 + i) * 16 + (lane & 15);
            const float bias = f1_wsb[n];
            #pragma unroll
            for (int r = 0; r < 4; ++r) {
                const int m = q * 4 + r;
                if (m < 8) FS[m * FSS + n] = fmaxf(acc1[i][r] + bias, 0.f);
            }
        }
    }
    #pragma unroll
    for (int oi = 0; oi < 2; ++oi) {
        const int o = qq + 16 * oi;
        const float* w = f1_wv + o * 32;
        float a0 = 0.f, a1 = 0.f, a2 = 0.f;
        for (int h = 0; h < 32; ++h) {
            const float wc = w[h];
            const float* p = VH + e * NNH + h * 3;
            a0 = fmaf(p[0], wc, a0); a1 = fmaf(p[1], wc, a1); a2 = fmaf(p[2], wc, a2);
        }
        const float nrm = sqrtf(fmaxf(a0 * a0 + a1 * a1 + a2 * a2, EPSF));
        const float sg = 1.f / (1.f + __expf(-nrm));
        float* p2 = FV + e * NNH + o * 3;
        p2[0] = a0 * sg; p2[1] = a1 * sg; p2[2] = a2 * sg;
    }
    __syncthreads();

    // P4: vh2 -> VH (overwrite); vn2 -> FS[512,544) (fp32, no split needed)
    #pragma unroll
    for (int hi = 0; hi < 2; ++hi) {
        const int h = qq + 16 * hi;
        const float* w = f2_wh + h * 32;
        float a0 = 0.f, a1 = 0.f, a2 = 0.f;
        for (int c = 0; c < 32; ++c) {
            const float wc = w[c];
            const float* p = FV + e * NNH + c * 3;
            a0 = fmaf(p[0], wc, a0); a1 = fmaf(p[1], wc, a1); a2 = fmaf(p[2], wc, a2);
        }
        float* o = VH + e * NNH + h * 3;
        o[0] = a0; o[1] = a1; o[2] = a2;
        FS[e * FSS + 512 + h] = sqrtf(fmaxf(a0 * a0 + a1 * a1 + a2 * a2, EPSF));
    }
    __syncthreads();

    // P5: f2 fp32 GEMM (K=544, NO=128, R1-proven float4 pattern) -> S1f residual;
    //     fv2 -> V1f residual
    {
        float acc[2][4];
        #pragma unroll
        for (int of = 0; of < 2; ++of) {
            const float bias = f2_wsb[lane + of * 64];
            #pragma unroll
            for (int e4 = 0; e4 < 4; ++e4) acc[of][e4] = bias;
        }
        for (int k = 0; k < FSS; k += 4) {
            float4 sv[4];
            #pragma unroll
            for (int e4 = 0; e4 < 4; ++e4)
                sv[e4] = *(const float4*)&FS[(wave * 4 + e4) * FSS + k];
            #pragma unroll
            for (int of = 0; of < 2; ++of) {
                const float4 w = *(const float4*)&f2_wsw[(size_t)(lane + of * 64) * 544 + k];
                #pragma unroll
                for (int e4 = 0; e4 < 4; ++e4) {
                    acc[of][e4] = fmaf(w.x, sv[e4].x, acc[of][e4]);
                    acc[of][e4] = fmaf(w.y, sv[e4].y, acc[of][e4]);
                    acc[of][e4] = fmaf(w.z, sv[e4].z, acc[of][e4]);
                    acc[of][e4] = fmaf(w.w, sv[e4].w, acc[of][e4]);
                }
            }
        }
        #pragma unroll
        for (int of = 0; of < 2; ++of)
            #pragma unroll
            for (int e4 = 0; e4 < 4; ++e4)
                S1f[(wave * 4 + e4) * NNS + lane + of * 64] += acc[of][e4];
    }
    {   // fv2: each thread one (e, o) pair
        const int o = qq;
        const float* w = f2_wv + o * 32;
        float a0 = 0.f, a1 = 0.f, a2 = 0.f;
        for (int h = 0; h < 32; ++h) {
            const float wc = w[h];
            const float* p = VH + e * NNH + h * 3;
            a0 = fmaf(p[0], wc, a0); a1 = fmaf(p[1], wc, a1); a2 = fmaf(p[2], wc, a2);
        }
        float* p2 = V1f + e * NNV + o * 3;
        p2[0] += a0; p2[1] += a1; p2[2] += a2;
    }
    __syncthreads();

    // P6: LN1 + store
    layer_norm4<NNS, NNV>(S1f + wave * 4 * NNS, V1f + wave * 4 * NNV,
                          ln1_g, ln1_b, red + wave * 32, lane);

    #pragma unroll
    for (int e4 = 0; e4 < ED; ++e4) {
        if (!oks[e4]) continue;
        const int idx = wave * 4 + e4;
        const int n = n0 + idx;
        if (lane < 32)
            ((float4*)(out + (size_t)n * 128))[lane] = ((const float4*)(S1f + idx * NNS))[lane];
        if (lane < 12)
            ((float4*)(out + (size_t)N * 128 + (size_t)n * 48))[lane] =
                ((const float4*)(V1f + idx * NNV))[lane];
    }
}

// ---------------------------------------------------------------------------
extern "C" void kernel_launch(void* const* d_in, const int* in_sizes, int n_in,
                              void* d_out, int out_size, void* d_ws, size_t ws_size,
                              hipStream_t stream)
{
    const float* s    = (const float*)d_in[0];
    const float* v    = (const float*)d_in[1];
    const int*   eidx = (const int*)d_in[2];
    const float* es   = (const float*)d_in[3];
    const float* ev   = (const float*)d_in[4];
    const float* m1_wh = (const float*)d_in[5];
    const float* m1_wsw = (const float*)d_in[6];
    const float* m1_wsb = (const float*)d_in[7];
    const float* m1_wv = (const float*)d_in[8];
    const float* m2_wh = (const float*)d_in[9];
    const float* m2_wsw = (const float*)d_in[10];
    const float* m2_wsb = (const float*)d_in[11];
    const float* m2_wv = (const float*)d_in[12];
    const float* m3_wh = (const float*)d_in[13];
    const float* m3_wsw = (const float*)d_in[14];
    const float* m3_wsb = (const float*)d_in[15];
    const float* m3_wv = (const float*)d_in[16];
    const float* f1_wh = (const float*)d_in[17];
    const float* f1_wsw = (const float*)d_in[18];
    const float* f1_wsb = (const float*)d_in[19];
    const float* f1_wv = (const float*)d_in[20];
    const float* f2_wh = (const float*)d_in[21];
    const float* f2_wsw = (const float*)d_in[22];
    const float* f2_wsb = (const float*)d_in[23];
    const float* f2_wv = (const float*)d_in[24];
    const float* ln0_g = (const float*)d_in[25];
    const float* ln0_b = (const float*)d_in[26];
    const float* ln1_g = (const float*)d_in[27];
    const float* ln1_b = (const float*)d_in[28];

    const int N = in_sizes[0] / 128;
    const int E = in_sizes[2] / 2;

    double* agg_s = (double*)d_ws;                     // N*128 f64
    double* agg_v = agg_s + (size_t)N * 128;           // N*48  f64
    float* cnt    = (float*)(agg_v + (size_t)N * 48);  // N     f32
    unsigned short* pk =
        (unsigned short*)(((uintptr_t)(cnt + N) + 15) & ~(uintptr_t)15);
    const int S_M1 = 45056, S_M23 = 20480, S_F1 = 81920;
    unsigned short* p1h = pk;            unsigned short* p1l = p1h + S_M1;
    unsigned short* p2h = p1l + S_M1;    unsigned short* p2l = p2h + S_M23;
    unsigned short* p3h = p2l + S_M23;   unsigned short* p3l = p3h + S_M23;
    unsigned short* pf1h = p3l + S_M23;  unsigned short* pf1l = pf1h + S_F1;

    hipMemsetAsync(d_ws, 0,
                   (size_t)N * 176 * sizeof(double) + (size_t)N * sizeof(float),
                   stream);

    pack_w<<<dim3((S_M1  + 255) / 256), dim3(256), 0, stream>>>(m1_wsw, p1h, p1l, 128, 321, 11);
    pack_w<<<dim3((S_M23 + 255) / 256), dim3(256), 0, stream>>>(m2_wsw, p2h, p2l, 128, 144, 5);
    pack_w<<<dim3((S_M23 + 255) / 256), dim3(256), 0, stream>>>(m3_wsw, p3h, p3l, 128, 144, 5);
    pack_w<<<dim3((S_F1  + 255) / 256), dim3(256), 0, stream>>>(f1_wsw, pf1h, pf1l, 512, 160, 5);

    edge_kernel<<<dim3((E + 15) / 16), dim3(256), 0, stream>>>(
        s, v, eidx, es, ev,
        m1_wh, m1_wsb, m1_wv,
        m2_wh, m2_wsb, m2_wv,
        m3_wh, m3_wsb, m3_wv,
        p1h, p1l, p2h, p2l, p3h, p3l,
        agg_s, agg_v, cnt, E);

    node_kernel<<<dim3((N + 7) / 8), dim3(128), 0, stream>>>(
        s, v,
        f1_wh, f1_wsb, f1_wv,
        f2_wh, f2_wsw, f2_wsb, f2_wv,
        ln0_g, ln0_b, ln1_g, ln1_b,
        pf1h, pf1l,
        agg_s, agg_v, cnt,
        (float*)d_out, N);
}

// Round 5
// 1419.342 us; speedup vs baseline: 1.3746x; 1.1111x over previous
//
#include <hip/hip_runtime.h>

#define EPSF 1e-8f
constexpr int ED = 4;   // nodes per wave in layer_norm4

typedef __attribute__((ext_vector_type(8))) short short8;
typedef __attribute__((ext_vector_type(4))) short short4v;
typedef __attribute__((ext_vector_type(4))) float float4v;

// ---- fp32 -> bf16 hi/lo split (RNE) ---------------------------------------
__device__ __forceinline__ unsigned bfhi_bits(float x) {
    unsigned u = __float_as_uint(x);
    return (u + 0x7fffu + ((u >> 16) & 1u)) >> 16;
}
__device__ __forceinline__ float bits2f(unsigned b) { return __uint_as_float(b << 16); }
__device__ __forceinline__ void split_bf(float x, unsigned short& h, unsigned short& l) {
    unsigned hb = bfhi_bits(x);
    h = (unsigned short)hb;
    l = (unsigned short)bfhi_bits(x - bits2f(hb));
}

// ---------------------------------------------------------------------------
// Pack W[NO][K] fp32 (row-major) into MFMA B-fragment order, bf16 hi/lo.
// ---------------------------------------------------------------------------
__global__ void pack_w(const float* __restrict__ W, unsigned short* __restrict__ hi,
                       unsigned short* __restrict__ lo, int NO, int K, int steps) {
    const int gid = blockIdx.x * 256 + threadIdx.x;
    const int total = (NO >> 4) * steps * 512;
    if (gid >= total) return;
    const int j = gid & 7, l = (gid >> 3) & 63, rest = gid >> 9;
    const int t = rest % steps, nt = rest / steps;
    const int n = nt * 16 + (l & 15);
    const int k = t * 32 + ((l >> 4) << 3) + j;
    const float x = (k < K) ? W[(size_t)n * K + k] : 0.f;
    unsigned short h, lw;
    split_bf(x, h, lw);
    hi[gid] = h; lo[gid] = lw;
}

// pack m1 edge-part B: NO=128, K=96, steps=3.
// k<32 -> m1_wsw[n][128+k] (es); 32<=k<65 -> m1_wsw[n][288+k-32] (vn1); else 0.
__global__ void pack_m1e(const float* __restrict__ W, unsigned short* __restrict__ hi,
                         unsigned short* __restrict__ lo) {
    const int gid = blockIdx.x * 256 + threadIdx.x;
    if (gid >= 12288) return;
    const int j = gid & 7, l = (gid >> 3) & 63, rest = gid >> 9;
    const int t = rest % 3, nt = rest / 3;
    const int n = nt * 16 + (l & 15);
    const int k = t * 32 + ((l >> 4) << 3) + j;
    float x = 0.f;
    if (k < 32)      x = W[(size_t)n * 321 + 128 + k];
    else if (k < 65) x = W[(size_t)n * 321 + 288 + (k - 32)];
    unsigned short h, lw; split_bf(x, h, lw);
    hi[gid] = h; lo[gid] = lw;
}

// pack node-pre B: NO=256, K=128, steps=4.
// n<128 -> m1_wsw[n][k] (s_src part W1); n>=128 -> m1_wsw[n-128][160+k] (s_dst part W3).
__global__ void pack_m1n(const float* __restrict__ W, unsigned short* __restrict__ hi,
                         unsigned short* __restrict__ lo) {
    const int gid = blockIdx.x * 256 + threadIdx.x;
    if (gid >= 32768) return;
    const int j = gid & 7, l = (gid >> 3) & 63, rest = gid >> 9;
    const int t = rest & 3, nt = rest >> 2;
    const int n = nt * 16 + (l & 15);
    const int k = t * 32 + ((l >> 4) << 3) + j;
    const float x = (n < 128) ? W[(size_t)n * 321 + k]
                              : W[(size_t)(n - 128) * 321 + 160 + k];
    unsigned short h, lw; split_bf(x, h, lw);
    hi[gid] = h; lo[gid] = lw;
}

// ---------------------------------------------------------------------------
// 3-pass split-bf16 MFMA K-loop (validated).
// ---------------------------------------------------------------------------
template<int STEPS, int NTPW, int ASTR>
__device__ __forceinline__ void kloop(const unsigned short* PAh, const unsigned short* PAl,
    const unsigned short* __restrict__ wph, const unsigned short* __restrict__ wpl,
    float4v* acc, int lane, int wave)
{
    const int m = lane & 15, q = lane >> 4;
    for (int t = 0; t < STEPS; ++t) {
        const int k0 = t * 32 + q * 8;
        const short8 ah = *(const short8*)(PAh + m * ASTR + k0);
        const short8 al = *(const short8*)(PAl + m * ASTR + k0);
        #pragma unroll
        for (int i = 0; i < NTPW; ++i) {
            const int nt = wave * NTPW + i;
            const size_t off = ((size_t)(nt * STEPS + t) * 64 + lane) * 8;
            const short8 bh = *(const short8*)(wph + off);
            const short8 bl = *(const short8*)(wpl + off);
            acc[i] = __builtin_amdgcn_mfma_f32_16x16x32_bf16(ah, bh, acc[i], 0, 0, 0);
            acc[i] = __builtin_amdgcn_mfma_f32_16x16x32_bf16(al, bh, acc[i], 0, 0, 0);
            acc[i] = __builtin_amdgcn_mfma_f32_16x16x32_bf16(ah, bl, acc[i], 0, 0, 0);
        }
    }
}

// ===========================================================================
// node_pre: per-node precompute for the m1 GVP.
//   P[n][0:128]   = s[n] @ W1^T + m1_wsb   (W1 = m1_wsw cols 0..127)
//   P[n][128:256] = s[n] @ W3^T            (W3 = m1_wsw cols 160..287)
//   Q1[n][h*3+t]  = sum_c m1_wh[h][c]    * v[n][c][t]   (c 0..15)
//   Q3[n][h*3+t]  = sum_c m1_wh[h][17+c] * v[n][c][t]
// 16 nodes/block, 256 threads. P via 3-pass bf16 MFMA (same scheme the full
// m1 GEMM used); Q in exact fp32 (same as old E3 loop).
// ===========================================================================
constexpr int PAS = 136;   // A stride (shorts), K=128

__global__ __launch_bounds__(256)
void node_pre(const float* __restrict__ s, const float* __restrict__ v,
              const float* __restrict__ m1_wh, const float* __restrict__ m1_wsb,
              const unsigned short* __restrict__ pnh, const unsigned short* __restrict__ pnl,
              float* __restrict__ Pg, float* __restrict__ Q1g, float* __restrict__ Q3g,
              int N)
{
    __shared__ __align__(16) unsigned short Ah[16 * PAS], Al[16 * PAS];
    __shared__ __align__(16) float Vs[16 * 48];

    const int tid = threadIdx.x, lane = tid & 63, wave = tid >> 6;
    const int e = tid & 15, q16 = tid >> 4;
    const int n0 = blockIdx.x * 16;
    const int ne = min(n0 + e, N - 1);

    {   // stage s row (bf16 split) + v row (fp32)
        const float* sp = s + (size_t)ne * 128 + q16 * 8;
        const float4 x = ((const float4*)sp)[0];
        const float4 y = ((const float4*)sp)[1];
        short8 hv, lv; unsigned short h, l;
        split_bf(x.x, h, l); hv[0] = h; lv[0] = l;
        split_bf(x.y, h, l); hv[1] = h; lv[1] = l;
        split_bf(x.z, h, l); hv[2] = h; lv[2] = l;
        split_bf(x.w, h, l); hv[3] = h; lv[3] = l;
        split_bf(y.x, h, l); hv[4] = h; lv[4] = l;
        split_bf(y.y, h, l); hv[5] = h; lv[5] = l;
        split_bf(y.z, h, l); hv[6] = h; lv[6] = l;
        split_bf(y.w, h, l); hv[7] = h; lv[7] = l;
        *(short8*)(Ah + e * PAS + q16 * 8) = hv;
        *(short8*)(Al + e * PAS + q16 * 8) = lv;
    }
    if (q16 < 12)
        ((float4*)(Vs + e * 48))[q16] = ((const float4*)(v + (size_t)ne * 48))[q16];
    __syncthreads();

    {   // P: K=128 MFMA, NO=256 (4 tiles/wave)
        float4v acc[4] = {{0,0,0,0},{0,0,0,0},{0,0,0,0},{0,0,0,0}};
        kloop<4, 4, PAS>(Ah, Al, pnh, pnl, acc, lane, wave);
        const int q = lane >> 4;
        #pragma unroll
        for (int i = 0; i < 4; ++i) {
            const int j = (wave * 4 + i) * 16 + (lane & 15);
            const float bias = (j < 128) ? m1_wsb[j] : 0.f;
            #pragma unroll
            for (int r = 0; r < 4; ++r) {
                const int m = q * 4 + r;
                if (n0 + m < N) Pg[(size_t)(n0 + m) * 256 + j] = acc[i][r] + bias;
            }
        }
    }
    // Q: 16 nodes x 99 (h,t) tasks
    #pragma unroll
    for (int k = 0; k < 7; ++k) {
        const int idx = tid + k * 256;
        if (idx < 16 * 99) {
            const int n = idx & 15, j = idx >> 4;
            const int h = j / 3, t = j - h * 3;
            const float* vb = Vs + n * 48 + t;
            const float* w = m1_wh + h * 33;
            float a1 = 0.f, a3 = 0.f;
            for (int c = 0; c < 16; ++c) {
                const float vv = vb[c * 3];
                a1 = fmaf(w[c], vv, a1);
                a3 = fmaf(w[17 + c], vv, a3);
            }
            const int nn = n0 + n;
            if (nn < N) {
                Q1g[(size_t)nn * 100 + j] = a1;
                Q3g[(size_t)nn * 100 + j] = a3;
            }
        }
    }
}

// ---------------------------------------------------------------------------
// Edge kernel: 16 edges / block, 256 threads (4 waves).
// m1's s-part comes precomputed (P gather-add -> SP), vh1 from Q gather-add.
// m1 MFMA runs only over [es(32) | vn1(33) | pad] = K=96.
// A buffer stride 168 shorts (336 B; m*20 mod 32 banking) shared by m1 (cols
// 0..95) and m3 (cols 0..159, written by m2 epilogue + E9).
// LDS = 39.9 KB -> 4 blocks/CU. fp64-atomic aggregation (deterministic).
// ---------------------------------------------------------------------------
constexpr int SA2 = 168;   // A stride (shorts)
constexpr int SBs = 168;   // PB stride (shorts)
constexpr int SB1 = 100;   // B1 stride (f32)
constexpr int SB2 = 52;    // B2 stride (f32)
constexpr int SPS = 132;   // SP stride (f32)

__global__ __launch_bounds__(256)
void edge_kernel(const int* __restrict__ eidx,
                 const float* __restrict__ es, const float* __restrict__ ev,
                 const float* __restrict__ m1_wh, const float* __restrict__ m1_wv,
                 const float* __restrict__ m2_wh, const float* __restrict__ m2_wsb,
                 const float* __restrict__ m2_wv,
                 const float* __restrict__ m3_wh, const float* __restrict__ m3_wsb,
                 const float* __restrict__ m3_wv,
                 const unsigned short* __restrict__ p1h, const unsigned short* __restrict__ p1l,
                 const unsigned short* __restrict__ p2h, const unsigned short* __restrict__ p2l,
                 const unsigned short* __restrict__ p3h, const unsigned short* __restrict__ p3l,
                 const float* __restrict__ Pg, const float* __restrict__ Q1g,
                 const float* __restrict__ Q3g,
                 double* __restrict__ agg_s, double* __restrict__ agg_v,
                 float* __restrict__ cnt, int E)
{
    __shared__ __align__(16) unsigned short Ah[16 * SA2], Al[16 * SA2];
    __shared__ __align__(16) unsigned short PBmem[2 * 16 * SBs];
    __shared__ __align__(16) float SP[16 * SPS];
    __shared__ __align__(16) float B1[16 * SB1];
    __shared__ __align__(16) float B2[16 * SB2];
    __shared__ int ssrc[16], sgd[16], sdst[16], seid[16];

    unsigned short* PBh = PBmem;
    unsigned short* PBl = PBmem + 16 * SBs;

    const int tid = threadIdx.x, lane = tid & 63, wave = tid >> 6;
    const int e = tid & 15, q16 = tid >> 4;
    const int e0 = blockIdx.x * 16;

    // E1: indices
    if (tid < 16) {
        const int eg = e0 + tid;
        const bool ok = (eg < E);
        const int ee = ok ? eg : (E - 1);
        seid[tid] = ee;
        ssrc[tid] = eidx[ee];
        const int d = eidx[E + ee];
        sgd[tid] = d;
        sdst[tid] = ok ? d : -1;
    }
    __syncthreads();

    // E2: es -> A cols[0,32) bf16; zero pad [65,96); SP = P1[src]+P3[dst];
    //     vh1 = Q1[src]+Q3[dst]+wh16*ev -> B1, vn1 -> A cols[32,65)
    if (q16 < 8) {
        const float4 x = ((const float4*)(es + (size_t)seid[e] * 32))[q16];
        short4v hv, lv; unsigned short h, l;
        split_bf(x.x, h, l); hv[0] = h; lv[0] = l;
        split_bf(x.y, h, l); hv[1] = h; lv[1] = l;
        split_bf(x.z, h, l); hv[2] = h; lv[2] = l;
        split_bf(x.w, h, l); hv[3] = h; lv[3] = l;
        *(short4v*)(Ah + e * SA2 + 4 * q16) = hv;
        *(short4v*)(Al + e * SA2 + 4 * q16) = lv;
    }
    { const int c = 65 + q16; Ah[e * SA2 + c] = 0; Al[e * SA2 + c] = 0; }
    { const int c = 81 + q16; if (c < 96) { Ah[e * SA2 + c] = 0; Al[e * SA2 + c] = 0; } }
    {
        const float* P1 = Pg + (size_t)ssrc[e] * 256;
        const float* P3 = Pg + (size_t)sgd[e] * 256 + 128;
        const float4 a0 = ((const float4*)P1)[2 * q16];
        const float4 a1 = ((const float4*)P1)[2 * q16 + 1];
        const float4 b0 = ((const float4*)P3)[2 * q16];
        const float4 b1 = ((const float4*)P3)[2 * q16 + 1];
        float4 r0, r1;
        r0.x = a0.x + b0.x; r0.y = a0.y + b0.y; r0.z = a0.z + b0.z; r0.w = a0.w + b0.w;
        r1.x = a1.x + b1.x; r1.y = a1.y + b1.y; r1.z = a1.z + b1.z; r1.w = a1.w + b1.w;
        float4* o = (float4*)(SP + e * SPS + 8 * q16);
        o[0] = r0; o[1] = r1;
    }
    #pragma unroll
    for (int k = 0; k < 3; ++k) {
        const int idx = tid + k * 256;
        if (idx < 528) {
            const int h = idx >> 4, e2 = idx & 15;
            const float* q1 = Q1g + (size_t)ssrc[e2] * 100 + h * 3;
            const float* q3 = Q3g + (size_t)sgd[e2] * 100 + h * 3;
            const float* evp = ev + (size_t)seid[e2] * 3;
            const float w16 = m1_wh[h * 33 + 16];
            const float v0 = q1[0] + q3[0] + w16 * evp[0];
            const float v1 = q1[1] + q3[1] + w16 * evp[1];
            const float v2 = q1[2] + q3[2] + w16 * evp[2];
            float* o = B1 + e2 * SB1 + h * 3;
            o[0] = v0; o[1] = v1; o[2] = v2;
            const float vn = sqrtf(fmaxf(v0 * v0 + v1 * v1 + v2 * v2, EPSF));
            unsigned short hh, ll; split_bf(vn, hh, ll);
            Ah[e2 * SA2 + 32 + h] = hh; Al[e2 * SA2 + 32 + h] = ll;
        }
    }
    __syncthreads();

    // E5: m1 MFMA (K=96) + SP add -> relu -> PB[0,128); vout1 -> B2
    {
        float4v acc[2] = {{0,0,0,0},{0,0,0,0}};
        kloop<3, 2, SA2>(Ah, Al, p1h, p1l, acc, lane, wave);
        const int q = lane >> 4;
        #pragma unroll
        for (int i = 0; i < 2; ++i) {
            const int n = (wave * 2 + i) * 16 + (lane & 15);
            #pragma unroll
            for (int r = 0; r < 4; ++r) {
                const int m = q * 4 + r;
                const float x = fmaxf(acc[i][r] + SP[m * SPS + n], 0.f);
                unsigned short h, l; split_bf(x, h, l);
                PBh[m * SBs + n] = h; PBl[m * SBs + n] = l;
            }
        }
    }
    {   // vout1: o = q16 (VO=16)
        const int o = q16;
        float a0 = 0.f, a1 = 0.f, a2 = 0.f;
        for (int h = 0; h < 33; ++h) {
            const float w = m1_wv[o * 33 + h];
            const float* p = B1 + e * SB1 + h * 3;
            a0 = fmaf(p[0], w, a0); a1 = fmaf(p[1], w, a1); a2 = fmaf(p[2], w, a2);
        }
        const float nrm = sqrtf(fmaxf(a0 * a0 + a1 * a1 + a2 * a2, EPSF));
        const float sg = 1.f / (1.f + __expf(-nrm));
        float* p2 = B2 + e * SB2 + o * 3;
        p2[0] = a0 * sg; p2[1] = a1 * sg; p2[2] = a2 * sg;
    }
    __syncthreads();

    // E6+E7: vh2 -> B1; vn2 -> PB[128,144); zero PB[144,160)
    {
        const int h = q16;
        float a0 = 0.f, a1 = 0.f, a2 = 0.f;
        for (int c = 0; c < 16; ++c) {
            const float w = m2_wh[h * 16 + c];
            const float* p = B2 + e * SB2 + c * 3;
            a0 = fmaf(p[0], w, a0); a1 = fmaf(p[1], w, a1); a2 = fmaf(p[2], w, a2);
        }
        float* o = B1 + e * SB1 + h * 3;
        o[0] = a0; o[1] = a1; o[2] = a2;
        const float vn = sqrtf(fmaxf(a0 * a0 + a1 * a1 + a2 * a2, EPSF));
        unsigned short hh, ll; split_bf(vn, hh, ll);
        PBh[e * SBs + 128 + h] = hh; PBl[e * SBs + 128 + h] = ll;
        PBh[e * SBs + 144 + h] = 0;  PBl[e * SBs + 144 + h] = 0;
    }
    __syncthreads();

    // E8: m2 MFMA (K=160) -> relu -> A[0,128); vout2 -> B2
    {
        float4v acc[2] = {{0,0,0,0},{0,0,0,0}};
        kloop<5, 2, SBs>(PBh, PBl, p2h, p2l, acc, lane, wave);
        const int q = lane >> 4;
        #pragma unroll
        for (int i = 0; i < 2; ++i) {
            const int n = (wave * 2 + i) * 16 + (lane & 15);
            const float bias = m2_wsb[n];
            #pragma unroll
            for (int r = 0; r < 4; ++r) {
                const int m = q * 4 + r;
                const float x = fmaxf(acc[i][r] + bias, 0.f);
                unsigned short h, l; split_bf(x, h, l);
                Ah[m * SA2 + n] = h; Al[m * SA2 + n] = l;
            }
        }
    }
    {   // vout2
        const int o = q16;
        float a0 = 0.f, a1 = 0.f, a2 = 0.f;
        for (int h = 0; h < 16; ++h) {
            const float w = m2_wv[o * 16 + h];
            const float* p = B1 + e * SB1 + h * 3;
            a0 = fmaf(p[0], w, a0); a1 = fmaf(p[1], w, a1); a2 = fmaf(p[2], w, a2);
        }
        const float nrm = sqrtf(fmaxf(a0 * a0 + a1 * a1 + a2 * a2, EPSF));
        const float sg = 1.f / (1.f + __expf(-nrm));
        float* p2 = B2 + e * SB2 + o * 3;
        p2[0] = a0 * sg; p2[1] = a1 * sg; p2[2] = a2 * sg;
    }
    __syncthreads();

    // E9+E10: vh3 -> B1; vn3 -> A[128,144); zero A[144,160)
    {
        const int h = q16;
        float a0 = 0.f, a1 = 0.f, a2 = 0.f;
        for (int c = 0; c < 16; ++c) {
            const float w = m3_wh[h * 16 + c];
            const float* p = B2 + e * SB2 + c * 3;
            a0 = fmaf(p[0], w, a0); a1 = fmaf(p[1], w, a1); a2 = fmaf(p[2], w, a2);
        }
        float* o = B1 + e * SB1 + h * 3;
        o[0] = a0; o[1] = a1; o[2] = a2;
        const float vn = sqrtf(fmaxf(a0 * a0 + a1 * a1 + a2 * a2, EPSF));
        unsigned short hh, ll; split_bf(vn, hh, ll);
        Ah[e * SA2 + 128 + h] = hh; Al[e * SA2 + 128 + h] = ll;
        Ah[e * SA2 + 144 + h] = 0;  Al[e * SA2 + 144 + h] = 0;
    }
    __syncthreads();

    // E11: m3 MFMA (K=160, no act) + vout3 -> B2
    float4v acc3[2] = {{0,0,0,0},{0,0,0,0}};
    kloop<5, 2, SA2>(Ah, Al, p3h, p3l, acc3, lane, wave);
    {
        const int o = q16;
        float a0 = 0.f, a1 = 0.f, a2 = 0.f;
        for (int h = 0; h < 16; ++h) {
            const float w = m3_wv[o * 16 + h];
            const float* p = B1 + e * SB1 + h * 3;
            a0 = fmaf(p[0], w, a0); a1 = fmaf(p[1], w, a1); a2 = fmaf(p[2], w, a2);
        }
        float* p2 = B2 + e * SB2 + o * 3;
        p2[0] = a0; p2[1] = a1; p2[2] = a2;
    }
    __syncthreads();

    // E12: scatter-add (fp64 atomics -> order-invariant)
    {
        const int q = lane >> 4;
        #pragma unroll
        for (int i = 0; i < 2; ++i) {
            const int n = (wave * 2 + i) * 16 + (lane & 15);
            const float bias = m3_wsb[n];
            #pragma unroll
            for (int r = 0; r < 4; ++r) {
                const int m = q * 4 + r;
                const int d = sdst[m];
                if (d >= 0) atomicAdd(&agg_s[(size_t)d * 128 + n], (double)(acc3[i][r] + bias));
            }
        }
    }
    #pragma unroll
    for (int it = 0; it < 3; ++it) {
        const int j = q16 + 16 * it;
        const int d = sdst[e];
        if (d >= 0) atomicAdd(&agg_v[(size_t)d * 48 + j], (double)B2[e * SB2 + j]);
    }
    if (tid < 16 && sdst[tid] >= 0) atomicAdd(&cnt[sdst[tid]], 1.0f);
}

// ===========================================================================
// layer_norm4 (proven, verbatim)
// ===========================================================================
template<int SSTR, int VSTR>
__device__ __forceinline__ void layer_norm4(float* S, float* V,
    const float* __restrict__ g, const float* __restrict__ b, float* red, int lane)
{
    #pragma unroll
    for (int e = 0; e < ED; ++e) {
        float x0 = S[e * SSTR + lane], x1 = S[e * SSTR + 64 + lane];
        float sum = x0 + x1;
        #pragma unroll
        for (int off = 32; off > 0; off >>= 1) sum += __shfl_xor(sum, off, 64);
        const float mu = sum * (1.f / 128.f);
        const float d0 = x0 - mu, d1 = x1 - mu;
        float vs = d0 * d0 + d1 * d1;
        #pragma unroll
        for (int off = 32; off > 0; off >>= 1) vs += __shfl_xor(vs, off, 64);
        const float rstd = rsqrtf(vs * (1.f / 128.f) + 1e-5f);
        S[e * SSTR + lane]      = d0 * rstd * g[lane]      + b[lane];
        S[e * SSTR + 64 + lane] = d1 * rstd * g[lane + 64] + b[lane + 64];

        if (lane < 16) {
            const float a = V[e * VSTR + lane * 3], bb = V[e * VSTR + lane * 3 + 1],
                        cc = V[e * VSTR + lane * 3 + 2];
            const float vn = fmaxf(a * a + bb * bb + cc * cc, EPSF);
            red[lane]      = vn;
            red[16 + lane] = (vn > 2.f * EPSF) ? 1.f : 0.f;
        }
        __syncthreads();
        float sn = 0.f, sm = 0.f;
        #pragma unroll
        for (int i = 0; i < 16; ++i) { sn += red[i] * red[16 + i]; sm += red[16 + i]; }
        const float rvm = rsqrtf(sn / (EPSF + sm) + EPSF);
        if (lane < 48) V[e * VSTR + lane] = red[16 + lane / 3] * V[e * VSTR + lane] * rvm;
        __syncthreads();
    }
}

// ===========================================================================
// Node kernel (green in R4, verbatim): 8 nodes/block, 128 threads.
// f1 via 3-pass bf16 MFMA; f2 in exact fp32 (LN1-facing).
// ===========================================================================
constexpr int NNS  = 164;
constexpr int NNV  = 52;
constexpr int NNH  = 98;
constexpr int NA1n = 168;
constexpr int FSS  = 544;

__global__ __launch_bounds__(128)
void node_kernel(const float* __restrict__ s, const float* __restrict__ v,
                 const float* __restrict__ f1_wh, const float* __restrict__ f1_wsb,
                 const float* __restrict__ f1_wv,
                 const float* __restrict__ f2_wh, const float* __restrict__ f2_wsw,
                 const float* __restrict__ f2_wsb, const float* __restrict__ f2_wv,
                 const float* __restrict__ ln0_g, const float* __restrict__ ln0_b,
                 const float* __restrict__ ln1_g, const float* __restrict__ ln1_b,
                 const unsigned short* __restrict__ pf1h, const unsigned short* __restrict__ pf1l,
                 const double* __restrict__ agg_s, const double* __restrict__ agg_v,
                 const float* __restrict__ cnt,
                 float* __restrict__ out, int N)
{
    __shared__ __align__(16) unsigned short UBh[16 * NA1n], UBl[16 * NA1n];
    __shared__ __align__(16) float FS[8 * FSS];
    __shared__ __align__(16) float S1f[8 * NNS];
    __shared__ __align__(16) float V1f[8 * NNV];
    __shared__ __align__(16) float VH[8 * NNH];
    __shared__ __align__(16) float FV[8 * NNH];
    __shared__ float red[2 * 32];

    const int tid = threadIdx.x, lane = tid & 63, wave = tid >> 6;
    const int e = tid & 7, qq = tid >> 3;
    const int n0 = blockIdx.x * 8;

    bool oks[ED];
    #pragma unroll
    for (int e4 = 0; e4 < ED; ++e4) {
        const int idx = wave * 4 + e4;
        const int ng = n0 + idx;
        oks[e4] = (ng < N);
        const int n = oks[e4] ? ng : (N - 1);
        const double inv = 1.0 / (double)fmaxf(cnt[n], 1.f);
        if (lane < 32) {
            const float4 a = ((const float4*)(s + (size_t)n * 128))[lane];
            const double2 b0 = ((const double2*)(agg_s + (size_t)n * 128))[2 * lane];
            const double2 b1 = ((const double2*)(agg_s + (size_t)n * 128))[2 * lane + 1];
            float4 r;
            r.x = (float)((double)a.x + b0.x * inv);
            r.y = (float)((double)a.y + b0.y * inv);
            r.z = (float)((double)a.z + b1.x * inv);
            r.w = (float)((double)a.w + b1.y * inv);
            ((float4*)(S1f + idx * NNS))[lane] = r;
        }
        if (lane < 12) {
            const float4 a = ((const float4*)(v + (size_t)n * 48))[lane];
            const double2 b0 = ((const double2*)(agg_v + (size_t)n * 48))[2 * lane];
            const double2 b1 = ((const double2*)(agg_v + (size_t)n * 48))[2 * lane + 1];
            float4 r;
            r.x = (float)((double)a.x + b0.x * inv);
            r.y = (float)((double)a.y + b0.y * inv);
            r.z = (float)((double)a.z + b1.x * inv);
            r.w = (float)((double)a.w + b1.y * inv);
            ((float4*)(V1f + idx * NNV))[lane] = r;
        }
    }
    __syncthreads();

    layer_norm4<NNS, NNV>(S1f + wave * 4 * NNS, V1f + wave * 4 * NNV,
                          ln0_g, ln0_b, red + wave * 32, lane);

    {
        const float* sp = S1f + e * NNS + qq * 8;
        short8 hv, lv; unsigned short h, l;
        #pragma unroll
        for (int j = 0; j < 8; ++j) { split_bf(sp[j], h, l); hv[j] = h; lv[j] = l; }
        *(short8*)(UBh + e * NA1n + qq * 8) = hv;
        *(short8*)(UBl + e * NA1n + qq * 8) = lv;
    }
    #pragma unroll
    for (int hi = 0; hi < 2; ++hi) {
        const int h = qq + 16 * hi;
        const float* w = f1_wh + h * 16;
        const float* vb = V1f + e * NNV;
        float a0 = 0.f, a1 = 0.f, a2 = 0.f;
        for (int c = 0; c < 16; ++c) {
            const float wc = w[c];
            a0 = fmaf(vb[c * 3 + 0], wc, a0);
            a1 = fmaf(vb[c * 3 + 1], wc, a1);
            a2 = fmaf(vb[c * 3 + 2], wc, a2);
        }
        float* o = VH + e * NNH + h * 3;
        o[0] = a0; o[1] = a1; o[2] = a2;
        const float vn = sqrtf(fmaxf(a0 * a0 + a1 * a1 + a2 * a2, EPSF));
        unsigned short hh, ll; split_bf(vn, hh, ll);
        UBh[e * NA1n + 128 + h] = hh; UBl[e * NA1n + 128 + h] = ll;
    }
    __syncthreads();

    {
        float4v acc1[16];
        #pragma unroll
        for (int i = 0; i < 16; ++i) acc1[i] = (float4v){0.f, 0.f, 0.f, 0.f};
        kloop<5, 16, NA1n>(UBh, UBl, pf1h, pf1l, acc1, lane, wave);
        const int q = lane >> 4;
        #pragma unroll
        for (int i = 0; i < 16; ++i) {
            const int n = (wave * 16 + i) * 16 + (lane & 15);
            const float bias = f1_wsb[n];
            #pragma unroll
            for (int r = 0; r < 4; ++r) {
                const int m = q * 4 + r;
                if (m < 8) FS[m * FSS + n] = fmaxf(acc1[i][r] + bias, 0.f);
            }
        }
    }
    #pragma unroll
    for (int oi = 0; oi < 2; ++oi) {
        const int o = qq + 16 * oi;
        const float* w = f1_wv + o * 32;
        float a0 = 0.f, a1 = 0.f, a2 = 0.f;
        for (int h = 0; h < 32; ++h) {
            const float wc = w[h];
            const float* p = VH + e * NNH + h * 3;
            a0 = fmaf(p[0], wc, a0); a1 = fmaf(p[1], wc, a1); a2 = fmaf(p[2], wc, a2);
        }
        const float nrm = sqrtf(fmaxf(a0 * a0 + a1 * a1 + a2 * a2, EPSF));
        const float sg = 1.f / (1.f + __expf(-nrm));
        float* p2 = FV + e * NNH + o * 3;
        p2[0] = a0 * sg; p2[1] = a1 * sg; p2[2] = a2 * sg;
    }
    __syncthreads();

    #pragma unroll
    for (int hi = 0; hi < 2; ++hi) {
        const int h = qq + 16 * hi;
        const float* w = f2_wh + h * 32;
        float a0 = 0.f, a1 = 0.f, a2 = 0.f;
        for (int c = 0; c < 32; ++c) {
            const float wc = w[c];
            const float* p = FV + e * NNH + c * 3;
            a0 = fmaf(p[0], wc, a0); a1 = fmaf(p[1], wc, a1); a2 = fmaf(p[2], wc, a2);
        }
        float* o = VH + e * NNH + h * 3;
        o[0] = a0; o[1] = a1; o[2] = a2;
        FS[e * FSS + 512 + h] = sqrtf(fmaxf(a0 * a0 + a1 * a1 + a2 * a2, EPSF));
    }
    __syncthreads();

    {
        float acc[2][4];
        #pragma unroll
        for (int of = 0; of < 2; ++of) {
            const float bias = f2_wsb[lane + of * 64];
            #pragma unroll
            for (int e4 = 0; e4 < 4; ++e4) acc[of][e4] = bias;
        }
        for (int k = 0; k < FSS; k += 4) {
            float4 sv[4];
            #pragma unroll
            for (int e4 = 0; e4 < 4; ++e4)
                sv[e4] = *(const float4*)&FS[(wave * 4 + e4) * FSS + k];
            #pragma unroll
            for (int of = 0; of < 2; ++of) {
                const float4 w = *(const float4*)&f2_wsw[(size_t)(lane + of * 64) * 544 + k];
                #pragma unroll
                for (int e4 = 0; e4 < 4; ++e4) {
                    acc[of][e4] = fmaf(w.x, sv[e4].x, acc[of][e4]);
                    acc[of][e4] = fmaf(w.y, sv[e4].y, acc[of][e4]);
                    acc[of][e4] = fmaf(w.z, sv[e4].z, acc[of][e4]);
                    acc[of][e4] = fmaf(w.w, sv[e4].w, acc[of][e4]);
                }
            }
        }
        #pragma unroll
        for (int of = 0; of < 2; ++of)
            #pragma unroll
            for (int e4 = 0; e4 < 4; ++e4)
                S1f[(wave * 4 + e4) * NNS + lane + of * 64] += acc[of][e4];
    }
    {
        const int o = qq;
        const float* w = f2_wv + o * 32;
        float a0 = 0.f, a1 = 0.f, a2 = 0.f;
        for (int h = 0; h < 32; ++h) {
            const float wc = w[h];
            const float* p = VH + e * NNH + h * 3;
            a0 = fmaf(p[0], wc, a0); a1 = fmaf(p[1], wc, a1); a2 = fmaf(p[2], wc, a2);
        }
        float* p2 = V1f + e * NNV + o * 3;
        p2[0] += a0; p2[1] += a1; p2[2] += a2;
    }
    __syncthreads();

    layer_norm4<NNS, NNV>(S1f + wave * 4 * NNS, V1f + wave * 4 * NNV,
                          ln1_g, ln1_b, red + wave * 32, lane);

    #pragma unroll
    for (int e4 = 0; e4 < ED; ++e4) {
        if (!oks[e4]) continue;
        const int idx = wave * 4 + e4;
        const int n = n0 + idx;
        if (lane < 32)
            ((float4*)(out + (size_t)n * 128))[lane] = ((const float4*)(S1f + idx * NNS))[lane];
        if (lane < 12)
            ((float4*)(out + (size_t)N * 128 + (size_t)n * 48))[lane] =
                ((const float4*)(V1f + idx * NNV))[lane];
    }
}

// ---------------------------------------------------------------------------
extern "C" void kernel_launch(void* const* d_in, const int* in_sizes, int n_in,
                              void* d_out, int out_size, void* d_ws, size_t ws_size,
                              hipStream_t stream)
{
    const float* s    = (const float*)d_in[0];
    const float* v    = (const float*)d_in[1];
    const int*   eidx = (const int*)d_in[2];
    const float* es   = (const float*)d_in[3];
    const float* ev   = (const float*)d_in[4];
    const float* m1_wh = (const float*)d_in[5];
    const float* m1_wsw = (const float*)d_in[6];
    const float* m1_wsb = (const float*)d_in[7];
    const float* m1_wv = (const float*)d_in[8];
    const float* m2_wh = (const float*)d_in[9];
    const float* m2_wsw = (const float*)d_in[10];
    const float* m2_wsb = (const float*)d_in[11];
    const float* m2_wv = (const float*)d_in[12];
    const float* m3_wh = (const float*)d_in[13];
    const float* m3_wsw = (const float*)d_in[14];
    const float* m3_wsb = (const float*)d_in[15];
    const float* m3_wv = (const float*)d_in[16];
    const float* f1_wh = (const float*)d_in[17];
    const float* f1_wsw = (const float*)d_in[18];
    const float* f1_wsb = (const float*)d_in[19];
    const float* f1_wv = (const float*)d_in[20];
    const float* f2_wh = (const float*)d_in[21];
    const float* f2_wsw = (const float*)d_in[22];
    const float* f2_wsb = (const float*)d_in[23];
    const float* f2_wv = (const float*)d_in[24];
    const float* ln0_g = (const float*)d_in[25];
    const float* ln0_b = (const float*)d_in[26];
    const float* ln1_g = (const float*)d_in[27];
    const float* ln1_b = (const float*)d_in[28];

    const int N = in_sizes[0] / 128;
    const int E = in_sizes[2] / 2;

    double* agg_s = (double*)d_ws;                     // N*128 f64
    double* agg_v = agg_s + (size_t)N * 128;           // N*48  f64
    float* cnt    = (float*)(agg_v + (size_t)N * 48);  // N     f32
    unsigned short* pk =
        (unsigned short*)(((uintptr_t)(cnt + N) + 15) & ~(uintptr_t)15);
    const int S_P1E = 12288, S_M23 = 20480, S_MN = 32768, S_F1 = 81920;
    unsigned short* p1h = pk;            unsigned short* p1l = p1h + S_P1E;
    unsigned short* p2h = p1l + S_P1E;   unsigned short* p2l = p2h + S_M23;
    unsigned short* p3h = p2l + S_M23;   unsigned short* p3l = p3h + S_M23;
    unsigned short* pnh = p3l + S_M23;   unsigned short* pnl = pnh + S_MN;
    unsigned short* pf1h = pnl + S_MN;   unsigned short* pf1l = pf1h + S_F1;
    float* Pg  = (float*)(((uintptr_t)(pf1l + S_F1) + 15) & ~(uintptr_t)15);
    float* Q1g = Pg + (size_t)N * 256;
    float* Q3g = Q1g + (size_t)N * 100;

    hipMemsetAsync(d_ws, 0,
                   (size_t)N * 176 * sizeof(double) + (size_t)N * sizeof(float),
                   stream);

    pack_m1e<<<dim3((12288 + 255) / 256), dim3(256), 0, stream>>>(m1_wsw, p1h, p1l);
    pack_w<<<dim3((S_M23 + 255) / 256), dim3(256), 0, stream>>>(m2_wsw, p2h, p2l, 128, 144, 5);
    pack_w<<<dim3((S_M23 + 255) / 256), dim3(256), 0, stream>>>(m3_wsw, p3h, p3l, 128, 144, 5);
    pack_m1n<<<dim3((32768 + 255) / 256), dim3(256), 0, stream>>>(m1_wsw, pnh, pnl);
    pack_w<<<dim3((S_F1 + 255) / 256), dim3(256), 0, stream>>>(f1_wsw, pf1h, pf1l, 512, 160, 5);

    node_pre<<<dim3((N + 15) / 16), dim3(256), 0, stream>>>(
        s, v, m1_wh, m1_wsb, pnh, pnl, Pg, Q1g, Q3g, N);

    edge_kernel<<<dim3((E + 15) / 16), dim3(256), 0, stream>>>(
        eidx, es, ev,
        m1_wh, m1_wv,
        m2_wh, m2_wsb, m2_wv,
        m3_wh, m3_wsb, m3_wv,
        p1h, p1l, p2h, p2l, p3h, p3l,
        Pg, Q1g, Q3g,
        agg_s, agg_v, cnt, E);

    node_kernel<<<dim3((N + 7) / 8), dim3(128), 0, stream>>>(
        s, v,
        f1_wh, f1_wsb, f1_wv,
        f2_wh, f2_wsw, f2_wsb, f2_wv,
        ln0_g, ln0_b, ln1_g, ln1_b,
        pf1h, pf1l,
        agg_s, agg_v, cnt,
        (float*)d_out, N);
}

// Round 7
// 1417.439 us; speedup vs baseline: 1.3764x; 1.0013x over previous
//
#include <hip/hip_runtime.h>

#define EPSF 1e-8f

typedef __attribute__((ext_vector_type(8))) short short8;
typedef __attribute__((ext_vector_type(4))) short short4v;
typedef __attribute__((ext_vector_type(4))) float float4v;

// ---- fp32 -> bf16 hi/lo split (RNE) ---------------------------------------
__device__ __forceinline__ unsigned bfhi_bits(float x) {
    unsigned u = __float_as_uint(x);
    return (u + 0x7fffu + ((u >> 16) & 1u)) >> 16;
}
__device__ __forceinline__ float bits2f(unsigned b) { return __uint_as_float(b << 16); }
__device__ __forceinline__ void split_bf(float x, unsigned short& h, unsigned short& l) {
    unsigned hb = bfhi_bits(x);
    h = (unsigned short)hb;
    l = (unsigned short)bfhi_bits(x - bits2f(hb));
}

// ---------------------------------------------------------------------------
// Pack W[NO][K] fp32 (row-major) into MFMA B-fragment order, bf16 hi/lo.
// ---------------------------------------------------------------------------
__global__ void pack_w(const float* __restrict__ W, unsigned short* __restrict__ hi,
                       unsigned short* __restrict__ lo, int NO, int K, int steps) {
    const int gid = blockIdx.x * 256 + threadIdx.x;
    const int total = (NO >> 4) * steps * 512;
    if (gid >= total) return;
    const int j = gid & 7, l = (gid >> 3) & 63, rest = gid >> 9;
    const int t = rest % steps, nt = rest / steps;
    const int n = nt * 16 + (l & 15);
    const int k = t * 32 + ((l >> 4) << 3) + j;
    const float x = (k < K) ? W[(size_t)n * K + k] : 0.f;
    unsigned short h, lw;
    split_bf(x, h, lw);
    hi[gid] = h; lo[gid] = lw;
}

// pack m1 edge-part B: NO=128, K=96, steps=3.
__global__ void pack_m1e(const float* __restrict__ W, unsigned short* __restrict__ hi,
                         unsigned short* __restrict__ lo) {
    const int gid = blockIdx.x * 256 + threadIdx.x;
    if (gid >= 12288) return;
    const int j = gid & 7, l = (gid >> 3) & 63, rest = gid >> 9;
    const int t = rest % 3, nt = rest / 3;
    const int n = nt * 16 + (l & 15);
    const int k = t * 32 + ((l >> 4) << 3) + j;
    float x = 0.f;
    if (k < 32)      x = W[(size_t)n * 321 + 128 + k];
    else if (k < 65) x = W[(size_t)n * 321 + 288 + (k - 32)];
    unsigned short h, lw; split_bf(x, h, lw);
    hi[gid] = h; lo[gid] = lw;
}

// pack node-pre B: NO=256, K=128, steps=4.
__global__ void pack_m1n(const float* __restrict__ W, unsigned short* __restrict__ hi,
                         unsigned short* __restrict__ lo) {
    const int gid = blockIdx.x * 256 + threadIdx.x;
    if (gid >= 32768) return;
    const int j = gid & 7, l = (gid >> 3) & 63, rest = gid >> 9;
    const int t = rest & 3, nt = rest >> 2;
    const int n = nt * 16 + (l & 15);
    const int k = t * 32 + ((l >> 4) << 3) + j;
    const float x = (n < 128) ? W[(size_t)n * 321 + k]
                              : W[(size_t)(n - 128) * 321 + 160 + k];
    unsigned short h, lw; split_bf(x, h, lw);
    hi[gid] = h; lo[gid] = lw;
}

// ---------------------------------------------------------------------------
// 3-pass split-bf16 MFMA K-loop (validated).
// ---------------------------------------------------------------------------
template<int STEPS, int NTPW, int ASTR>
__device__ __forceinline__ void kloop(const unsigned short* PAh, const unsigned short* PAl,
    const unsigned short* __restrict__ wph, const unsigned short* __restrict__ wpl,
    float4v* acc, int lane, int wave)
{
    const int m = lane & 15, q = lane >> 4;
    for (int t = 0; t < STEPS; ++t) {
        const int k0 = t * 32 + q * 8;
        const short8 ah = *(const short8*)(PAh + m * ASTR + k0);
        const short8 al = *(const short8*)(PAl + m * ASTR + k0);
        #pragma unroll
        for (int i = 0; i < NTPW; ++i) {
            const int nt = wave * NTPW + i;
            const size_t off = ((size_t)(nt * STEPS + t) * 64 + lane) * 8;
            const short8 bh = *(const short8*)(wph + off);
            const short8 bl = *(const short8*)(wpl + off);
            acc[i] = __builtin_amdgcn_mfma_f32_16x16x32_bf16(ah, bh, acc[i], 0, 0, 0);
            acc[i] = __builtin_amdgcn_mfma_f32_16x16x32_bf16(al, bh, acc[i], 0, 0, 0);
            acc[i] = __builtin_amdgcn_mfma_f32_16x16x32_bf16(ah, bl, acc[i], 0, 0, 0);
        }
    }
}

// ===========================================================================
// node_pre (green in R5, verbatim)
// ===========================================================================
constexpr int PAS = 136;

__global__ __launch_bounds__(256)
void node_pre(const float* __restrict__ s, const float* __restrict__ v,
              const float* __restrict__ m1_wh, const float* __restrict__ m1_wsb,
              const unsigned short* __restrict__ pnh, const unsigned short* __restrict__ pnl,
              float* __restrict__ Pg, float* __restrict__ Q1g, float* __restrict__ Q3g,
              int N)
{
    __shared__ __align__(16) unsigned short Ah[16 * PAS], Al[16 * PAS];
    __shared__ __align__(16) float Vs[16 * 48];

    const int tid = threadIdx.x, lane = tid & 63, wave = tid >> 6;
    const int e = tid & 15, q16 = tid >> 4;
    const int n0 = blockIdx.x * 16;
    const int ne = min(n0 + e, N - 1);

    {
        const float* sp = s + (size_t)ne * 128 + q16 * 8;
        const float4 x = ((const float4*)sp)[0];
        const float4 y = ((const float4*)sp)[1];
        short8 hv, lv; unsigned short h, l;
        split_bf(x.x, h, l); hv[0] = h; lv[0] = l;
        split_bf(x.y, h, l); hv[1] = h; lv[1] = l;
        split_bf(x.z, h, l); hv[2] = h; lv[2] = l;
        split_bf(x.w, h, l); hv[3] = h; lv[3] = l;
        split_bf(y.x, h, l); hv[4] = h; lv[4] = l;
        split_bf(y.y, h, l); hv[5] = h; lv[5] = l;
        split_bf(y.z, h, l); hv[6] = h; lv[6] = l;
        split_bf(y.w, h, l); hv[7] = h; lv[7] = l;
        *(short8*)(Ah + e * PAS + q16 * 8) = hv;
        *(short8*)(Al + e * PAS + q16 * 8) = lv;
    }
    if (q16 < 12)
        ((float4*)(Vs + e * 48))[q16] = ((const float4*)(v + (size_t)ne * 48))[q16];
    __syncthreads();

    {
        float4v acc[4] = {{0,0,0,0},{0,0,0,0},{0,0,0,0},{0,0,0,0}};
        kloop<4, 4, PAS>(Ah, Al, pnh, pnl, acc, lane, wave);
        const int q = lane >> 4;
        #pragma unroll
        for (int i = 0; i < 4; ++i) {
            const int j = (wave * 4 + i) * 16 + (lane & 15);
            const float bias = (j < 128) ? m1_wsb[j] : 0.f;
            #pragma unroll
            for (int r = 0; r < 4; ++r) {
                const int m = q * 4 + r;
                if (n0 + m < N) Pg[(size_t)(n0 + m) * 256 + j] = acc[i][r] + bias;
            }
        }
    }
    #pragma unroll
    for (int k = 0; k < 7; ++k) {
        const int idx = tid + k * 256;
        if (idx < 16 * 99) {
            const int n = idx & 15, j = idx >> 4;
            const int h = j / 3, t = j - h * 3;
            const float* vb = Vs + n * 48 + t;
            const float* w = m1_wh + h * 33;
            float a1 = 0.f, a3 = 0.f;
            for (int c = 0; c < 16; ++c) {
                const float vv = vb[c * 3];
                a1 = fmaf(w[c], vv, a1);
                a3 = fmaf(w[17 + c], vv, a3);
            }
            const int nn = n0 + n;
            if (nn < N) {
                Q1g[(size_t)nn * 100 + j] = a1;
                Q3g[(size_t)nn * 100 + j] = a3;
            }
        }
    }
}

// ---------------------------------------------------------------------------
// Edge kernel (green in R5, verbatim): 16 edges / block, 256 threads.
// ---------------------------------------------------------------------------
constexpr int SA2 = 168;
constexpr int SBs = 168;
constexpr int SB1 = 100;
constexpr int SB2 = 52;
constexpr int SPS = 132;

__global__ __launch_bounds__(256)
void edge_kernel(const int* __restrict__ eidx,
                 const float* __restrict__ es, const float* __restrict__ ev,
                 const float* __restrict__ m1_wh, const float* __restrict__ m1_wv,
                 const float* __restrict__ m2_wh, const float* __restrict__ m2_wsb,
                 const float* __restrict__ m2_wv,
                 const float* __restrict__ m3_wh, const float* __restrict__ m3_wsb,
                 const float* __restrict__ m3_wv,
                 const unsigned short* __restrict__ p1h, const unsigned short* __restrict__ p1l,
                 const unsigned short* __restrict__ p2h, const unsigned short* __restrict__ p2l,
                 const unsigned short* __restrict__ p3h, const unsigned short* __restrict__ p3l,
                 const float* __restrict__ Pg, const float* __restrict__ Q1g,
                 const float* __restrict__ Q3g,
                 double* __restrict__ agg_s, double* __restrict__ agg_v,
                 float* __restrict__ cnt, int E)
{
    __shared__ __align__(16) unsigned short Ah[16 * SA2], Al[16 * SA2];
    __shared__ __align__(16) unsigned short PBmem[2 * 16 * SBs];
    __shared__ __align__(16) float SP[16 * SPS];
    __shared__ __align__(16) float B1[16 * SB1];
    __shared__ __align__(16) float B2[16 * SB2];
    __shared__ int ssrc[16], sgd[16], sdst[16], seid[16];

    unsigned short* PBh = PBmem;
    unsigned short* PBl = PBmem + 16 * SBs;

    const int tid = threadIdx.x, lane = tid & 63, wave = tid >> 6;
    const int e = tid & 15, q16 = tid >> 4;
    const int e0 = blockIdx.x * 16;

    if (tid < 16) {
        const int eg = e0 + tid;
        const bool ok = (eg < E);
        const int ee = ok ? eg : (E - 1);
        seid[tid] = ee;
        ssrc[tid] = eidx[ee];
        const int d = eidx[E + ee];
        sgd[tid] = d;
        sdst[tid] = ok ? d : -1;
    }
    __syncthreads();

    if (q16 < 8) {
        const float4 x = ((const float4*)(es + (size_t)seid[e] * 32))[q16];
        short4v hv, lv; unsigned short h, l;
        split_bf(x.x, h, l); hv[0] = h; lv[0] = l;
        split_bf(x.y, h, l); hv[1] = h; lv[1] = l;
        split_bf(x.z, h, l); hv[2] = h; lv[2] = l;
        split_bf(x.w, h, l); hv[3] = h; lv[3] = l;
        *(short4v*)(Ah + e * SA2 + 4 * q16) = hv;
        *(short4v*)(Al + e * SA2 + 4 * q16) = lv;
    }
    { const int c = 65 + q16; Ah[e * SA2 + c] = 0; Al[e * SA2 + c] = 0; }
    { const int c = 81 + q16; if (c < 96) { Ah[e * SA2 + c] = 0; Al[e * SA2 + c] = 0; } }
    {
        const float* P1 = Pg + (size_t)ssrc[e] * 256;
        const float* P3 = Pg + (size_t)sgd[e] * 256 + 128;
        const float4 a0 = ((const float4*)P1)[2 * q16];
        const float4 a1 = ((const float4*)P1)[2 * q16 + 1];
        const float4 b0 = ((const float4*)P3)[2 * q16];
        const float4 b1 = ((const float4*)P3)[2 * q16 + 1];
        float4 r0, r1;
        r0.x = a0.x + b0.x; r0.y = a0.y + b0.y; r0.z = a0.z + b0.z; r0.w = a0.w + b0.w;
        r1.x = a1.x + b1.x; r1.y = a1.y + b1.y; r1.z = a1.z + b1.z; r1.w = a1.w + b1.w;
        float4* o = (float4*)(SP + e * SPS + 8 * q16);
        o[0] = r0; o[1] = r1;
    }
    #pragma unroll
    for (int k = 0; k < 3; ++k) {
        const int idx = tid + k * 256;
        if (idx < 528) {
            const int h = idx >> 4, e2 = idx & 15;
            const float* q1 = Q1g + (size_t)ssrc[e2] * 100 + h * 3;
            const float* q3 = Q3g + (size_t)sgd[e2] * 100 + h * 3;
            const float* evp = ev + (size_t)seid[e2] * 3;
            const float w16 = m1_wh[h * 33 + 16];
            const float v0 = q1[0] + q3[0] + w16 * evp[0];
            const float v1 = q1[1] + q3[1] + w16 * evp[1];
            const float v2 = q1[2] + q3[2] + w16 * evp[2];
            float* o = B1 + e2 * SB1 + h * 3;
            o[0] = v0; o[1] = v1; o[2] = v2;
            const float vn = sqrtf(fmaxf(v0 * v0 + v1 * v1 + v2 * v2, EPSF));
            unsigned short hh, ll; split_bf(vn, hh, ll);
            Ah[e2 * SA2 + 32 + h] = hh; Al[e2 * SA2 + 32 + h] = ll;
        }
    }
    __syncthreads();

    {
        float4v acc[2] = {{0,0,0,0},{0,0,0,0}};
        kloop<3, 2, SA2>(Ah, Al, p1h, p1l, acc, lane, wave);
        const int q = lane >> 4;
        #pragma unroll
        for (int i = 0; i < 2; ++i) {
            const int n = (wave * 2 + i) * 16 + (lane & 15);
            #pragma unroll
            for (int r = 0; r < 4; ++r) {
                const int m = q * 4 + r;
                const float x = fmaxf(acc[i][r] + SP[m * SPS + n], 0.f);
                unsigned short h, l; split_bf(x, h, l);
                PBh[m * SBs + n] = h; PBl[m * SBs + n] = l;
            }
        }
    }
    {
        const int o = q16;
        float a0 = 0.f, a1 = 0.f, a2 = 0.f;
        for (int h = 0; h < 33; ++h) {
            const float w = m1_wv[o * 33 + h];
            const float* p = B1 + e * SB1 + h * 3;
            a0 = fmaf(p[0], w, a0); a1 = fmaf(p[1], w, a1); a2 = fmaf(p[2], w, a2);
        }
        const float nrm = sqrtf(fmaxf(a0 * a0 + a1 * a1 + a2 * a2, EPSF));
        const float sg = 1.f / (1.f + __expf(-nrm));
        float* p2 = B2 + e * SB2 + o * 3;
        p2[0] = a0 * sg; p2[1] = a1 * sg; p2[2] = a2 * sg;
    }
    __syncthreads();

    {
        const int h = q16;
        float a0 = 0.f, a1 = 0.f, a2 = 0.f;
        for (int c = 0; c < 16; ++c) {
            const float w = m2_wh[h * 16 + c];
            const float* p = B2 + e * SB2 + c * 3;
            a0 = fmaf(p[0], w, a0); a1 = fmaf(p[1], w, a1); a2 = fmaf(p[2], w, a2);
        }
        float* o = B1 + e * SB1 + h * 3;
        o[0] = a0; o[1] = a1; o[2] = a2;
        const float vn = sqrtf(fmaxf(a0 * a0 + a1 * a1 + a2 * a2, EPSF));
        unsigned short hh, ll; split_bf(vn, hh, ll);
        PBh[e * SBs + 128 + h] = hh; PBl[e * SBs + 128 + h] = ll;
        PBh[e * SBs + 144 + h] = 0;  PBl[e * SBs + 144 + h] = 0;
    }
    __syncthreads();

    {
        float4v acc[2] = {{0,0,0,0},{0,0,0,0}};
        kloop<5, 2, SBs>(PBh, PBl, p2h, p2l, acc, lane, wave);
        const int q = lane >> 4;
        #pragma unroll
        for (int i = 0; i < 2; ++i) {
            const int n = (wave * 2 + i) * 16 + (lane & 15);
            const float bias = m2_wsb[n];
            #pragma unroll
            for (int r = 0; r < 4; ++r) {
                const int m = q * 4 + r;
                const float x = fmaxf(acc[i][r] + bias, 0.f);
                unsigned short h, l; split_bf(x, h, l);
                Ah[m * SA2 + n] = h; Al[m * SA2 + n] = l;
            }
        }
    }
    {
        const int o = q16;
        float a0 = 0.f, a1 = 0.f, a2 = 0.f;
        for (int h = 0; h < 16; ++h) {
            const float w = m2_wv[o * 16 + h];
            const float* p = B1 + e * SB1 + h * 3;
            a0 = fmaf(p[0], w, a0); a1 = fmaf(p[1], w, a1); a2 = fmaf(p[2], w, a2);
        }
        const float nrm = sqrtf(fmaxf(a0 * a0 + a1 * a1 + a2 * a2, EPSF));
        const float sg = 1.f / (1.f + __expf(-nrm));
        float* p2 = B2 + e * SB2 + o * 3;
        p2[0] = a0 * sg; p2[1] = a1 * sg; p2[2] = a2 * sg;
    }
    __syncthreads();

    {
        const int h = q16;
        float a0 = 0.f, a1 = 0.f, a2 = 0.f;
        for (int c = 0; c < 16; ++c) {
            const float w = m3_wh[h * 16 + c];
            const float* p = B2 + e * SB2 + c * 3;
            a0 = fmaf(p[0], w, a0); a1 = fmaf(p[1], w, a1); a2 = fmaf(p[2], w, a2);
        }
        float* o = B1 + e * SB1 + h * 3;
        o[0] = a0; o[1] = a1; o[2] = a2;
        const float vn = sqrtf(fmaxf(a0 * a0 + a1 * a1 + a2 * a2, EPSF));
        unsigned short hh, ll; split_bf(vn, hh, ll);
        Ah[e * SA2 + 128 + h] = hh; Al[e * SA2 + 128 + h] = ll;
        Ah[e * SA2 + 144 + h] = 0;  Al[e * SA2 + 144 + h] = 0;
    }
    __syncthreads();

    float4v acc3[2] = {{0,0,0,0},{0,0,0,0}};
    kloop<5, 2, SA2>(Ah, Al, p3h, p3l, acc3, lane, wave);
    {
        const int o = q16;
        float a0 = 0.f, a1 = 0.f, a2 = 0.f;
        for (int h = 0; h < 16; ++h) {
            const float w = m3_wv[o * 16 + h];
            const float* p = B1 + e * SB1 + h * 3;
            a0 = fmaf(p[0], w, a0); a1 = fmaf(p[1], w, a1); a2 = fmaf(p[2], w, a2);
        }
        float* p2 = B2 + e * SB2 + o * 3;
        p2[0] = a0; p2[1] = a1; p2[2] = a2;
    }
    __syncthreads();

    {
        const int q = lane >> 4;
        #pragma unroll
        for (int i = 0; i < 2; ++i) {
            const int n = (wave * 2 + i) * 16 + (lane & 15);
            const float bias = m3_wsb[n];
            #pragma unroll
            for (int r = 0; r < 4; ++r) {
                const int m = q * 4 + r;
                const int d = sdst[m];
                if (d >= 0) atomicAdd(&agg_s[(size_t)d * 128 + n], (double)(acc3[i][r] + bias));
            }
        }
    }
    #pragma unroll
    for (int it = 0; it < 3; ++it) {
        const int j = q16 + 16 * it;
        const int d = sdst[e];
        if (d >= 0) atomicAdd(&agg_v[(size_t)d * 48 + j], (double)B2[e * SB2 + j]);
    }
    if (tid < 16 && sdst[tid] >= 0) atomicAdd(&cnt[sdst[tid]], 1.0f);
}

// ===========================================================================
// layer_normT: wave processes NE nodes (proven math, verbatim per node)
// ===========================================================================
template<int NE, int SSTR, int VSTR>
__device__ __forceinline__ void layer_normT(float* S, float* V,
    const float* __restrict__ g, const float* __restrict__ b, float* red, int lane)
{
    #pragma unroll
    for (int e = 0; e < NE; ++e) {
        float x0 = S[e * SSTR + lane], x1 = S[e * SSTR + 64 + lane];
        float sum = x0 + x1;
        #pragma unroll
        for (int off = 32; off > 0; off >>= 1) sum += __shfl_xor(sum, off, 64);
        const float mu = sum * (1.f / 128.f);
        const float d0 = x0 - mu, d1 = x1 - mu;
        float vs = d0 * d0 + d1 * d1;
        #pragma unroll
        for (int off = 32; off > 0; off >>= 1) vs += __shfl_xor(vs, off, 64);
        const float rstd = rsqrtf(vs * (1.f / 128.f) + 1e-5f);
        S[e * SSTR + lane]      = d0 * rstd * g[lane]      + b[lane];
        S[e * SSTR + 64 + lane] = d1 * rstd * g[lane + 64] + b[lane + 64];

        if (lane < 16) {
            const float a = V[e * VSTR + lane * 3], bb = V[e * VSTR + lane * 3 + 1],
                        cc = V[e * VSTR + lane * 3 + 2];
            const float vn = fmaxf(a * a + bb * bb + cc * cc, EPSF);
            red[lane]      = vn;
            red[16 + lane] = (vn > 2.f * EPSF) ? 1.f : 0.f;
        }
        __syncthreads();
        float sn = 0.f, sm = 0.f;
        #pragma unroll
        for (int i = 0; i < 16; ++i) { sn += red[i] * red[16 + i]; sm += red[16 + i]; }
        const float rvm = rsqrtf(sn / (EPSF + sm) + EPSF);
        if (lane < 48) V[e * VSTR + lane] = red[16 + lane / 3] * V[e * VSTR + lane] * rvm;
        __syncthreads();
    }
}

// ===========================================================================
// Node kernel (R4/R5-green structure, 8 nodes/block, 128 threads, 2 waves).
// Only changes vs green: UBh/UBl shrunk 16->8 rows (rows 8-15 were NEVER
// written -- MFMA rows m>=8 consumed garbage and were discarded before and
// still are; reads land inside the block's LDS either way) and S1f stride
// 164->132. LDS 41600 -> 35200 B => 4 blocks/CU (was 3), 8 waves/CU.
// ===========================================================================
constexpr int NNS  = 132;  // S1f stride (f32)
constexpr int NNV  = 52;   // V1f stride (f32)
constexpr int NNH  = 98;   // VH/FV stride (f32)
constexpr int NA1n = 168;  // f1 A stride (shorts), K=160
constexpr int FSS  = 544;  // FS stride (f32): [relu(fs1) 512 | vn2 32]

__global__ __launch_bounds__(128)
void node_kernel(const float* __restrict__ s, const float* __restrict__ v,
                 const float* __restrict__ f1_wh, const float* __restrict__ f1_wsb,
                 const float* __restrict__ f1_wv,
                 const float* __restrict__ f2_wh, const float* __restrict__ f2_wsw,
                 const float* __restrict__ f2_wsb, const float* __restrict__ f2_wv,
                 const float* __restrict__ ln0_g, const float* __restrict__ ln0_b,
                 const float* __restrict__ ln1_g, const float* __restrict__ ln1_b,
                 const unsigned short* __restrict__ pf1h, const unsigned short* __restrict__ pf1l,
                 const double* __restrict__ agg_s, const double* __restrict__ agg_v,
                 const float* __restrict__ cnt,
                 float* __restrict__ out, int N)
{
    __shared__ __align__(16) unsigned short UBh[8 * NA1n], UBl[8 * NA1n];
    __shared__ __align__(16) float FS[8 * FSS];
    __shared__ __align__(16) float S1f[8 * NNS];
    __shared__ __align__(16) float V1f[8 * NNV];
    __shared__ __align__(16) float VH[8 * NNH];
    __shared__ __align__(16) float FV[8 * NNH];
    __shared__ float red[2 * 32];

    const int tid = threadIdx.x, lane = tid & 63, wave = tid >> 6;
    const int e = tid & 7, qq = tid >> 3;    // e: node 0-7, qq: 0-15
    const int n0 = blockIdx.x * 8;

    bool oks[4];
    #pragma unroll
    for (int e4 = 0; e4 < 4; ++e4) {
        const int idx = wave * 4 + e4;
        const int ng = n0 + idx;
        oks[e4] = (ng < N);
        const int n = oks[e4] ? ng : (N - 1);
        const double inv = 1.0 / (double)fmaxf(cnt[n], 1.f);
        if (lane < 32) {
            const float4 a = ((const float4*)(s + (size_t)n * 128))[lane];
            const double2 b0 = ((const double2*)(agg_s + (size_t)n * 128))[2 * lane];
            const double2 b1 = ((const double2*)(agg_s + (size_t)n * 128))[2 * lane + 1];
            float4 r;
            r.x = (float)((double)a.x + b0.x * inv);
            r.y = (float)((double)a.y + b0.y * inv);
            r.z = (float)((double)a.z + b1.x * inv);
            r.w = (float)((double)a.w + b1.y * inv);
            ((float4*)(S1f + idx * NNS))[lane] = r;
        }
        if (lane < 12) {
            const float4 a = ((const float4*)(v + (size_t)n * 48))[lane];
            const double2 b0 = ((const double2*)(agg_v + (size_t)n * 48))[2 * lane];
            const double2 b1 = ((const double2*)(agg_v + (size_t)n * 48))[2 * lane + 1];
            float4 r;
            r.x = (float)((double)a.x + b0.x * inv);
            r.y = (float)((double)a.y + b0.y * inv);
            r.z = (float)((double)a.z + b1.x * inv);
            r.w = (float)((double)a.w + b1.y * inv);
            ((float4*)(V1f + idx * NNV))[lane] = r;
        }
    }
    __syncthreads();

    layer_normT<4, NNS, NNV>(S1f + wave * 4 * NNS, V1f + wave * 4 * NNV,
                             ln0_g, ln0_b, red + wave * 32, lane);

    {
        const float* sp = S1f + e * NNS + qq * 8;
        short8 hv, lv; unsigned short h, l;
        #pragma unroll
        for (int j = 0; j < 8; ++j) { split_bf(sp[j], h, l); hv[j] = h; lv[j] = l; }
        *(short8*)(UBh + e * NA1n + qq * 8) = hv;
        *(short8*)(UBl + e * NA1n + qq * 8) = lv;
    }
    #pragma unroll
    for (int hi = 0; hi < 2; ++hi) {
        const int h = qq + 16 * hi;
        const float* w = f1_wh + h * 16;
        const float* vb = V1f + e * NNV;
        float a0 = 0.f, a1 = 0.f, a2 = 0.f;
        for (int c = 0; c < 16; ++c) {
            const float wc = w[c];
            a0 = fmaf(vb[c * 3 + 0], wc, a0);
            a1 = fmaf(vb[c * 3 + 1], wc, a1);
            a2 = fmaf(vb[c * 3 + 2], wc, a2);
        }
        float* o = VH + e * NNH + h * 3;
        o[0] = a0; o[1] = a1; o[2] = a2;
        const float vn = sqrtf(fmaxf(a0 * a0 + a1 * a1 + a2 * a2, EPSF));
        unsigned short hh, ll; split_bf(vn, hh, ll);
        UBh[e * NA1n + 128 + h] = hh; UBl[e * NA1n + 128 + h] = ll;
    }
    __syncthreads();

    {
        float4v acc1[16];
        #pragma unroll
        for (int i = 0; i < 16; ++i) acc1[i] = (float4v){0.f, 0.f, 0.f, 0.f};
        kloop<5, 16, NA1n>(UBh, UBl, pf1h, pf1l, acc1, lane, wave);
        const int q = lane >> 4;
        #pragma unroll
        for (int i = 0; i < 16; ++i) {
            const int n = (wave * 16 + i) * 16 + (lane & 15);
            const float bias = f1_wsb[n];
            #pragma unroll
            for (int r = 0; r < 4; ++r) {
                const int m = q * 4 + r;
                if (m < 8) FS[m * FSS + n] = fmaxf(acc1[i][r] + bias, 0.f);
            }
        }
    }
    #pragma unroll
    for (int oi = 0; oi < 2; ++oi) {
        const int o = qq + 16 * oi;
        const float* w = f1_wv + o * 32;
        float a0 = 0.f, a1 = 0.f, a2 = 0.f;
        for (int h = 0; h < 32; ++h) {
            const float wc = w[h];
            const float* p = VH + e * NNH + h * 3;
            a0 = fmaf(p[0], wc, a0); a1 = fmaf(p[1], wc, a1); a2 = fmaf(p[2], wc, a2);
        }
        const float nrm = sqrtf(fmaxf(a0 * a0 + a1 * a1 + a2 * a2, EPSF));
        const float sg = 1.f / (1.f + __expf(-nrm));
        float* p2 = FV + e * NNH + o * 3;
        p2[0] = a0 * sg; p2[1] = a1 * sg; p2[2] = a2 * sg;
    }
    __syncthreads();

    #pragma unroll
    for (int hi = 0; hi < 2; ++hi) {
        const int h = qq + 16 * hi;
        const float* w = f2_wh + h * 32;
        float a0 = 0.f, a1 = 0.f, a2 = 0.f;
        for (int c = 0; c < 32; ++c) {
            const float wc = w[c];
            const float* p = FV + e * NNH + c * 3;
            a0 = fmaf(p[0], wc, a0); a1 = fmaf(p[1], wc, a1); a2 = fmaf(p[2], wc, a2);
        }
        float* o = VH + e * NNH + h * 3;
        o[0] = a0; o[1] = a1; o[2] = a2;
        FS[e * FSS + 512 + h] = sqrtf(fmaxf(a0 * a0 + a1 * a1 + a2 * a2, EPSF));
    }
    __syncthreads();

    {
        float acc[2][4];
        #pragma unroll
        for (int of = 0; of < 2; ++of) {
            const float bias = f2_wsb[lane + of * 64];
            #pragma unroll
            for (int e4 = 0; e4 < 4; ++e4) acc[of][e4] = bias;
        }
        for (int k = 0; k < FSS; k += 4) {
            float4 sv[4];
            #pragma unroll
            for (int e4 = 0; e4 < 4; ++e4)
                sv[e4] = *(const float4*)&FS[(wave * 4 + e4) * FSS + k];
            #pragma unroll
            for (int of = 0; of < 2; ++of) {
                const float4 w = *(const float4*)&f2_wsw[(size_t)(lane + of * 64) * 544 + k];
                #pragma unroll
                for (int e4 = 0; e4 < 4; ++e4) {
                    acc[of][e4] = fmaf(w.x, sv[e4].x, acc[of][e4]);
                    acc[of][e4] = fmaf(w.y, sv[e4].y, acc[of][e4]);
                    acc[of][e4] = fmaf(w.z, sv[e4].z, acc[of][e4]);
                    acc[of][e4] = fmaf(w.w, sv[e4].w, acc[of][e4]);
                }
            }
        }
        #pragma unroll
        for (int of = 0; of < 2; ++of)
            #pragma unroll
            for (int e4 = 0; e4 < 4; ++e4)
                S1f[(wave * 4 + e4) * NNS + lane + of * 64] += acc[of][e4];
    }
    {
        const int o = qq;
        const float* w = f2_wv + o * 32;
        float a0 = 0.f, a1 = 0.f, a2 = 0.f;
        for (int h = 0; h < 32; ++h) {
            const float wc = w[h];
            const float* p = VH + e * NNH + h * 3;
            a0 = fmaf(p[0], wc, a0); a1 = fmaf(p[1], wc, a1); a2 = fmaf(p[2], wc, a2);
        }
        float* p2 = V1f + e * NNV + o * 3;
        p2[0] += a0; p2[1] += a1; p2[2] += a2;
    }
    __syncthreads();

    layer_normT<4, NNS, NNV>(S1f + wave * 4 * NNS, V1f + wave * 4 * NNV,
                             ln1_g, ln1_b, red + wave * 32, lane);

    #pragma unroll
    for (int e4 = 0; e4 < 4; ++e4) {
        if (!oks[e4]) continue;
        const int idx = wave * 4 + e4;
        const int n = n0 + idx;
        if (lane < 32)
            ((float4*)(out + (size_t)n * 128))[lane] = ((const float4*)(S1f + idx * NNS))[lane];
        if (lane < 12)
            ((float4*)(out + (size_t)N * 128 + (size_t)n * 48))[lane] =
                ((const float4*)(V1f + idx * NNV))[lane];
    }
}

// ---------------------------------------------------------------------------
extern "C" void kernel_launch(void* const* d_in, const int* in_sizes, int n_in,
                              void* d_out, int out_size, void* d_ws, size_t ws_size,
                              hipStream_t stream)
{
    const float* s    = (const float*)d_in[0];
    const float* v    = (const float*)d_in[1];
    const int*   eidx = (const int*)d_in[2];
    const float* es   = (const float*)d_in[3];
    const float* ev   = (const float*)d_in[4];
    const float* m1_wh = (const float*)d_in[5];
    const float* m1_wsw = (const float*)d_in[6];
    const float* m1_wsb = (const float*)d_in[7];
    const float* m1_wv = (const float*)d_in[8];
    const float* m2_wh = (const float*)d_in[9];
    const float* m2_wsw = (const float*)d_in[10];
    const float* m2_wsb = (const float*)d_in[11];
    const float* m2_wv = (const float*)d_in[12];
    const float* m3_wh = (const float*)d_in[13];
    const float* m3_wsw = (const float*)d_in[14];
    const float* m3_wsb = (const float*)d_in[15];
    const float* m3_wv = (const float*)d_in[16];
    const float* f1_wh = (const float*)d_in[17];
    const float* f1_wsw = (const float*)d_in[18];
    const float* f1_wsb = (const float*)d_in[19];
    const float* f1_wv = (const float*)d_in[20];
    const float* f2_wh = (const float*)d_in[21];
    const float* f2_wsw = (const float*)d_in[22];
    const float* f2_wsb = (const float*)d_in[23];
    const float* f2_wv = (const float*)d_in[24];
    const float* ln0_g = (const float*)d_in[25];
    const float* ln0_b = (const float*)d_in[26];
    const float* ln1_g = (const float*)d_in[27];
    const float* ln1_b = (const float*)d_in[28];

    const int N = in_sizes[0] / 128;
    const int E = in_sizes[2] / 2;

    double* agg_s = (double*)d_ws;                     // N*128 f64
    double* agg_v = agg_s + (size_t)N * 128;           // N*48  f64
    float* cnt    = (float*)(agg_v + (size_t)N * 48);  // N     f32
    unsigned short* pk =
        (unsigned short*)(((uintptr_t)(cnt + N) + 15) & ~(uintptr_t)15);
    const int S_P1E = 12288, S_M23 = 20480, S_MN = 32768, S_F1 = 81920;
    unsigned short* p1h = pk;            unsigned short* p1l = p1h + S_P1E;
    unsigned short* p2h = p1l + S_P1E;   unsigned short* p2l = p2h + S_M23;
    unsigned short* p3h = p2l + S_M23;   unsigned short* p3l = p3h + S_M23;
    unsigned short* pnh = p3l + S_M23;   unsigned short* pnl = pnh + S_MN;
    unsigned short* pf1h = pnl + S_MN;   unsigned short* pf1l = pf1h + S_F1;
    float* Pg  = (float*)(((uintptr_t)(pf1l + S_F1) + 15) & ~(uintptr_t)15);
    float* Q1g = Pg + (size_t)N * 256;
    float* Q3g = Q1g + (size_t)N * 100;

    hipMemsetAsync(d_ws, 0,
                   (size_t)N * 176 * sizeof(double) + (size_t)N * sizeof(float),
                   stream);

    pack_m1e<<<dim3((12288 + 255) / 256), dim3(256), 0, stream>>>(m1_wsw, p1h, p1l);
    pack_w<<<dim3((S_M23 + 255) / 256), dim3(256), 0, stream>>>(m2_wsw, p2h, p2l, 128, 144, 5);
    pack_w<<<dim3((S_M23 + 255) / 256), dim3(256), 0, stream>>>(m3_wsw, p3h, p3l, 128, 144, 5);
    pack_m1n<<<dim3((32768 + 255) / 256), dim3(256), 0, stream>>>(m1_wsw, pnh, pnl);
    pack_w<<<dim3((S_F1 + 255) / 256), dim3(256), 0, stream>>>(f1_wsw, pf1h, pf1l, 512, 160, 5);

    node_pre<<<dim3((N + 15) / 16), dim3(256), 0, stream>>>(
        s, v, m1_wh, m1_wsb, pnh, pnl, Pg, Q1g, Q3g, N);

    edge_kernel<<<dim3((E + 15) / 16), dim3(256), 0, stream>>>(
        eidx, es, ev,
        m1_wh, m1_wv,
        m2_wh, m2_wsb, m2_wv,
        m3_wh, m3_wsb, m3_wv,
        p1h, p1l, p2h, p2l, p3h, p3l,
        Pg, Q1g, Q3g,
        agg_s, agg_v, cnt, E);

    node_kernel<<<dim3((N + 7) / 8), dim3(128), 0, stream>>>(
        s, v,
        f1_wh, f1_wsb, f1_wv,
        f2_wh, f2_wsw, f2_wsb, f2_wv,
        ln0_g, ln0_b, ln1_g, ln1_b,
        pf1h, pf1l,
        agg_s, agg_v, cnt,
        (float*)d_out, N);
}

// Round 8
// 1406.406 us; speedup vs baseline: 1.3872x; 1.0078x over previous
//
#include <hip/hip_runtime.h>

#define EPSF 1e-8f

typedef __attribute__((ext_vector_type(8))) short short8;
typedef __attribute__((ext_vector_type(4))) short short4v;
typedef __attribute__((ext_vector_type(4))) float float4v;

// ---- fp32 -> bf16 hi/lo split (RNE) ---------------------------------------
__device__ __forceinline__ unsigned bfhi_bits(float x) {
    unsigned u = __float_as_uint(x);
    return (u + 0x7fffu + ((u >> 16) & 1u)) >> 16;
}
__device__ __forceinline__ float bits2f(unsigned b) { return __uint_as_float(b << 16); }
__device__ __forceinline__ void split_bf(float x, unsigned short& h, unsigned short& l) {
    unsigned hb = bfhi_bits(x);
    h = (unsigned short)hb;
    l = (unsigned short)bfhi_bits(x - bits2f(hb));
}

// ---------------------------------------------------------------------------
// Pack W[NO][K] fp32 (row-major) into MFMA B-fragment order, bf16 hi/lo.
// ---------------------------------------------------------------------------
__global__ void pack_w(const float* __restrict__ W, unsigned short* __restrict__ hi,
                       unsigned short* __restrict__ lo, int NO, int K, int steps) {
    const int gid = blockIdx.x * 256 + threadIdx.x;
    const int total = (NO >> 4) * steps * 512;
    if (gid >= total) return;
    const int j = gid & 7, l = (gid >> 3) & 63, rest = gid >> 9;
    const int t = rest % steps, nt = rest / steps;
    const int n = nt * 16 + (l & 15);
    const int k = t * 32 + ((l >> 4) << 3) + j;
    const float x = (k < K) ? W[(size_t)n * K + k] : 0.f;
    unsigned short h, lw;
    split_bf(x, h, lw);
    hi[gid] = h; lo[gid] = lw;
}

// pack m1 edge-part B: NO=128, K=96, steps=3.
__global__ void pack_m1e(const float* __restrict__ W, unsigned short* __restrict__ hi,
                         unsigned short* __restrict__ lo) {
    const int gid = blockIdx.x * 256 + threadIdx.x;
    if (gid >= 12288) return;
    const int j = gid & 7, l = (gid >> 3) & 63, rest = gid >> 9;
    const int t = rest % 3, nt = rest / 3;
    const int n = nt * 16 + (l & 15);
    const int k = t * 32 + ((l >> 4) << 3) + j;
    float x = 0.f;
    if (k < 32)      x = W[(size_t)n * 321 + 128 + k];
    else if (k < 65) x = W[(size_t)n * 321 + 288 + (k - 32)];
    unsigned short h, lw; split_bf(x, h, lw);
    hi[gid] = h; lo[gid] = lw;
}

// pack node-pre B: NO=256, K=128, steps=4.
__global__ void pack_m1n(const float* __restrict__ W, unsigned short* __restrict__ hi,
                         unsigned short* __restrict__ lo) {
    const int gid = blockIdx.x * 256 + threadIdx.x;
    if (gid >= 32768) return;
    const int j = gid & 7, l = (gid >> 3) & 63, rest = gid >> 9;
    const int t = rest & 3, nt = rest >> 2;
    const int n = nt * 16 + (l & 15);
    const int k = t * 32 + ((l >> 4) << 3) + j;
    const float x = (n < 128) ? W[(size_t)n * 321 + k]
                              : W[(size_t)(n - 128) * 321 + 160 + k];
    unsigned short h, lw; split_bf(x, h, lw);
    hi[gid] = h; lo[gid] = lw;
}

// ---------------------------------------------------------------------------
// 3-pass split-bf16 MFMA K-loop (validated).
// ---------------------------------------------------------------------------
template<int STEPS, int NTPW, int ASTR>
__device__ __forceinline__ void kloop(const unsigned short* PAh, const unsigned short* PAl,
    const unsigned short* __restrict__ wph, const unsigned short* __restrict__ wpl,
    float4v* acc, int lane, int wave)
{
    const int m = lane & 15, q = lane >> 4;
    for (int t = 0; t < STEPS; ++t) {
        const int k0 = t * 32 + q * 8;
        const short8 ah = *(const short8*)(PAh + m * ASTR + k0);
        const short8 al = *(const short8*)(PAl + m * ASTR + k0);
        #pragma unroll
        for (int i = 0; i < NTPW; ++i) {
            const int nt = wave * NTPW + i;
            const size_t off = ((size_t)(nt * STEPS + t) * 64 + lane) * 8;
            const short8 bh = *(const short8*)(wph + off);
            const short8 bl = *(const short8*)(wpl + off);
            acc[i] = __builtin_amdgcn_mfma_f32_16x16x32_bf16(ah, bh, acc[i], 0, 0, 0);
            acc[i] = __builtin_amdgcn_mfma_f32_16x16x32_bf16(al, bh, acc[i], 0, 0, 0);
            acc[i] = __builtin_amdgcn_mfma_f32_16x16x32_bf16(ah, bl, acc[i], 0, 0, 0);
        }
    }
}

// ===========================================================================
// node_pre (green in R5, verbatim)
// ===========================================================================
constexpr int PAS = 136;

__global__ __launch_bounds__(256)
void node_pre(const float* __restrict__ s, const float* __restrict__ v,
              const float* __restrict__ m1_wh, const float* __restrict__ m1_wsb,
              const unsigned short* __restrict__ pnh, const unsigned short* __restrict__ pnl,
              float* __restrict__ Pg, float* __restrict__ Q1g, float* __restrict__ Q3g,
              int N)
{
    __shared__ __align__(16) unsigned short Ah[16 * PAS], Al[16 * PAS];
    __shared__ __align__(16) float Vs[16 * 48];

    const int tid = threadIdx.x, lane = tid & 63, wave = tid >> 6;
    const int e = tid & 15, q16 = tid >> 4;
    const int n0 = blockIdx.x * 16;
    const int ne = min(n0 + e, N - 1);

    {
        const float* sp = s + (size_t)ne * 128 + q16 * 8;
        const float4 x = ((const float4*)sp)[0];
        const float4 y = ((const float4*)sp)[1];
        short8 hv, lv; unsigned short h, l;
        split_bf(x.x, h, l); hv[0] = h; lv[0] = l;
        split_bf(x.y, h, l); hv[1] = h; lv[1] = l;
        split_bf(x.z, h, l); hv[2] = h; lv[2] = l;
        split_bf(x.w, h, l); hv[3] = h; lv[3] = l;
        split_bf(y.x, h, l); hv[4] = h; lv[4] = l;
        split_bf(y.y, h, l); hv[5] = h; lv[5] = l;
        split_bf(y.z, h, l); hv[6] = h; lv[6] = l;
        split_bf(y.w, h, l); hv[7] = h; lv[7] = l;
        *(short8*)(Ah + e * PAS + q16 * 8) = hv;
        *(short8*)(Al + e * PAS + q16 * 8) = lv;
    }
    if (q16 < 12)
        ((float4*)(Vs + e * 48))[q16] = ((const float4*)(v + (size_t)ne * 48))[q16];
    __syncthreads();

    {
        float4v acc[4] = {{0,0,0,0},{0,0,0,0},{0,0,0,0},{0,0,0,0}};
        kloop<4, 4, PAS>(Ah, Al, pnh, pnl, acc, lane, wave);
        const int q = lane >> 4;
        #pragma unroll
        for (int i = 0; i < 4; ++i) {
            const int j = (wave * 4 + i) * 16 + (lane & 15);
            const float bias = (j < 128) ? m1_wsb[j] : 0.f;
            #pragma unroll
            for (int r = 0; r < 4; ++r) {
                const int m = q * 4 + r;
                if (n0 + m < N) Pg[(size_t)(n0 + m) * 256 + j] = acc[i][r] + bias;
            }
        }
    }
    #pragma unroll
    for (int k = 0; k < 7; ++k) {
        const int idx = tid + k * 256;
        if (idx < 16 * 99) {
            const int n = idx & 15, j = idx >> 4;
            const int h = j / 3, t = j - h * 3;
            const float* vb = Vs + n * 48 + t;
            const float* w = m1_wh + h * 33;
            float a1 = 0.f, a3 = 0.f;
            for (int c = 0; c < 16; ++c) {
                const float vv = vb[c * 3];
                a1 = fmaf(w[c], vv, a1);
                a3 = fmaf(w[17 + c], vv, a3);
            }
            const int nn = n0 + n;
            if (nn < N) {
                Q1g[(size_t)nn * 100 + j] = a1;
                Q3g[(size_t)nn * 100 + j] = a3;
            }
        }
    }
}

// ---------------------------------------------------------------------------
// Edge kernel: 16 edges / block, 256 threads (4 waves).
// R7-green arithmetic, LDS overlays for occupancy:
//   PB overlays A (identical 16x168-short geometry; A dead after m1 kloop;
//     m2 relu output rewrites in place).  B2 overlays SP (SP dead after m1
//     epilogue).  +3 barriers enforce the overlay hand-offs.
// LDS 39936 -> 25856 B  =>  6 blocks/CU (was 4), 24 waves/CU.
// Phase/barrier schedule (read -> write sets audited):
//   E2: write A[0,96), SP, B1, idx | bar
//   E5a: m1 kloop reads A[0,96) | bar | E5b: read SP, write PB(=A)[*][0,128)
//        | bar | E5c: vout1 read B1, write B2(=SP) | bar
//   E6: read B2, write B1 + PB[*][128,160) | bar
//   E8a: m2 kloop reads PB(=A)[0,160) | bar | E8b: write A[*][0,128) (relu),
//        vout2 read B1 write B2 | bar
//   E9: read B2, write B1 + A[128,160) | bar
//   E11: m3 kloop reads A[0,160); vout3 read B1 write B2 | bar
//   E12: read B2 + acc regs -> fp64 atomics (order-invariant, deterministic)
// ---------------------------------------------------------------------------
constexpr int SA2 = 168;
constexpr int SBs = 168;
constexpr int SB1 = 100;
constexpr int SB2 = 52;
constexpr int SPS = 132;

__global__ __launch_bounds__(256)
void edge_kernel(const int* __restrict__ eidx,
                 const float* __restrict__ es, const float* __restrict__ ev,
                 const float* __restrict__ m1_wh, const float* __restrict__ m1_wv,
                 const float* __restrict__ m2_wh, const float* __restrict__ m2_wsb,
                 const float* __restrict__ m2_wv,
                 const float* __restrict__ m3_wh, const float* __restrict__ m3_wsb,
                 const float* __restrict__ m3_wv,
                 const unsigned short* __restrict__ p1h, const unsigned short* __restrict__ p1l,
                 const unsigned short* __restrict__ p2h, const unsigned short* __restrict__ p2l,
                 const unsigned short* __restrict__ p3h, const unsigned short* __restrict__ p3l,
                 const float* __restrict__ Pg, const float* __restrict__ Q1g,
                 const float* __restrict__ Q3g,
                 double* __restrict__ agg_s, double* __restrict__ agg_v,
                 float* __restrict__ cnt, int E)
{
    __shared__ __align__(16) unsigned short Ah[16 * SA2], Al[16 * SA2];
    __shared__ __align__(16) float SP[16 * SPS];
    __shared__ __align__(16) float B1[16 * SB1];
    __shared__ int ssrc[16], sgd[16], sdst[16], seid[16];

    unsigned short* PBh = Ah;      // overlay: PB == A (identical geometry)
    unsigned short* PBl = Al;
    float* B2 = SP;                // overlay: B2 in SP's first 3328 B

    const int tid = threadIdx.x, lane = tid & 63, wave = tid >> 6;
    const int e = tid & 15, q16 = tid >> 4;
    const int e0 = blockIdx.x * 16;

    // E1: indices
    if (tid < 16) {
        const int eg = e0 + tid;
        const bool ok = (eg < E);
        const int ee = ok ? eg : (E - 1);
        seid[tid] = ee;
        ssrc[tid] = eidx[ee];
        const int d = eidx[E + ee];
        sgd[tid] = d;
        sdst[tid] = ok ? d : -1;
    }
    __syncthreads();

    // E2: es -> A[0,32) bf16; vn1 -> A[32,65); zero [65,96); SP; B1 (vh1)
    if (q16 < 8) {
        const float4 x = ((const float4*)(es + (size_t)seid[e] * 32))[q16];
        short4v hv, lv; unsigned short h, l;
        split_bf(x.x, h, l); hv[0] = h; lv[0] = l;
        split_bf(x.y, h, l); hv[1] = h; lv[1] = l;
        split_bf(x.z, h, l); hv[2] = h; lv[2] = l;
        split_bf(x.w, h, l); hv[3] = h; lv[3] = l;
        *(short4v*)(Ah + e * SA2 + 4 * q16) = hv;
        *(short4v*)(Al + e * SA2 + 4 * q16) = lv;
    }
    { const int c = 65 + q16; Ah[e * SA2 + c] = 0; Al[e * SA2 + c] = 0; }
    { const int c = 81 + q16; if (c < 96) { Ah[e * SA2 + c] = 0; Al[e * SA2 + c] = 0; } }
    {
        const float* P1 = Pg + (size_t)ssrc[e] * 256;
        const float* P3 = Pg + (size_t)sgd[e] * 256 + 128;
        const float4 a0 = ((const float4*)P1)[2 * q16];
        const float4 a1 = ((const float4*)P1)[2 * q16 + 1];
        const float4 b0 = ((const float4*)P3)[2 * q16];
        const float4 b1 = ((const float4*)P3)[2 * q16 + 1];
        float4 r0, r1;
        r0.x = a0.x + b0.x; r0.y = a0.y + b0.y; r0.z = a0.z + b0.z; r0.w = a0.w + b0.w;
        r1.x = a1.x + b1.x; r1.y = a1.y + b1.y; r1.z = a1.z + b1.z; r1.w = a1.w + b1.w;
        float4* o = (float4*)(SP + e * SPS + 8 * q16);
        o[0] = r0; o[1] = r1;
    }
    #pragma unroll
    for (int k = 0; k < 3; ++k) {
        const int idx = tid + k * 256;
        if (idx < 528) {
            const int h = idx >> 4, e2 = idx & 15;
            const float* q1 = Q1g + (size_t)ssrc[e2] * 100 + h * 3;
            const float* q3 = Q3g + (size_t)sgd[e2] * 100 + h * 3;
            const float* evp = ev + (size_t)seid[e2] * 3;
            const float w16 = m1_wh[h * 33 + 16];
            const float v0 = q1[0] + q3[0] + w16 * evp[0];
            const float v1 = q1[1] + q3[1] + w16 * evp[1];
            const float v2 = q1[2] + q3[2] + w16 * evp[2];
            float* o = B1 + e2 * SB1 + h * 3;
            o[0] = v0; o[1] = v1; o[2] = v2;
            const float vn = sqrtf(fmaxf(v0 * v0 + v1 * v1 + v2 * v2, EPSF));
            unsigned short hh, ll; split_bf(vn, hh, ll);
            Ah[e2 * SA2 + 32 + h] = hh; Al[e2 * SA2 + 32 + h] = ll;
        }
    }
    __syncthreads();

    // E5a: m1 MFMA (K=96) reads A
    float4v acc1[2] = {{0,0,0,0},{0,0,0,0}};
    kloop<3, 2, SA2>(Ah, Al, p1h, p1l, acc1, lane, wave);
    __syncthreads();   // all waves done reading A before PB(=A) is written

    // E5b: +SP -> relu -> PB(=A)[*][0,128)
    {
        const int q = lane >> 4;
        #pragma unroll
        for (int i = 0; i < 2; ++i) {
            const int n = (wave * 2 + i) * 16 + (lane & 15);
            #pragma unroll
            for (int r = 0; r < 4; ++r) {
                const int m = q * 4 + r;
                const float x = fmaxf(acc1[i][r] + SP[m * SPS + n], 0.f);
                unsigned short h, l; split_bf(x, h, l);
                PBh[m * SBs + n] = h; PBl[m * SBs + n] = l;
            }
        }
    }
    __syncthreads();   // all SP reads done before B2(=SP) is written

    // E5c: vout1 -> B2(=SP)
    {
        const int o = q16;
        float a0 = 0.f, a1 = 0.f, a2 = 0.f;
        for (int h = 0; h < 33; ++h) {
            const float w = m1_wv[o * 33 + h];
            const float* p = B1 + e * SB1 + h * 3;
            a0 = fmaf(p[0], w, a0); a1 = fmaf(p[1], w, a1); a2 = fmaf(p[2], w, a2);
        }
        const float nrm = sqrtf(fmaxf(a0 * a0 + a1 * a1 + a2 * a2, EPSF));
        const float sg = 1.f / (1.f + __expf(-nrm));
        float* p2 = B2 + e * SB2 + o * 3;
        p2[0] = a0 * sg; p2[1] = a1 * sg; p2[2] = a2 * sg;
    }
    __syncthreads();

    // E6: vh2 -> B1; vn2 -> PB[128,144); zero PB[144,160)
    {
        const int h = q16;
        float a0 = 0.f, a1 = 0.f, a2 = 0.f;
        for (int c = 0; c < 16; ++c) {
            const float w = m2_wh[h * 16 + c];
            const float* p = B2 + e * SB2 + c * 3;
            a0 = fmaf(p[0], w, a0); a1 = fmaf(p[1], w, a1); a2 = fmaf(p[2], w, a2);
        }
        float* o = B1 + e * SB1 + h * 3;
        o[0] = a0; o[1] = a1; o[2] = a2;
        const float vn = sqrtf(fmaxf(a0 * a0 + a1 * a1 + a2 * a2, EPSF));
        unsigned short hh, ll; split_bf(vn, hh, ll);
        PBh[e * SBs + 128 + h] = hh; PBl[e * SBs + 128 + h] = ll;
        PBh[e * SBs + 144 + h] = 0;  PBl[e * SBs + 144 + h] = 0;
    }
    __syncthreads();

    // E8a: m2 MFMA (K=160) reads PB(=A)
    float4v acc2[2] = {{0,0,0,0},{0,0,0,0}};
    kloop<5, 2, SBs>(PBh, PBl, p2h, p2l, acc2, lane, wave);
    __syncthreads();   // all waves done reading PB before A is rewritten

    // E8b: relu -> A[*][0,128); vout2 -> B2
    {
        const int q = lane >> 4;
        #pragma unroll
        for (int i = 0; i < 2; ++i) {
            const int n = (wave * 2 + i) * 16 + (lane & 15);
            const float bias = m2_wsb[n];
            #pragma unroll
            for (int r = 0; r < 4; ++r) {
                const int m = q * 4 + r;
                const float x = fmaxf(acc2[i][r] + bias, 0.f);
                unsigned short h, l; split_bf(x, h, l);
                Ah[m * SA2 + n] = h; Al[m * SA2 + n] = l;
            }
        }
    }
    {
        const int o = q16;
        float a0 = 0.f, a1 = 0.f, a2 = 0.f;
        for (int h = 0; h < 16; ++h) {
            const float w = m2_wv[o * 16 + h];
            const float* p = B1 + e * SB1 + h * 3;
            a0 = fmaf(p[0], w, a0); a1 = fmaf(p[1], w, a1); a2 = fmaf(p[2], w, a2);
        }
        const float nrm = sqrtf(fmaxf(a0 * a0 + a1 * a1 + a2 * a2, EPSF));
        const float sg = 1.f / (1.f + __expf(-nrm));
        float* p2 = B2 + e * SB2 + o * 3;
        p2[0] = a0 * sg; p2[1] = a1 * sg; p2[2] = a2 * sg;
    }
    __syncthreads();

    // E9: vh3 -> B1; vn3 -> A[128,144); zero A[144,160)
    {
        const int h = q16;
        float a0 = 0.f, a1 = 0.f, a2 = 0.f;
        for (int c = 0; c < 16; ++c) {
            const float w = m3_wh[h * 16 + c];
            const float* p = B2 + e * SB2 + c * 3;
            a0 = fmaf(p[0], w, a0); a1 = fmaf(p[1], w, a1); a2 = fmaf(p[2], w, a2);
        }
        float* o = B1 + e * SB1 + h * 3;
        o[0] = a0; o[1] = a1; o[2] = a2;
        const float vn = sqrtf(fmaxf(a0 * a0 + a1 * a1 + a2 * a2, EPSF));
        unsigned short hh, ll; split_bf(vn, hh, ll);
        Ah[e * SA2 + 128 + h] = hh; Al[e * SA2 + 128 + h] = ll;
        Ah[e * SA2 + 144 + h] = 0;  Al[e * SA2 + 144 + h] = 0;
    }
    __syncthreads();

    // E11: m3 MFMA (K=160, no act) reads A; vout3 -> B2 (disjoint from A)
    float4v acc3[2] = {{0,0,0,0},{0,0,0,0}};
    kloop<5, 2, SA2>(Ah, Al, p3h, p3l, acc3, lane, wave);
    {
        const int o = q16;
        float a0 = 0.f, a1 = 0.f, a2 = 0.f;
        for (int h = 0; h < 16; ++h) {
            const float w = m3_wv[o * 16 + h];
            const float* p = B1 + e * SB1 + h * 3;
            a0 = fmaf(p[0], w, a0); a1 = fmaf(p[1], w, a1); a2 = fmaf(p[2], w, a2);
        }
        float* p2 = B2 + e * SB2 + o * 3;
        p2[0] = a0; p2[1] = a1; p2[2] = a2;
    }
    __syncthreads();

    // E12: scatter-add (fp64 atomics -> order-invariant)
    {
        const int q = lane >> 4;
        #pragma unroll
        for (int i = 0; i < 2; ++i) {
            const int n = (wave * 2 + i) * 16 + (lane & 15);
            const float bias = m3_wsb[n];
            #pragma unroll
            for (int r = 0; r < 4; ++r) {
                const int m = q * 4 + r;
                const int d = sdst[m];
                if (d >= 0) atomicAdd(&agg_s[(size_t)d * 128 + n], (double)(acc3[i][r] + bias));
            }
        }
    }
    #pragma unroll
    for (int it = 0; it < 3; ++it) {
        const int j = q16 + 16 * it;
        const int d = sdst[e];
        if (d >= 0) atomicAdd(&agg_v[(size_t)d * 48 + j], (double)B2[e * SB2 + j]);
    }
    if (tid < 16 && sdst[tid] >= 0) atomicAdd(&cnt[sdst[tid]], 1.0f);
}

// ===========================================================================
// layer_normT: wave processes NE nodes (proven math, verbatim per node)
// ===========================================================================
template<int NE, int SSTR, int VSTR>
__device__ __forceinline__ void layer_normT(float* S, float* V,
    const float* __restrict__ g, const float* __restrict__ b, float* red, int lane)
{
    #pragma unroll
    for (int e = 0; e < NE; ++e) {
        float x0 = S[e * SSTR + lane], x1 = S[e * SSTR + 64 + lane];
        float sum = x0 + x1;
        #pragma unroll
        for (int off = 32; off > 0; off >>= 1) sum += __shfl_xor(sum, off, 64);
        const float mu = sum * (1.f / 128.f);
        const float d0 = x0 - mu, d1 = x1 - mu;
        float vs = d0 * d0 + d1 * d1;
        #pragma unroll
        for (int off = 32; off > 0; off >>= 1) vs += __shfl_xor(vs, off, 64);
        const float rstd = rsqrtf(vs * (1.f / 128.f) + 1e-5f);
        S[e * SSTR + lane]      = d0 * rstd * g[lane]      + b[lane];
        S[e * SSTR + 64 + lane] = d1 * rstd * g[lane + 64] + b[lane + 64];

        if (lane < 16) {
            const float a = V[e * VSTR + lane * 3], bb = V[e * VSTR + lane * 3 + 1],
                        cc = V[e * VSTR + lane * 3 + 2];
            const float vn = fmaxf(a * a + bb * bb + cc * cc, EPSF);
            red[lane]      = vn;
            red[16 + lane] = (vn > 2.f * EPSF) ? 1.f : 0.f;
        }
        __syncthreads();
        float sn = 0.f, sm = 0.f;
        #pragma unroll
        for (int i = 0; i < 16; ++i) { sn += red[i] * red[16 + i]; sm += red[16 + i]; }
        const float rvm = rsqrtf(sn / (EPSF + sm) + EPSF);
        if (lane < 48) V[e * VSTR + lane] = red[16 + lane / 3] * V[e * VSTR + lane] * rvm;
        __syncthreads();
    }
}

// ===========================================================================
// Node kernel (green in R7, verbatim): 8 nodes/block, 128 threads, 2 waves.
// ===========================================================================
constexpr int NNS  = 132;
constexpr int NNV  = 52;
constexpr int NNH  = 98;
constexpr int NA1n = 168;
constexpr int FSS  = 544;

__global__ __launch_bounds__(128)
void node_kernel(const float* __restrict__ s, const float* __restrict__ v,
                 const float* __restrict__ f1_wh, const float* __restrict__ f1_wsb,
                 const float* __restrict__ f1_wv,
                 const float* __restrict__ f2_wh, const float* __restrict__ f2_wsw,
                 const float* __restrict__ f2_wsb, const float* __restrict__ f2_wv,
                 const float* __restrict__ ln0_g, const float* __restrict__ ln0_b,
                 const float* __restrict__ ln1_g, const float* __restrict__ ln1_b,
                 const unsigned short* __restrict__ pf1h, const unsigned short* __restrict__ pf1l,
                 const double* __restrict__ agg_s, const double* __restrict__ agg_v,
                 const float* __restrict__ cnt,
                 float* __restrict__ out, int N)
{
    __shared__ __align__(16) unsigned short UBh[8 * NA1n], UBl[8 * NA1n];
    __shared__ __align__(16) float FS[8 * FSS];
    __shared__ __align__(16) float S1f[8 * NNS];
    __shared__ __align__(16) float V1f[8 * NNV];
    __shared__ __align__(16) float VH[8 * NNH];
    __shared__ __align__(16) float FV[8 * NNH];
    __shared__ float red[2 * 32];

    const int tid = threadIdx.x, lane = tid & 63, wave = tid >> 6;
    const int e = tid & 7, qq = tid >> 3;
    const int n0 = blockIdx.x * 8;

    bool oks[4];
    #pragma unroll
    for (int e4 = 0; e4 < 4; ++e4) {
        const int idx = wave * 4 + e4;
        const int ng = n0 + idx;
        oks[e4] = (ng < N);
        const int n = oks[e4] ? ng : (N - 1);
        const double inv = 1.0 / (double)fmaxf(cnt[n], 1.f);
        if (lane < 32) {
            const float4 a = ((const float4*)(s + (size_t)n * 128))[lane];
            const double2 b0 = ((const double2*)(agg_s + (size_t)n * 128))[2 * lane];
            const double2 b1 = ((const double2*)(agg_s + (size_t)n * 128))[2 * lane + 1];
            float4 r;
            r.x = (float)((double)a.x + b0.x * inv);
            r.y = (float)((double)a.y + b0.y * inv);
            r.z = (float)((double)a.z + b1.x * inv);
            r.w = (float)((double)a.w + b1.y * inv);
            ((float4*)(S1f + idx * NNS))[lane] = r;
        }
        if (lane < 12) {
            const float4 a = ((const float4*)(v + (size_t)n * 48))[lane];
            const double2 b0 = ((const double2*)(agg_v + (size_t)n * 48))[2 * lane];
            const double2 b1 = ((const double2*)(agg_v + (size_t)n * 48))[2 * lane + 1];
            float4 r;
            r.x = (float)((double)a.x + b0.x * inv);
            r.y = (float)((double)a.y + b0.y * inv);
            r.z = (float)((double)a.z + b1.x * inv);
            r.w = (float)((double)a.w + b1.y * inv);
            ((float4*)(V1f + idx * NNV))[lane] = r;
        }
    }
    __syncthreads();

    layer_normT<4, NNS, NNV>(S1f + wave * 4 * NNS, V1f + wave * 4 * NNV,
                             ln0_g, ln0_b, red + wave * 32, lane);

    {
        const float* sp = S1f + e * NNS + qq * 8;
        short8 hv, lv; unsigned short h, l;
        #pragma unroll
        for (int j = 0; j < 8; ++j) { split_bf(sp[j], h, l); hv[j] = h; lv[j] = l; }
        *(short8*)(UBh + e * NA1n + qq * 8) = hv;
        *(short8*)(UBl + e * NA1n + qq * 8) = lv;
    }
    #pragma unroll
    for (int hi = 0; hi < 2; ++hi) {
        const int h = qq + 16 * hi;
        const float* w = f1_wh + h * 16;
        const float* vb = V1f + e * NNV;
        float a0 = 0.f, a1 = 0.f, a2 = 0.f;
        for (int c = 0; c < 16; ++c) {
            const float wc = w[c];
            a0 = fmaf(vb[c * 3 + 0], wc, a0);
            a1 = fmaf(vb[c * 3 + 1], wc, a1);
            a2 = fmaf(vb[c * 3 + 2], wc, a2);
        }
        float* o = VH + e * NNH + h * 3;
        o[0] = a0; o[1] = a1; o[2] = a2;
        const float vn = sqrtf(fmaxf(a0 * a0 + a1 * a1 + a2 * a2, EPSF));
        unsigned short hh, ll; split_bf(vn, hh, ll);
        UBh[e * NA1n + 128 + h] = hh; UBl[e * NA1n + 128 + h] = ll;
    }
    __syncthreads();

    {
        float4v acc1[16];
        #pragma unroll
        for (int i = 0; i < 16; ++i) acc1[i] = (float4v){0.f, 0.f, 0.f, 0.f};
        kloop<5, 16, NA1n>(UBh, UBl, pf1h, pf1l, acc1, lane, wave);
        const int q = lane >> 4;
        #pragma unroll
        for (int i = 0; i < 16; ++i) {
            const int n = (wave * 16 + i) * 16 + (lane & 15);
            const float bias = f1_wsb[n];
            #pragma unroll
            for (int r = 0; r < 4; ++r) {
                const int m = q * 4 + r;
                if (m < 8) FS[m * FSS + n] = fmaxf(acc1[i][r] + bias, 0.f);
            }
        }
    }
    #pragma unroll
    for (int oi = 0; oi < 2; ++oi) {
        const int o = qq + 16 * oi;
        const float* w = f1_wv + o * 32;
        float a0 = 0.f, a1 = 0.f, a2 = 0.f;
        for (int h = 0; h < 32; ++h) {
            const float wc = w[h];
            const float* p = VH + e * NNH + h * 3;
            a0 = fmaf(p[0], wc, a0); a1 = fmaf(p[1], wc, a1); a2 = fmaf(p[2], wc, a2);
        }
        const float nrm = sqrtf(fmaxf(a0 * a0 + a1 * a1 + a2 * a2, EPSF));
        const float sg = 1.f / (1.f + __expf(-nrm));
        float* p2 = FV + e * NNH + o * 3;
        p2[0] = a0 * sg; p2[1] = a1 * sg; p2[2] = a2 * sg;
    }
    __syncthreads();

    #pragma unroll
    for (int hi = 0; hi < 2; ++hi) {
        const int h = qq + 16 * hi;
        const float* w = f2_wh + h * 32;
        float a0 = 0.f, a1 = 0.f, a2 = 0.f;
        for (int c = 0; c < 32; ++c) {
            const float wc = w[c];
            const float* p = FV + e * NNH + c * 3;
            a0 = fmaf(p[0], wc, a0); a1 = fmaf(p[1], wc, a1); a2 = fmaf(p[2], wc, a2);
        }
        float* o = VH + e * NNH + h * 3;
        o[0] = a0; o[1] = a1; o[2] = a2;
        FS[e * FSS + 512 + h] = sqrtf(fmaxf(a0 * a0 + a1 * a1 + a2 * a2, EPSF));
    }
    __syncthreads();

    {
        float acc[2][4];
        #pragma unroll
        for (int of = 0; of < 2; ++of) {
            const float bias = f2_wsb[lane + of * 64];
            #pragma unroll
            for (int e4 = 0; e4 < 4; ++e4) acc[of][e4] = bias;
        }
        for (int k = 0; k < FSS; k += 4) {
            float4 sv[4];
            #pragma unroll
            for (int e4 = 0; e4 < 4; ++e4)
                sv[e4] = *(const float4*)&FS[(wave * 4 + e4) * FSS + k];
            #pragma unroll
            for (int of = 0; of < 2; ++of) {
                const float4 w = *(const float4*)&f2_wsw[(size_t)(lane + of * 64) * 544 + k];
                #pragma unroll
                for (int e4 = 0; e4 < 4; ++e4) {
                    acc[of][e4] = fmaf(w.x, sv[e4].x, acc[of][e4]);
                    acc[of][e4] = fmaf(w.y, sv[e4].y, acc[of][e4]);
                    acc[of][e4] = fmaf(w.z, sv[e4].z, acc[of][e4]);
                    acc[of][e4] = fmaf(w.w, sv[e4].w, acc[of][e4]);
                }
            }
        }
        #pragma unroll
        for (int of = 0; of < 2; ++of)
            #pragma unroll
            for (int e4 = 0; e4 < 4; ++e4)
                S1f[(wave * 4 + e4) * NNS + lane + of * 64] += acc[of][e4];
    }
    {
        const int o = qq;
        const float* w = f2_wv + o * 32;
        float a0 = 0.f, a1 = 0.f, a2 = 0.f;
        for (int h = 0; h < 32; ++h) {
            const float wc = w[h];
            const float* p = VH + e * NNH + h * 3;
            a0 = fmaf(p[0], wc, a0); a1 = fmaf(p[1], wc, a1); a2 = fmaf(p[2], wc, a2);
        }
        float* p2 = V1f + e * NNV + o * 3;
        p2[0] += a0; p2[1] += a1; p2[2] += a2;
    }
    __syncthreads();

    layer_normT<4, NNS, NNV>(S1f + wave * 4 * NNS, V1f + wave * 4 * NNV,
                             ln1_g, ln1_b, red + wave * 32, lane);

    #pragma unroll
    for (int e4 = 0; e4 < 4; ++e4) {
        if (!oks[e4]) continue;
        const int idx = wave * 4 + e4;
        const int n = n0 + idx;
        if (lane < 32)
            ((float4*)(out + (size_t)n * 128))[lane] = ((const float4*)(S1f + idx * NNS))[lane];
        if (lane < 12)
            ((float4*)(out + (size_t)N * 128 + (size_t)n * 48))[lane] =
                ((const float4*)(V1f + idx * NNV))[lane];
    }
}

// ---------------------------------------------------------------------------
extern "C" void kernel_launch(void* const* d_in, const int* in_sizes, int n_in,
                              void* d_out, int out_size, void* d_ws, size_t ws_size,
                              hipStream_t stream)
{
    const float* s    = (const float*)d_in[0];
    const float* v    = (const float*)d_in[1];
    const int*   eidx = (const int*)d_in[2];
    const float* es   = (const float*)d_in[3];
    const float* ev   = (const float*)d_in[4];
    const float* m1_wh = (const float*)d_in[5];
    const float* m1_wsw = (const float*)d_in[6];
    const float* m1_wsb = (const float*)d_in[7];
    const float* m1_wv = (const float*)d_in[8];
    const float* m2_wh = (const float*)d_in[9];
    const float* m2_wsw = (const float*)d_in[10];
    const float* m2_wsb = (const float*)d_in[11];
    const float* m2_wv = (const float*)d_in[12];
    const float* m3_wh = (const float*)d_in[13];
    const float* m3_wsw = (const float*)d_in[14];
    const float* m3_wsb = (const float*)d_in[15];
    const float* m3_wv = (const float*)d_in[16];
    const float* f1_wh = (const float*)d_in[17];
    const float* f1_wsw = (const float*)d_in[18];
    const float* f1_wsb = (const float*)d_in[19];
    const float* f1_wv = (const float*)d_in[20];
    const float* f2_wh = (const float*)d_in[21];
    const float* f2_wsw = (const float*)d_in[22];
    const float* f2_wsb = (const float*)d_in[23];
    const float* f2_wv = (const float*)d_in[24];
    const float* ln0_g = (const float*)d_in[25];
    const float* ln0_b = (const float*)d_in[26];
    const float* ln1_g = (const float*)d_in[27];
    const float* ln1_b = (const float*)d_in[28];

    const int N = in_sizes[0] / 128;
    const int E = in_sizes[2] / 2;

    double* agg_s = (double*)d_ws;                     // N*128 f64
    double* agg_v = agg_s + (size_t)N * 128;           // N*48  f64
    float* cnt    = (float*)(agg_v + (size_t)N * 48);  // N     f32
    unsigned short* pk =
        (unsigned short*)(((uintptr_t)(cnt + N) + 15) & ~(uintptr_t)15);
    const int S_P1E = 12288, S_M23 = 20480, S_MN = 32768, S_F1 = 81920;
    unsigned short* p1h = pk;            unsigned short* p1l = p1h + S_P1E;
    unsigned short* p2h = p1l + S_P1E;   unsigned short* p2l = p2h + S_M23;
    unsigned short* p3h = p2l + S_M23;   unsigned short* p3l = p3h + S_M23;
    unsigned short* pnh = p3l + S_M23;   unsigned short* pnl = pnh + S_MN;
    unsigned short* pf1h = pnl + S_MN;   unsigned short* pf1l = pf1h + S_F1;
    float* Pg  = (float*)(((uintptr_t)(pf1l + S_F1) + 15) & ~(uintptr_t)15);
    float* Q1g = Pg + (size_t)N * 256;
    float* Q3g = Q1g + (size_t)N * 100;

    hipMemsetAsync(d_ws, 0,
                   (size_t)N * 176 * sizeof(double) + (size_t)N * sizeof(float),
                   stream);

    pack_m1e<<<dim3((12288 + 255) / 256), dim3(256), 0, stream>>>(m1_wsw, p1h, p1l);
    pack_w<<<dim3((S_M23 + 255) / 256), dim3(256), 0, stream>>>(m2_wsw, p2h, p2l, 128, 144, 5);
    pack_w<<<dim3((S_M23 + 255) / 256), dim3(256), 0, stream>>>(m3_wsw, p3h, p3l, 128, 144, 5);
    pack_m1n<<<dim3((32768 + 255) / 256), dim3(256), 0, stream>>>(m1_wsw, pnh, pnl);
    pack_w<<<dim3((S_F1 + 255) / 256), dim3(256), 0, stream>>>(f1_wsw, pf1h, pf1l, 512, 160, 5);

    node_pre<<<dim3((N + 15) / 16), dim3(256), 0, stream>>>(
        s, v, m1_wh, m1_wsb, pnh, pnl, Pg, Q1g, Q3g, N);

    edge_kernel<<<dim3((E + 15) / 16), dim3(256), 0, stream>>>(
        eidx, es, ev,
        m1_wh, m1_wv,
        m2_wh, m2_wsb, m2_wv,
        m3_wh, m3_wsb, m3_wv,
        p1h, p1l, p2h, p2l, p3h, p3l,
        Pg, Q1g, Q3g,
        agg_s, agg_v, cnt, E);

    node_kernel<<<dim3((N + 7) / 8), dim3(128), 0, stream>>>(
        s, v,
        f1_wh, f1_wsb, f1_wv,
        f2_wh, f2_wsw, f2_wsb, f2_wv,
        ln0_g, ln0_b, ln1_g, ln1_b,
        pf1h, pf1l,
        agg_s, agg_v, cnt,
        (float*)d_out, N);
}

// Round 9
// 1403.921 us; speedup vs baseline: 1.3897x; 1.0018x over previous
//
#include <hip/hip_runtime.h>

#define EPSF 1e-8f

typedef __attribute__((ext_vector_type(8))) short short8;
typedef __attribute__((ext_vector_type(4))) short short4v;
typedef __attribute__((ext_vector_type(4))) float float4v;

// ---- fp32 -> bf16 hi/lo split (RNE) ---------------------------------------
__device__ __forceinline__ unsigned bfhi_bits(float x) {
    unsigned u = __float_as_uint(x);
    return (u + 0x7fffu + ((u >> 16) & 1u)) >> 16;
}
__device__ __forceinline__ float bits2f(unsigned b) { return __uint_as_float(b << 16); }
__device__ __forceinline__ void split_bf(float x, unsigned short& h, unsigned short& l) {
    unsigned hb = bfhi_bits(x);
    h = (unsigned short)hb;
    l = (unsigned short)bfhi_bits(x - bits2f(hb));
}

// ---------------------------------------------------------------------------
// matvec3_v: acc[t] += sum_h wrow[h] * prow[h*3+t], NH entries (mult of 4),
// prow 16B-aligned LDS. float4 loads; per-accumulator fma order identical to
// the scalar h-loop (h strictly increasing) -> bit-identical results.
// ---------------------------------------------------------------------------
template<int NH>
__device__ __forceinline__ void matvec3_v(const float* __restrict__ wrow,
                                          const float* prow,
                                          float& a0, float& a1, float& a2)
{
    #pragma unroll
    for (int g = 0; g < NH / 4; ++g) {
        const float4 f0 = ((const float4*)prow)[3 * g + 0];
        const float4 f1 = ((const float4*)prow)[3 * g + 1];
        const float4 f2 = ((const float4*)prow)[3 * g + 2];
        const float w0 = wrow[4 * g + 0], w1 = wrow[4 * g + 1];
        const float w2 = wrow[4 * g + 2], w3 = wrow[4 * g + 3];
        a0 = fmaf(w0, f0.x, a0); a1 = fmaf(w0, f0.y, a1); a2 = fmaf(w0, f0.z, a2);
        a0 = fmaf(w1, f0.w, a0); a1 = fmaf(w1, f1.x, a1); a2 = fmaf(w1, f1.y, a2);
        a0 = fmaf(w2, f1.z, a0); a1 = fmaf(w2, f1.w, a1); a2 = fmaf(w2, f2.x, a2);
        a0 = fmaf(w3, f2.y, a0); a1 = fmaf(w3, f2.z, a1); a2 = fmaf(w3, f2.w, a2);
    }
}

// ---------------------------------------------------------------------------
// Pack W[NO][K] fp32 (row-major) into MFMA B-fragment order, bf16 hi/lo.
// ---------------------------------------------------------------------------
__global__ void pack_w(const float* __restrict__ W, unsigned short* __restrict__ hi,
                       unsigned short* __restrict__ lo, int NO, int K, int steps) {
    const int gid = blockIdx.x * 256 + threadIdx.x;
    const int total = (NO >> 4) * steps * 512;
    if (gid >= total) return;
    const int j = gid & 7, l = (gid >> 3) & 63, rest = gid >> 9;
    const int t = rest % steps, nt = rest / steps;
    const int n = nt * 16 + (l & 15);
    const int k = t * 32 + ((l >> 4) << 3) + j;
    const float x = (k < K) ? W[(size_t)n * K + k] : 0.f;
    unsigned short h, lw;
    split_bf(x, h, lw);
    hi[gid] = h; lo[gid] = lw;
}

// pack m1 edge-part B: NO=128, K=96, steps=3.
__global__ void pack_m1e(const float* __restrict__ W, unsigned short* __restrict__ hi,
                         unsigned short* __restrict__ lo) {
    const int gid = blockIdx.x * 256 + threadIdx.x;
    if (gid >= 12288) return;
    const int j = gid & 7, l = (gid >> 3) & 63, rest = gid >> 9;
    const int t = rest % 3, nt = rest / 3;
    const int n = nt * 16 + (l & 15);
    const int k = t * 32 + ((l >> 4) << 3) + j;
    float x = 0.f;
    if (k < 32)      x = W[(size_t)n * 321 + 128 + k];
    else if (k < 65) x = W[(size_t)n * 321 + 288 + (k - 32)];
    unsigned short h, lw; split_bf(x, h, lw);
    hi[gid] = h; lo[gid] = lw;
}

// pack node-pre B: NO=256, K=128, steps=4.
__global__ void pack_m1n(const float* __restrict__ W, unsigned short* __restrict__ hi,
                         unsigned short* __restrict__ lo) {
    const int gid = blockIdx.x * 256 + threadIdx.x;
    if (gid >= 32768) return;
    const int j = gid & 7, l = (gid >> 3) & 63, rest = gid >> 9;
    const int t = rest & 3, nt = rest >> 2;
    const int n = nt * 16 + (l & 15);
    const int k = t * 32 + ((l >> 4) << 3) + j;
    const float x = (n < 128) ? W[(size_t)n * 321 + k]
                              : W[(size_t)(n - 128) * 321 + 160 + k];
    unsigned short h, lw; split_bf(x, h, lw);
    hi[gid] = h; lo[gid] = lw;
}

// ---------------------------------------------------------------------------
// 3-pass split-bf16 MFMA K-loop (validated).
// ---------------------------------------------------------------------------
template<int STEPS, int NTPW, int ASTR>
__device__ __forceinline__ void kloop(const unsigned short* PAh, const unsigned short* PAl,
    const unsigned short* __restrict__ wph, const unsigned short* __restrict__ wpl,
    float4v* acc, int lane, int wave)
{
    const int m = lane & 15, q = lane >> 4;
    for (int t = 0; t < STEPS; ++t) {
        const int k0 = t * 32 + q * 8;
        const short8 ah = *(const short8*)(PAh + m * ASTR + k0);
        const short8 al = *(const short8*)(PAl + m * ASTR + k0);
        #pragma unroll
        for (int i = 0; i < NTPW; ++i) {
            const int nt = wave * NTPW + i;
            const size_t off = ((size_t)(nt * STEPS + t) * 64 + lane) * 8;
            const short8 bh = *(const short8*)(wph + off);
            const short8 bl = *(const short8*)(wpl + off);
            acc[i] = __builtin_amdgcn_mfma_f32_16x16x32_bf16(ah, bh, acc[i], 0, 0, 0);
            acc[i] = __builtin_amdgcn_mfma_f32_16x16x32_bf16(al, bh, acc[i], 0, 0, 0);
            acc[i] = __builtin_amdgcn_mfma_f32_16x16x32_bf16(ah, bl, acc[i], 0, 0, 0);
        }
    }
}

// ===========================================================================
// node_pre (green in R5, verbatim)
// ===========================================================================
constexpr int PAS = 136;

__global__ __launch_bounds__(256)
void node_pre(const float* __restrict__ s, const float* __restrict__ v,
              const float* __restrict__ m1_wh, const float* __restrict__ m1_wsb,
              const unsigned short* __restrict__ pnh, const unsigned short* __restrict__ pnl,
              float* __restrict__ Pg, float* __restrict__ Q1g, float* __restrict__ Q3g,
              int N)
{
    __shared__ __align__(16) unsigned short Ah[16 * PAS], Al[16 * PAS];
    __shared__ __align__(16) float Vs[16 * 48];

    const int tid = threadIdx.x, lane = tid & 63, wave = tid >> 6;
    const int e = tid & 15, q16 = tid >> 4;
    const int n0 = blockIdx.x * 16;
    const int ne = min(n0 + e, N - 1);

    {
        const float* sp = s + (size_t)ne * 128 + q16 * 8;
        const float4 x = ((const float4*)sp)[0];
        const float4 y = ((const float4*)sp)[1];
        short8 hv, lv; unsigned short h, l;
        split_bf(x.x, h, l); hv[0] = h; lv[0] = l;
        split_bf(x.y, h, l); hv[1] = h; lv[1] = l;
        split_bf(x.z, h, l); hv[2] = h; lv[2] = l;
        split_bf(x.w, h, l); hv[3] = h; lv[3] = l;
        split_bf(y.x, h, l); hv[4] = h; lv[4] = l;
        split_bf(y.y, h, l); hv[5] = h; lv[5] = l;
        split_bf(y.z, h, l); hv[6] = h; lv[6] = l;
        split_bf(y.w, h, l); hv[7] = h; lv[7] = l;
        *(short8*)(Ah + e * PAS + q16 * 8) = hv;
        *(short8*)(Al + e * PAS + q16 * 8) = lv;
    }
    if (q16 < 12)
        ((float4*)(Vs + e * 48))[q16] = ((const float4*)(v + (size_t)ne * 48))[q16];
    __syncthreads();

    {
        float4v acc[4] = {{0,0,0,0},{0,0,0,0},{0,0,0,0},{0,0,0,0}};
        kloop<4, 4, PAS>(Ah, Al, pnh, pnl, acc, lane, wave);
        const int q = lane >> 4;
        #pragma unroll
        for (int i = 0; i < 4; ++i) {
            const int j = (wave * 4 + i) * 16 + (lane & 15);
            const float bias = (j < 128) ? m1_wsb[j] : 0.f;
            #pragma unroll
            for (int r = 0; r < 4; ++r) {
                const int m = q * 4 + r;
                if (n0 + m < N) Pg[(size_t)(n0 + m) * 256 + j] = acc[i][r] + bias;
            }
        }
    }
    #pragma unroll
    for (int k = 0; k < 7; ++k) {
        const int idx = tid + k * 256;
        if (idx < 16 * 99) {
            const int n = idx & 15, j = idx >> 4;
            const int h = j / 3, t = j - h * 3;
            const float* vb = Vs + n * 48 + t;
            const float* w = m1_wh + h * 33;
            float a1 = 0.f, a3 = 0.f;
            for (int c = 0; c < 16; ++c) {
                const float vv = vb[c * 3];
                a1 = fmaf(w[c], vv, a1);
                a3 = fmaf(w[17 + c], vv, a3);
            }
            const int nn = n0 + n;
            if (nn < N) {
                Q1g[(size_t)nn * 100 + j] = a1;
                Q3g[(size_t)nn * 100 + j] = a3;
            }
        }
    }
}

// ---------------------------------------------------------------------------
// Edge kernel: 16 edges / block, 256 threads (4 waves).
// R8-green structure + (a) per-thread eidx regs and pre-barrier P/es gathers
// (removes E1-barrier -> gather serialization; Q-loop still uses LDS idx),
// (b) float4 matvec3_v for the 5 B1/B2 read loops (bit-identical order).
// LDS 25856 B. fp64-atomic aggregation (deterministic).
// ---------------------------------------------------------------------------
constexpr int SA2 = 168;
constexpr int SBs = 168;
constexpr int SB1 = 100;
constexpr int SB2 = 52;
constexpr int SPS = 132;

__global__ __launch_bounds__(256)
void edge_kernel(const int* __restrict__ eidx,
                 const float* __restrict__ es, const float* __restrict__ ev,
                 const float* __restrict__ m1_wh, const float* __restrict__ m1_wv,
                 const float* __restrict__ m2_wh, const float* __restrict__ m2_wsb,
                 const float* __restrict__ m2_wv,
                 const float* __restrict__ m3_wh, const float* __restrict__ m3_wsb,
                 const float* __restrict__ m3_wv,
                 const unsigned short* __restrict__ p1h, const unsigned short* __restrict__ p1l,
                 const unsigned short* __restrict__ p2h, const unsigned short* __restrict__ p2l,
                 const unsigned short* __restrict__ p3h, const unsigned short* __restrict__ p3l,
                 const float* __restrict__ Pg, const float* __restrict__ Q1g,
                 const float* __restrict__ Q3g,
                 double* __restrict__ agg_s, double* __restrict__ agg_v,
                 float* __restrict__ cnt, int E)
{
    __shared__ __align__(16) unsigned short Ah[16 * SA2], Al[16 * SA2];
    __shared__ __align__(16) float SP[16 * SPS];
    __shared__ __align__(16) float B1[16 * SB1];
    __shared__ int ssrc[16], sgd[16], sdst[16], seid[16];

    unsigned short* PBh = Ah;      // overlay: PB == A (identical geometry)
    unsigned short* PBl = Al;
    float* B2 = SP;                // overlay: B2 in SP's first 3328 B

    const int tid = threadIdx.x, lane = tid & 63, wave = tid >> 6;
    const int e = tid & 15, q16 = tid >> 4;
    const int e0 = blockIdx.x * 16;

    // ---- pre-barrier: per-thread index regs; es split; pads; P gather -> SP
    const int eg_r = e0 + e;
    const int ee_r = (eg_r < E) ? eg_r : (E - 1);
    const int src_r = eidx[ee_r];
    const int dst_r = eidx[E + ee_r];

    if (q16 < 8) {
        const float4 x = ((const float4*)(es + (size_t)ee_r * 32))[q16];
        short4v hv, lv; unsigned short h, l;
        split_bf(x.x, h, l); hv[0] = h; lv[0] = l;
        split_bf(x.y, h, l); hv[1] = h; lv[1] = l;
        split_bf(x.z, h, l); hv[2] = h; lv[2] = l;
        split_bf(x.w, h, l); hv[3] = h; lv[3] = l;
        *(short4v*)(Ah + e * SA2 + 4 * q16) = hv;
        *(short4v*)(Al + e * SA2 + 4 * q16) = lv;
    }
    { const int c = 65 + q16; Ah[e * SA2 + c] = 0; Al[e * SA2 + c] = 0; }
    { const int c = 81 + q16; if (c < 96) { Ah[e * SA2 + c] = 0; Al[e * SA2 + c] = 0; } }
    {
        const float* P1 = Pg + (size_t)src_r * 256;
        const float* P3 = Pg + (size_t)dst_r * 256 + 128;
        const float4 a0 = ((const float4*)P1)[2 * q16];
        const float4 a1 = ((const float4*)P1)[2 * q16 + 1];
        const float4 b0 = ((const float4*)P3)[2 * q16];
        const float4 b1 = ((const float4*)P3)[2 * q16 + 1];
        float4 r0, r1;
        r0.x = a0.x + b0.x; r0.y = a0.y + b0.y; r0.z = a0.z + b0.z; r0.w = a0.w + b0.w;
        r1.x = a1.x + b1.x; r1.y = a1.y + b1.y; r1.z = a1.z + b1.z; r1.w = a1.w + b1.w;
        float4* o = (float4*)(SP + e * SPS + 8 * q16);
        o[0] = r0; o[1] = r1;
    }
    // E1: index table for the Q-loop / E12
    if (tid < 16) {
        const int eg = e0 + tid;
        const bool ok = (eg < E);
        const int ee = ok ? eg : (E - 1);
        seid[tid] = ee;
        ssrc[tid] = eidx[ee];
        const int d = eidx[E + ee];
        sgd[tid] = d;
        sdst[tid] = ok ? d : -1;
    }
    __syncthreads();

    // Q-loop: vh1 = Q1[src]+Q3[dst]+wh16*ev -> B1; vn1 -> A[32,65)
    #pragma unroll
    for (int k = 0; k < 3; ++k) {
        const int idx = tid + k * 256;
        if (idx < 528) {
            const int h = idx >> 4, e2 = idx & 15;
            const float* q1 = Q1g + (size_t)ssrc[e2] * 100 + h * 3;
            const float* q3 = Q3g + (size_t)sgd[e2] * 100 + h * 3;
            const float* evp = ev + (size_t)seid[e2] * 3;
            const float w16 = m1_wh[h * 33 + 16];
            const float v0 = q1[0] + q3[0] + w16 * evp[0];
            const float v1 = q1[1] + q3[1] + w16 * evp[1];
            const float v2 = q1[2] + q3[2] + w16 * evp[2];
            float* o = B1 + e2 * SB1 + h * 3;
            o[0] = v0; o[1] = v1; o[2] = v2;
            const float vn = sqrtf(fmaxf(v0 * v0 + v1 * v1 + v2 * v2, EPSF));
            unsigned short hh, ll; split_bf(vn, hh, ll);
            Ah[e2 * SA2 + 32 + h] = hh; Al[e2 * SA2 + 32 + h] = ll;
        }
    }
    __syncthreads();

    // E5a: m1 MFMA (K=96) reads A
    float4v acc1[2] = {{0,0,0,0},{0,0,0,0}};
    kloop<3, 2, SA2>(Ah, Al, p1h, p1l, acc1, lane, wave);
    __syncthreads();   // all waves done reading A before PB(=A) is written

    // E5b: +SP -> relu -> PB(=A)[*][0,128)
    {
        const int q = lane >> 4;
        #pragma unroll
        for (int i = 0; i < 2; ++i) {
            const int n = (wave * 2 + i) * 16 + (lane & 15);
            #pragma unroll
            for (int r = 0; r < 4; ++r) {
                const int m = q * 4 + r;
                const float x = fmaxf(acc1[i][r] + SP[m * SPS + n], 0.f);
                unsigned short h, l; split_bf(x, h, l);
                PBh[m * SBs + n] = h; PBl[m * SBs + n] = l;
            }
        }
    }
    __syncthreads();   // all SP reads done before B2(=SP) is written

    // E5c: vout1 -> B2(=SP)   (33 h: 32 vectorized + tail h=32)
    {
        const int o = q16;
        const float* wrow = m1_wv + o * 33;
        const float* prow = B1 + e * SB1;
        float a0 = 0.f, a1 = 0.f, a2 = 0.f;
        matvec3_v<32>(wrow, prow, a0, a1, a2);
        const float w32 = wrow[32];
        a0 = fmaf(w32, prow[96], a0); a1 = fmaf(w32, prow[97], a1); a2 = fmaf(w32, prow[98], a2);
        const float nrm = sqrtf(fmaxf(a0 * a0 + a1 * a1 + a2 * a2, EPSF));
        const float sg = 1.f / (1.f + __expf(-nrm));
        float* p2 = B2 + e * SB2 + o * 3;
        p2[0] = a0 * sg; p2[1] = a1 * sg; p2[2] = a2 * sg;
    }
    __syncthreads();

    // E6: vh2 -> B1; vn2 -> PB[128,144); zero PB[144,160)
    {
        const int h = q16;
        float a0 = 0.f, a1 = 0.f, a2 = 0.f;
        matvec3_v<16>(m2_wh + h * 16, B2 + e * SB2, a0, a1, a2);
        float* o = B1 + e * SB1 + h * 3;
        o[0] = a0; o[1] = a1; o[2] = a2;
        const float vn = sqrtf(fmaxf(a0 * a0 + a1 * a1 + a2 * a2, EPSF));
        unsigned short hh, ll; split_bf(vn, hh, ll);
        PBh[e * SBs + 128 + h] = hh; PBl[e * SBs + 128 + h] = ll;
        PBh[e * SBs + 144 + h] = 0;  PBl[e * SBs + 144 + h] = 0;
    }
    __syncthreads();

    // E8a: m2 MFMA (K=160) reads PB(=A)
    float4v acc2[2] = {{0,0,0,0},{0,0,0,0}};
    kloop<5, 2, SBs>(PBh, PBl, p2h, p2l, acc2, lane, wave);
    __syncthreads();   // all waves done reading PB before A is rewritten

    // E8b: relu -> A[*][0,128); vout2 -> B2
    {
        const int q = lane >> 4;
        #pragma unroll
        for (int i = 0; i < 2; ++i) {
            const int n = (wave * 2 + i) * 16 + (lane & 15);
            const float bias = m2_wsb[n];
            #pragma unroll
            for (int r = 0; r < 4; ++r) {
                const int m = q * 4 + r;
                const float x = fmaxf(acc2[i][r] + bias, 0.f);
                unsigned short h, l; split_bf(x, h, l);
                Ah[m * SA2 + n] = h; Al[m * SA2 + n] = l;
            }
        }
    }
    {
        const int o = q16;
        float a0 = 0.f, a1 = 0.f, a2 = 0.f;
        matvec3_v<16>(m2_wv + o * 16, B1 + e * SB1, a0, a1, a2);
        const float nrm = sqrtf(fmaxf(a0 * a0 + a1 * a1 + a2 * a2, EPSF));
        const float sg = 1.f / (1.f + __expf(-nrm));
        float* p2 = B2 + e * SB2 + o * 3;
        p2[0] = a0 * sg; p2[1] = a1 * sg; p2[2] = a2 * sg;
    }
    __syncthreads();

    // E9: vh3 -> B1; vn3 -> A[128,144); zero A[144,160)
    {
        const int h = q16;
        float a0 = 0.f, a1 = 0.f, a2 = 0.f;
        matvec3_v<16>(m3_wh + h * 16, B2 + e * SB2, a0, a1, a2);
        float* o = B1 + e * SB1 + h * 3;
        o[0] = a0; o[1] = a1; o[2] = a2;
        const float vn = sqrtf(fmaxf(a0 * a0 + a1 * a1 + a2 * a2, EPSF));
        unsigned short hh, ll; split_bf(vn, hh, ll);
        Ah[e * SA2 + 128 + h] = hh; Al[e * SA2 + 128 + h] = ll;
        Ah[e * SA2 + 144 + h] = 0;  Al[e * SA2 + 144 + h] = 0;
    }
    __syncthreads();

    // E11: m3 MFMA (K=160, no act) reads A; vout3 -> B2 (disjoint from A)
    float4v acc3[2] = {{0,0,0,0},{0,0,0,0}};
    kloop<5, 2, SA2>(Ah, Al, p3h, p3l, acc3, lane, wave);
    {
        const int o = q16;
        float a0 = 0.f, a1 = 0.f, a2 = 0.f;
        matvec3_v<16>(m3_wv + o * 16, B1 + e * SB1, a0, a1, a2);
        float* p2 = B2 + e * SB2 + o * 3;
        p2[0] = a0; p2[1] = a1; p2[2] = a2;
    }
    __syncthreads();

    // E12: scatter-add (fp64 atomics -> order-invariant)
    {
        const int q = lane >> 4;
        #pragma unroll
        for (int i = 0; i < 2; ++i) {
            const int n = (wave * 2 + i) * 16 + (lane & 15);
            const float bias = m3_wsb[n];
            #pragma unroll
            for (int r = 0; r < 4; ++r) {
                const int m = q * 4 + r;
                const int d = sdst[m];
                if (d >= 0) atomicAdd(&agg_s[(size_t)d * 128 + n], (double)(acc3[i][r] + bias));
            }
        }
    }
    #pragma unroll
    for (int it = 0; it < 3; ++it) {
        const int j = q16 + 16 * it;
        const int d = sdst[e];
        if (d >= 0) atomicAdd(&agg_v[(size_t)d * 48 + j], (double)B2[e * SB2 + j]);
    }
    if (tid < 16 && sdst[tid] >= 0) atomicAdd(&cnt[sdst[tid]], 1.0f);
}

// ===========================================================================
// layer_normT: wave processes NE nodes (proven math, verbatim per node)
// ===========================================================================
template<int NE, int SSTR, int VSTR>
__device__ __forceinline__ void layer_normT(float* S, float* V,
    const float* __restrict__ g, const float* __restrict__ b, float* red, int lane)
{
    #pragma unroll
    for (int e = 0; e < NE; ++e) {
        float x0 = S[e * SSTR + lane], x1 = S[e * SSTR + 64 + lane];
        float sum = x0 + x1;
        #pragma unroll
        for (int off = 32; off > 0; off >>= 1) sum += __shfl_xor(sum, off, 64);
        const float mu = sum * (1.f / 128.f);
        const float d0 = x0 - mu, d1 = x1 - mu;
        float vs = d0 * d0 + d1 * d1;
        #pragma unroll
        for (int off = 32; off > 0; off >>= 1) vs += __shfl_xor(vs, off, 64);
        const float rstd = rsqrtf(vs * (1.f / 128.f) + 1e-5f);
        S[e * SSTR + lane]      = d0 * rstd * g[lane]      + b[lane];
        S[e * SSTR + 64 + lane] = d1 * rstd * g[lane + 64] + b[lane + 64];

        if (lane < 16) {
            const float a = V[e * VSTR + lane * 3], bb = V[e * VSTR + lane * 3 + 1],
                        cc = V[e * VSTR + lane * 3 + 2];
            const float vn = fmaxf(a * a + bb * bb + cc * cc, EPSF);
            red[lane]      = vn;
            red[16 + lane] = (vn > 2.f * EPSF) ? 1.f : 0.f;
        }
        __syncthreads();
        float sn = 0.f, sm = 0.f;
        #pragma unroll
        for (int i = 0; i < 16; ++i) { sn += red[i] * red[16 + i]; sm += red[16 + i]; }
        const float rvm = rsqrtf(sn / (EPSF + sm) + EPSF);
        if (lane < 48) V[e * VSTR + lane] = red[16 + lane / 3] * V[e * VSTR + lane] * rvm;
        __syncthreads();
    }
}

// ===========================================================================
// Node kernel (R7-green structure): 8 nodes/block, 128 threads, 2 waves.
// Changes: NNH 98->100 (16B-aligned rows) + matvec3_v for vh1/fv1/vh2/fv2
// (bit-identical fma order). LDS 35328 B -> 4 blocks/CU.
// ===========================================================================
constexpr int NNS  = 132;
constexpr int NNV  = 52;
constexpr int NNH  = 100;
constexpr int NA1n = 168;
constexpr int FSS  = 544;

__global__ __launch_bounds__(128)
void node_kernel(const float* __restrict__ s, const float* __restrict__ v,
                 const float* __restrict__ f1_wh, const float* __restrict__ f1_wsb,
                 const float* __restrict__ f1_wv,
                 const float* __restrict__ f2_wh, const float* __restrict__ f2_wsw,
                 const float* __restrict__ f2_wsb, const float* __restrict__ f2_wv,
                 const float* __restrict__ ln0_g, const float* __restrict__ ln0_b,
                 const float* __restrict__ ln1_g, const float* __restrict__ ln1_b,
                 const unsigned short* __restrict__ pf1h, const unsigned short* __restrict__ pf1l,
                 const double* __restrict__ agg_s, const double* __restrict__ agg_v,
                 const float* __restrict__ cnt,
                 float* __restrict__ out, int N)
{
    __shared__ __align__(16) unsigned short UBh[8 * NA1n], UBl[8 * NA1n];
    __shared__ __align__(16) float FS[8 * FSS];
    __shared__ __align__(16) float S1f[8 * NNS];
    __shared__ __align__(16) float V1f[8 * NNV];
    __shared__ __align__(16) float VH[8 * NNH];
    __shared__ __align__(16) float FV[8 * NNH];
    __shared__ float red[2 * 32];

    const int tid = threadIdx.x, lane = tid & 63, wave = tid >> 6;
    const int e = tid & 7, qq = tid >> 3;
    const int n0 = blockIdx.x * 8;

    bool oks[4];
    #pragma unroll
    for (int e4 = 0; e4 < 4; ++e4) {
        const int idx = wave * 4 + e4;
        const int ng = n0 + idx;
        oks[e4] = (ng < N);
        const int n = oks[e4] ? ng : (N - 1);
        const double inv = 1.0 / (double)fmaxf(cnt[n], 1.f);
        if (lane < 32) {
            const float4 a = ((const float4*)(s + (size_t)n * 128))[lane];
            const double2 b0 = ((const double2*)(agg_s + (size_t)n * 128))[2 * lane];
            const double2 b1 = ((const double2*)(agg_s + (size_t)n * 128))[2 * lane + 1];
            float4 r;
            r.x = (float)((double)a.x + b0.x * inv);
            r.y = (float)((double)a.y + b0.y * inv);
            r.z = (float)((double)a.z + b1.x * inv);
            r.w = (float)((double)a.w + b1.y * inv);
            ((float4*)(S1f + idx * NNS))[lane] = r;
        }
        if (lane < 12) {
            const float4 a = ((const float4*)(v + (size_t)n * 48))[lane];
            const double2 b0 = ((const double2*)(agg_v + (size_t)n * 48))[2 * lane];
            const double2 b1 = ((const double2*)(agg_v + (size_t)n * 48))[2 * lane + 1];
            float4 r;
            r.x = (float)((double)a.x + b0.x * inv);
            r.y = (float)((double)a.y + b0.y * inv);
            r.z = (float)((double)a.z + b1.x * inv);
            r.w = (float)((double)a.w + b1.y * inv);
            ((float4*)(V1f + idx * NNV))[lane] = r;
        }
    }
    __syncthreads();

    layer_normT<4, NNS, NNV>(S1f + wave * 4 * NNS, V1f + wave * 4 * NNV,
                             ln0_g, ln0_b, red + wave * 32, lane);

    {
        const float* sp = S1f + e * NNS + qq * 8;
        short8 hv, lv; unsigned short h, l;
        #pragma unroll
        for (int j = 0; j < 8; ++j) { split_bf(sp[j], h, l); hv[j] = h; lv[j] = l; }
        *(short8*)(UBh + e * NA1n + qq * 8) = hv;
        *(short8*)(UBl + e * NA1n + qq * 8) = lv;
    }
    #pragma unroll
    for (int hi = 0; hi < 2; ++hi) {
        const int h = qq + 16 * hi;
        float a0 = 0.f, a1 = 0.f, a2 = 0.f;
        matvec3_v<16>(f1_wh + h * 16, V1f + e * NNV, a0, a1, a2);
        float* o = VH + e * NNH + h * 3;
        o[0] = a0; o[1] = a1; o[2] = a2;
        const float vn = sqrtf(fmaxf(a0 * a0 + a1 * a1 + a2 * a2, EPSF));
        unsigned short hh, ll; split_bf(vn, hh, ll);
        UBh[e * NA1n + 128 + h] = hh; UBl[e * NA1n + 128 + h] = ll;
    }
    __syncthreads();

    {
        float4v acc1[16];
        #pragma unroll
        for (int i = 0; i < 16; ++i) acc1[i] = (float4v){0.f, 0.f, 0.f, 0.f};
        kloop<5, 16, NA1n>(UBh, UBl, pf1h, pf1l, acc1, lane, wave);
        const int q = lane >> 4;
        #pragma unroll
        for (int i = 0; i < 16; ++i) {
            const int n = (wave * 16 + i) * 16 + (lane & 15);
            const float bias = f1_wsb[n];
            #pragma unroll
            for (int r = 0; r < 4; ++r) {
                const int m = q * 4 + r;
                if (m < 8) FS[m * FSS + n] = fmaxf(acc1[i][r] + bias, 0.f);
            }
        }
    }
    #pragma unroll
    for (int oi = 0; oi < 2; ++oi) {
        const int o = qq + 16 * oi;
        float a0 = 0.f, a1 = 0.f, a2 = 0.f;
        matvec3_v<32>(f1_wv + o * 32, VH + e * NNH, a0, a1, a2);
        const float nrm = sqrtf(fmaxf(a0 * a0 + a1 * a1 + a2 * a2, EPSF));
        const float sg = 1.f / (1.f + __expf(-nrm));
        float* p2 = FV + e * NNH + o * 3;
        p2[0] = a0 * sg; p2[1] = a1 * sg; p2[2] = a2 * sg;
    }
    __syncthreads();

    #pragma unroll
    for (int hi = 0; hi < 2; ++hi) {
        const int h = qq + 16 * hi;
        float a0 = 0.f, a1 = 0.f, a2 = 0.f;
        matvec3_v<32>(f2_wh + h * 32, FV + e * NNH, a0, a1, a2);
        float* o = VH + e * NNH + h * 3;
        o[0] = a0; o[1] = a1; o[2] = a2;
        FS[e * FSS + 512 + h] = sqrtf(fmaxf(a0 * a0 + a1 * a1 + a2 * a2, EPSF));
    }
    __syncthreads();

    {
        float acc[2][4];
        #pragma unroll
        for (int of = 0; of < 2; ++of) {
            const float bias = f2_wsb[lane + of * 64];
            #pragma unroll
            for (int e4 = 0; e4 < 4; ++e4) acc[of][e4] = bias;
        }
        for (int k = 0; k < FSS; k += 4) {
            float4 sv[4];
            #pragma unroll
            for (int e4 = 0; e4 < 4; ++e4)
                sv[e4] = *(const float4*)&FS[(wave * 4 + e4) * FSS + k];
            #pragma unroll
            for (int of = 0; of < 2; ++of) {
                const float4 w = *(const float4*)&f2_wsw[(size_t)(lane + of * 64) * 544 + k];
                #pragma unroll
                for (int e4 = 0; e4 < 4; ++e4) {
                    acc[of][e4] = fmaf(w.x, sv[e4].x, acc[of][e4]);
                    acc[of][e4] = fmaf(w.y, sv[e4].y, acc[of][e4]);
                    acc[of][e4] = fmaf(w.z, sv[e4].z, acc[of][e4]);
                    acc[of][e4] = fmaf(w.w, sv[e4].w, acc[of][e4]);
                }
            }
        }
        #pragma unroll
        for (int of = 0; of < 2; ++of)
            #pragma unroll
            for (int e4 = 0; e4 < 4; ++e4)
                S1f[(wave * 4 + e4) * NNS + lane + of * 64] += acc[of][e4];
    }
    {
        const int o = qq;
        float a0 = 0.f, a1 = 0.f, a2 = 0.f;
        matvec3_v<32>(f2_wv + o * 32, VH + e * NNH, a0, a1, a2);
        float* p2 = V1f + e * NNV + o * 3;
        p2[0] += a0; p2[1] += a1; p2[2] += a2;
    }
    __syncthreads();

    layer_normT<4, NNS, NNV>(S1f + wave * 4 * NNS, V1f + wave * 4 * NNV,
                             ln1_g, ln1_b, red + wave * 32, lane);

    #pragma unroll
    for (int e4 = 0; e4 < 4; ++e4) {
        if (!oks[e4]) continue;
        const int idx = wave * 4 + e4;
        const int n = n0 + idx;
        if (lane < 32)
            ((float4*)(out + (size_t)n * 128))[lane] = ((const float4*)(S1f + idx * NNS))[lane];
        if (lane < 12)
            ((float4*)(out + (size_t)N * 128 + (size_t)n * 48))[lane] =
                ((const float4*)(V1f + idx * NNV))[lane];
    }
}

// ---------------------------------------------------------------------------
extern "C" void kernel_launch(void* const* d_in, const int* in_sizes, int n_in,
                              void* d_out, int out_size, void* d_ws, size_t ws_size,
                              hipStream_t stream)
{
    const float* s    = (const float*)d_in[0];
    const float* v    = (const float*)d_in[1];
    const int*   eidx = (const int*)d_in[2];
    const float* es   = (const float*)d_in[3];
    const float* ev   = (const float*)d_in[4];
    const float* m1_wh = (const float*)d_in[5];
    const float* m1_wsw = (const float*)d_in[6];
    const float* m1_wsb = (const float*)d_in[7];
    const float* m1_wv = (const float*)d_in[8];
    const float* m2_wh = (const float*)d_in[9];
    const float* m2_wsw = (const float*)d_in[10];
    const float* m2_wsb = (const float*)d_in[11];
    const float* m2_wv = (const float*)d_in[12];
    const float* m3_wh = (const float*)d_in[13];
    const float* m3_wsw = (const float*)d_in[14];
    const float* m3_wsb = (const float*)d_in[15];
    const float* m3_wv = (const float*)d_in[16];
    const float* f1_wh = (const float*)d_in[17];
    const float* f1_wsw = (const float*)d_in[18];
    const float* f1_wsb = (const float*)d_in[19];
    const float* f1_wv = (const float*)d_in[20];
    const float* f2_wh = (const float*)d_in[21];
    const float* f2_wsw = (const float*)d_in[22];
    const float* f2_wsb = (const float*)d_in[23];
    const float* f2_wv = (const float*)d_in[24];
    const float* ln0_g = (const float*)d_in[25];
    const float* ln0_b = (const float*)d_in[26];
    const float* ln1_g = (const float*)d_in[27];
    const float* ln1_b = (const float*)d_in[28];

    const int N = in_sizes[0] / 128;
    const int E = in_sizes[2] / 2;

    double* agg_s = (double*)d_ws;                     // N*128 f64
    double* agg_v = agg_s + (size_t)N * 128;           // N*48  f64
    float* cnt    = (float*)(agg_v + (size_t)N * 48);  // N     f32
    unsigned short* pk =
        (unsigned short*)(((uintptr_t)(cnt + N) + 15) & ~(uintptr_t)15);
    const int S_P1E = 12288, S_M23 = 20480, S_MN = 32768, S_F1 = 81920;
    unsigned short* p1h = pk;            unsigned short* p1l = p1h + S_P1E;
    unsigned short* p2h = p1l + S_P1E;   unsigned short* p2l = p2h + S_M23;
    unsigned short* p3h = p2l + S_M23;   unsigned short* p3l = p3h + S_M23;
    unsigned short* pnh = p3l + S_M23;   unsigned short* pnl = pnh + S_MN;
    unsigned short* pf1h = pnl + S_MN;   unsigned short* pf1l = pf1h + S_F1;
    float* Pg  = (float*)(((uintptr_t)(pf1l + S_F1) + 15) & ~(uintptr_t)15);
    float* Q1g = Pg + (size_t)N * 256;
    float* Q3g = Q1g + (size_t)N * 100;

    hipMemsetAsync(d_ws, 0,
                   (size_t)N * 176 * sizeof(double) + (size_t)N * sizeof(float),
                   stream);

    pack_m1e<<<dim3((12288 + 255) / 256), dim3(256), 0, stream>>>(m1_wsw, p1h, p1l);
    pack_w<<<dim3((S_M23 + 255) / 256), dim3(256), 0, stream>>>(m2_wsw, p2h, p2l, 128, 144, 5);
    pack_w<<<dim3((S_M23 + 255) / 256), dim3(256), 0, stream>>>(m3_wsw, p3h, p3l, 128, 144, 5);
    pack_m1n<<<dim3((32768 + 255) / 256), dim3(256), 0, stream>>>(m1_wsw, pnh, pnl);
    pack_w<<<dim3((S_F1 + 255) / 256), dim3(256), 0, stream>>>(f1_wsw, pf1h, pf1l, 512, 160, 5);

    node_pre<<<dim3((N + 15) / 16), dim3(256), 0, stream>>>(
        s, v, m1_wh, m1_wsb, pnh, pnl, Pg, Q1g, Q3g, N);

    edge_kernel<<<dim3((E + 15) / 16), dim3(256), 0, stream>>>(
        eidx, es, ev,
        m1_wh, m1_wv,
        m2_wh, m2_wsb, m2_wv,
        m3_wh, m3_wsb, m3_wv,
        p1h, p1l, p2h, p2l, p3h, p3l,
        Pg, Q1g, Q3g,
        agg_s, agg_v, cnt, E);

    node_kernel<<<dim3((N + 7) / 8), dim3(128), 0, stream>>>(
        s, v,
        f1_wh, f1_wsb, f1_wv,
        f2_wh, f2_wsw, f2_wsb, f2_wv,
        ln0_g, ln0_b, ln1_g, ln1_b,
        pf1h, pf1l,
        agg_s, agg_v, cnt,
        (float*)d_out, N);
}

// Round 10
// 1247.167 us; speedup vs baseline: 1.5643x; 1.1257x over previous
//
#include <hip/hip_runtime.h>

#define EPSF 1e-8f

typedef __attribute__((ext_vector_type(8))) short short8;
typedef __attribute__((ext_vector_type(4))) short short4v;
typedef __attribute__((ext_vector_type(4))) float float4v;

// ---- fp32 -> bf16 hi/lo split (RNE) ---------------------------------------
__device__ __forceinline__ unsigned bfhi_bits(float x) {
    unsigned u = __float_as_uint(x);
    return (u + 0x7fffu + ((u >> 16) & 1u)) >> 16;
}
__device__ __forceinline__ float bits2f(unsigned b) { return __uint_as_float(b << 16); }
__device__ __forceinline__ void split_bf(float x, unsigned short& h, unsigned short& l) {
    unsigned hb = bfhi_bits(x);
    h = (unsigned short)hb;
    l = (unsigned short)bfhi_bits(x - bits2f(hb));
}

// ---------------------------------------------------------------------------
// matvec3_v: acc[t] += sum_h wrow[h] * prow[h*3+t], NH entries (mult of 4),
// prow 16B-aligned LDS. float4 loads; per-accumulator fma order identical to
// the scalar h-loop (h strictly increasing) -> bit-identical results.
// ---------------------------------------------------------------------------
template<int NH>
__device__ __forceinline__ void matvec3_v(const float* __restrict__ wrow,
                                          const float* prow,
                                          float& a0, float& a1, float& a2)
{
    #pragma unroll
    for (int g = 0; g < NH / 4; ++g) {
        const float4 f0 = ((const float4*)prow)[3 * g + 0];
        const float4 f1 = ((const float4*)prow)[3 * g + 1];
        const float4 f2 = ((const float4*)prow)[3 * g + 2];
        const float w0 = wrow[4 * g + 0], w1 = wrow[4 * g + 1];
        const float w2 = wrow[4 * g + 2], w3 = wrow[4 * g + 3];
        a0 = fmaf(w0, f0.x, a0); a1 = fmaf(w0, f0.y, a1); a2 = fmaf(w0, f0.z, a2);
        a0 = fmaf(w1, f0.w, a0); a1 = fmaf(w1, f1.x, a1); a2 = fmaf(w1, f1.y, a2);
        a0 = fmaf(w2, f1.z, a0); a1 = fmaf(w2, f1.w, a1); a2 = fmaf(w2, f2.x, a2);
        a0 = fmaf(w3, f2.y, a0); a1 = fmaf(w3, f2.z, a1); a2 = fmaf(w3, f2.w, a2);
    }
}

// ---------------------------------------------------------------------------
// Pack W[NO][K] fp32 (row-major) into MFMA B-fragment order, bf16 hi/lo.
// ---------------------------------------------------------------------------
__global__ void pack_w(const float* __restrict__ W, unsigned short* __restrict__ hi,
                       unsigned short* __restrict__ lo, int NO, int K, int steps) {
    const int gid = blockIdx.x * 256 + threadIdx.x;
    const int total = (NO >> 4) * steps * 512;
    if (gid >= total) return;
    const int j = gid & 7, l = (gid >> 3) & 63, rest = gid >> 9;
    const int t = rest % steps, nt = rest / steps;
    const int n = nt * 16 + (l & 15);
    const int k = t * 32 + ((l >> 4) << 3) + j;
    const float x = (k < K) ? W[(size_t)n * K + k] : 0.f;
    unsigned short h, lw;
    split_bf(x, h, lw);
    hi[gid] = h; lo[gid] = lw;
}

// pack m1 edge-part B: NO=128, K=96, steps=3.
__global__ void pack_m1e(const float* __restrict__ W, unsigned short* __restrict__ hi,
                         unsigned short* __restrict__ lo) {
    const int gid = blockIdx.x * 256 + threadIdx.x;
    if (gid >= 12288) return;
    const int j = gid & 7, l = (gid >> 3) & 63, rest = gid >> 9;
    const int t = rest % 3, nt = rest / 3;
    const int n = nt * 16 + (l & 15);
    const int k = t * 32 + ((l >> 4) << 3) + j;
    float x = 0.f;
    if (k < 32)      x = W[(size_t)n * 321 + 128 + k];
    else if (k < 65) x = W[(size_t)n * 321 + 288 + (k - 32)];
    unsigned short h, lw; split_bf(x, h, lw);
    hi[gid] = h; lo[gid] = lw;
}

// pack node-pre B: NO=256, K=128, steps=4.
__global__ void pack_m1n(const float* __restrict__ W, unsigned short* __restrict__ hi,
                         unsigned short* __restrict__ lo) {
    const int gid = blockIdx.x * 256 + threadIdx.x;
    if (gid >= 32768) return;
    const int j = gid & 7, l = (gid >> 3) & 63, rest = gid >> 9;
    const int t = rest & 3, nt = rest >> 2;
    const int n = nt * 16 + (l & 15);
    const int k = t * 32 + ((l >> 4) << 3) + j;
    const float x = (n < 128) ? W[(size_t)n * 321 + k]
                              : W[(size_t)(n - 128) * 321 + 160 + k];
    unsigned short h, lw; split_bf(x, h, lw);
    hi[gid] = h; lo[gid] = lw;
}

// ---------------------------------------------------------------------------
// 3-pass split-bf16 MFMA K-loop (validated).  MCLAMP masks the A-row index
// (use 7 when the A buffer has only 8 rows: lanes 8-15 re-read rows 0-7,
// producing garbage-but-finite C rows 8-15 that the caller discards).
// ---------------------------------------------------------------------------
template<int STEPS, int NTPW, int ASTR, int MCLAMP = 15>
__device__ __forceinline__ void kloop(const unsigned short* PAh, const unsigned short* PAl,
    const unsigned short* __restrict__ wph, const unsigned short* __restrict__ wpl,
    float4v* acc, int lane, int wave)
{
    const int m = (lane & 15) & MCLAMP, q = lane >> 4;
    for (int t = 0; t < STEPS; ++t) {
        const int k0 = t * 32 + q * 8;
        const short8 ah = *(const short8*)(PAh + m * ASTR + k0);
        const short8 al = *(const short8*)(PAl + m * ASTR + k0);
        #pragma unroll
        for (int i = 0; i < NTPW; ++i) {
            const int nt = wave * NTPW + i;
            const size_t off = ((size_t)(nt * STEPS + t) * 64 + lane) * 8;
            const short8 bh = *(const short8*)(wph + off);
            const short8 bl = *(const short8*)(wpl + off);
            acc[i] = __builtin_amdgcn_mfma_f32_16x16x32_bf16(ah, bh, acc[i], 0, 0, 0);
            acc[i] = __builtin_amdgcn_mfma_f32_16x16x32_bf16(al, bh, acc[i], 0, 0, 0);
            acc[i] = __builtin_amdgcn_mfma_f32_16x16x32_bf16(ah, bl, acc[i], 0, 0, 0);
        }
    }
}

// ===========================================================================
// node_pre (green in R5, verbatim)
// ===========================================================================
constexpr int PAS = 136;

__global__ __launch_bounds__(256)
void node_pre(const float* __restrict__ s, const float* __restrict__ v,
              const float* __restrict__ m1_wh, const float* __restrict__ m1_wsb,
              const unsigned short* __restrict__ pnh, const unsigned short* __restrict__ pnl,
              float* __restrict__ Pg, float* __restrict__ Q1g, float* __restrict__ Q3g,
              int N)
{
    __shared__ __align__(16) unsigned short Ah[16 * PAS], Al[16 * PAS];
    __shared__ __align__(16) float Vs[16 * 48];

    const int tid = threadIdx.x, lane = tid & 63, wave = tid >> 6;
    const int e = tid & 15, q16 = tid >> 4;
    const int n0 = blockIdx.x * 16;
    const int ne = min(n0 + e, N - 1);

    {
        const float* sp = s + (size_t)ne * 128 + q16 * 8;
        const float4 x = ((const float4*)sp)[0];
        const float4 y = ((const float4*)sp)[1];
        short8 hv, lv; unsigned short h, l;
        split_bf(x.x, h, l); hv[0] = h; lv[0] = l;
        split_bf(x.y, h, l); hv[1] = h; lv[1] = l;
        split_bf(x.z, h, l); hv[2] = h; lv[2] = l;
        split_bf(x.w, h, l); hv[3] = h; lv[3] = l;
        split_bf(y.x, h, l); hv[4] = h; lv[4] = l;
        split_bf(y.y, h, l); hv[5] = h; lv[5] = l;
        split_bf(y.z, h, l); hv[6] = h; lv[6] = l;
        split_bf(y.w, h, l); hv[7] = h; lv[7] = l;
        *(short8*)(Ah + e * PAS + q16 * 8) = hv;
        *(short8*)(Al + e * PAS + q16 * 8) = lv;
    }
    if (q16 < 12)
        ((float4*)(Vs + e * 48))[q16] = ((const float4*)(v + (size_t)ne * 48))[q16];
    __syncthreads();

    {
        float4v acc[4] = {{0,0,0,0},{0,0,0,0},{0,0,0,0},{0,0,0,0}};
        kloop<4, 4, PAS>(Ah, Al, pnh, pnl, acc, lane, wave);
        const int q = lane >> 4;
        #pragma unroll
        for (int i = 0; i < 4; ++i) {
            const int j = (wave * 4 + i) * 16 + (lane & 15);
            const float bias = (j < 128) ? m1_wsb[j] : 0.f;
            #pragma unroll
            for (int r = 0; r < 4; ++r) {
                const int m = q * 4 + r;
                if (n0 + m < N) Pg[(size_t)(n0 + m) * 256 + j] = acc[i][r] + bias;
            }
        }
    }
    #pragma unroll
    for (int k = 0; k < 7; ++k) {
        const int idx = tid + k * 256;
        if (idx < 16 * 99) {
            const int n = idx & 15, j = idx >> 4;
            const int h = j / 3, t = j - h * 3;
            const float* vb = Vs + n * 48 + t;
            const float* w = m1_wh + h * 33;
            float a1 = 0.f, a3 = 0.f;
            for (int c = 0; c < 16; ++c) {
                const float vv = vb[c * 3];
                a1 = fmaf(w[c], vv, a1);
                a3 = fmaf(w[17 + c], vv, a3);
            }
            const int nn = n0 + n;
            if (nn < N) {
                Q1g[(size_t)nn * 100 + j] = a1;
                Q3g[(size_t)nn * 100 + j] = a3;
            }
        }
    }
}

// ---------------------------------------------------------------------------
// Edge kernel (green in R9, verbatim): 16 edges / block, 256 threads.
// ---------------------------------------------------------------------------
constexpr int SA2 = 168;
constexpr int SBs = 168;
constexpr int SB1 = 100;
constexpr int SB2 = 52;
constexpr int SPS = 132;

__global__ __launch_bounds__(256)
void edge_kernel(const int* __restrict__ eidx,
                 const float* __restrict__ es, const float* __restrict__ ev,
                 const float* __restrict__ m1_wh, const float* __restrict__ m1_wv,
                 const float* __restrict__ m2_wh, const float* __restrict__ m2_wsb,
                 const float* __restrict__ m2_wv,
                 const float* __restrict__ m3_wh, const float* __restrict__ m3_wsb,
                 const float* __restrict__ m3_wv,
                 const unsigned short* __restrict__ p1h, const unsigned short* __restrict__ p1l,
                 const unsigned short* __restrict__ p2h, const unsigned short* __restrict__ p2l,
                 const unsigned short* __restrict__ p3h, const unsigned short* __restrict__ p3l,
                 const float* __restrict__ Pg, const float* __restrict__ Q1g,
                 const float* __restrict__ Q3g,
                 double* __restrict__ agg_s, double* __restrict__ agg_v,
                 float* __restrict__ cnt, int E)
{
    __shared__ __align__(16) unsigned short Ah[16 * SA2], Al[16 * SA2];
    __shared__ __align__(16) float SP[16 * SPS];
    __shared__ __align__(16) float B1[16 * SB1];
    __shared__ int ssrc[16], sgd[16], sdst[16], seid[16];

    unsigned short* PBh = Ah;      // overlay: PB == A (identical geometry)
    unsigned short* PBl = Al;
    float* B2 = SP;                // overlay: B2 in SP's first 3328 B

    const int tid = threadIdx.x, lane = tid & 63, wave = tid >> 6;
    const int e = tid & 15, q16 = tid >> 4;
    const int e0 = blockIdx.x * 16;

    const int eg_r = e0 + e;
    const int ee_r = (eg_r < E) ? eg_r : (E - 1);
    const int src_r = eidx[ee_r];
    const int dst_r = eidx[E + ee_r];

    if (q16 < 8) {
        const float4 x = ((const float4*)(es + (size_t)ee_r * 32))[q16];
        short4v hv, lv; unsigned short h, l;
        split_bf(x.x, h, l); hv[0] = h; lv[0] = l;
        split_bf(x.y, h, l); hv[1] = h; lv[1] = l;
        split_bf(x.z, h, l); hv[2] = h; lv[2] = l;
        split_bf(x.w, h, l); hv[3] = h; lv[3] = l;
        *(short4v*)(Ah + e * SA2 + 4 * q16) = hv;
        *(short4v*)(Al + e * SA2 + 4 * q16) = lv;
    }
    { const int c = 65 + q16; Ah[e * SA2 + c] = 0; Al[e * SA2 + c] = 0; }
    { const int c = 81 + q16; if (c < 96) { Ah[e * SA2 + c] = 0; Al[e * SA2 + c] = 0; } }
    {
        const float* P1 = Pg + (size_t)src_r * 256;
        const float* P3 = Pg + (size_t)dst_r * 256 + 128;
        const float4 a0 = ((const float4*)P1)[2 * q16];
        const float4 a1 = ((const float4*)P1)[2 * q16 + 1];
        const float4 b0 = ((const float4*)P3)[2 * q16];
        const float4 b1 = ((const float4*)P3)[2 * q16 + 1];
        float4 r0, r1;
        r0.x = a0.x + b0.x; r0.y = a0.y + b0.y; r0.z = a0.z + b0.z; r0.w = a0.w + b0.w;
        r1.x = a1.x + b1.x; r1.y = a1.y + b1.y; r1.z = a1.z + b1.z; r1.w = a1.w + b1.w;
        float4* o = (float4*)(SP + e * SPS + 8 * q16);
        o[0] = r0; o[1] = r1;
    }
    if (tid < 16) {
        const int eg = e0 + tid;
        const bool ok = (eg < E);
        const int ee = ok ? eg : (E - 1);
        seid[tid] = ee;
        ssrc[tid] = eidx[ee];
        const int d = eidx[E + ee];
        sgd[tid] = d;
        sdst[tid] = ok ? d : -1;
    }
    __syncthreads();

    #pragma unroll
    for (int k = 0; k < 3; ++k) {
        const int idx = tid + k * 256;
        if (idx < 528) {
            const int h = idx >> 4, e2 = idx & 15;
            const float* q1 = Q1g + (size_t)ssrc[e2] * 100 + h * 3;
            const float* q3 = Q3g + (size_t)sgd[e2] * 100 + h * 3;
            const float* evp = ev + (size_t)seid[e2] * 3;
            const float w16 = m1_wh[h * 33 + 16];
            const float v0 = q1[0] + q3[0] + w16 * evp[0];
            const float v1 = q1[1] + q3[1] + w16 * evp[1];
            const float v2 = q1[2] + q3[2] + w16 * evp[2];
            float* o = B1 + e2 * SB1 + h * 3;
            o[0] = v0; o[1] = v1; o[2] = v2;
            const float vn = sqrtf(fmaxf(v0 * v0 + v1 * v1 + v2 * v2, EPSF));
            unsigned short hh, ll; split_bf(vn, hh, ll);
            Ah[e2 * SA2 + 32 + h] = hh; Al[e2 * SA2 + 32 + h] = ll;
        }
    }
    __syncthreads();

    float4v acc1[2] = {{0,0,0,0},{0,0,0,0}};
    kloop<3, 2, SA2>(Ah, Al, p1h, p1l, acc1, lane, wave);
    __syncthreads();

    {
        const int q = lane >> 4;
        #pragma unroll
        for (int i = 0; i < 2; ++i) {
            const int n = (wave * 2 + i) * 16 + (lane & 15);
            #pragma unroll
            for (int r = 0; r < 4; ++r) {
                const int m = q * 4 + r;
                const float x = fmaxf(acc1[i][r] + SP[m * SPS + n], 0.f);
                unsigned short h, l; split_bf(x, h, l);
                PBh[m * SBs + n] = h; PBl[m * SBs + n] = l;
            }
        }
    }
    __syncthreads();

    {
        const int o = q16;
        const float* wrow = m1_wv + o * 33;
        const float* prow = B1 + e * SB1;
        float a0 = 0.f, a1 = 0.f, a2 = 0.f;
        matvec3_v<32>(wrow, prow, a0, a1, a2);
        const float w32 = wrow[32];
        a0 = fmaf(w32, prow[96], a0); a1 = fmaf(w32, prow[97], a1); a2 = fmaf(w32, prow[98], a2);
        const float nrm = sqrtf(fmaxf(a0 * a0 + a1 * a1 + a2 * a2, EPSF));
        const float sg = 1.f / (1.f + __expf(-nrm));
        float* p2 = B2 + e * SB2 + o * 3;
        p2[0] = a0 * sg; p2[1] = a1 * sg; p2[2] = a2 * sg;
    }
    __syncthreads();

    {
        const int h = q16;
        float a0 = 0.f, a1 = 0.f, a2 = 0.f;
        matvec3_v<16>(m2_wh + h * 16, B2 + e * SB2, a0, a1, a2);
        float* o = B1 + e * SB1 + h * 3;
        o[0] = a0; o[1] = a1; o[2] = a2;
        const float vn = sqrtf(fmaxf(a0 * a0 + a1 * a1 + a2 * a2, EPSF));
        unsigned short hh, ll; split_bf(vn, hh, ll);
        PBh[e * SBs + 128 + h] = hh; PBl[e * SBs + 128 + h] = ll;
        PBh[e * SBs + 144 + h] = 0;  PBl[e * SBs + 144 + h] = 0;
    }
    __syncthreads();

    float4v acc2[2] = {{0,0,0,0},{0,0,0,0}};
    kloop<5, 2, SBs>(PBh, PBl, p2h, p2l, acc2, lane, wave);
    __syncthreads();

    {
        const int q = lane >> 4;
        #pragma unroll
        for (int i = 0; i < 2; ++i) {
            const int n = (wave * 2 + i) * 16 + (lane & 15);
            const float bias = m2_wsb[n];
            #pragma unroll
            for (int r = 0; r < 4; ++r) {
                const int m = q * 4 + r;
                const float x = fmaxf(acc2[i][r] + bias, 0.f);
                unsigned short h, l; split_bf(x, h, l);
                Ah[m * SA2 + n] = h; Al[m * SA2 + n] = l;
            }
        }
    }
    {
        const int o = q16;
        float a0 = 0.f, a1 = 0.f, a2 = 0.f;
        matvec3_v<16>(m2_wv + o * 16, B1 + e * SB1, a0, a1, a2);
        const float nrm = sqrtf(fmaxf(a0 * a0 + a1 * a1 + a2 * a2, EPSF));
        const float sg = 1.f / (1.f + __expf(-nrm));
        float* p2 = B2 + e * SB2 + o * 3;
        p2[0] = a0 * sg; p2[1] = a1 * sg; p2[2] = a2 * sg;
    }
    __syncthreads();

    {
        const int h = q16;
        float a0 = 0.f, a1 = 0.f, a2 = 0.f;
        matvec3_v<16>(m3_wh + h * 16, B2 + e * SB2, a0, a1, a2);
        float* o = B1 + e * SB1 + h * 3;
        o[0] = a0; o[1] = a1; o[2] = a2;
        const float vn = sqrtf(fmaxf(a0 * a0 + a1 * a1 + a2 * a2, EPSF));
        unsigned short hh, ll; split_bf(vn, hh, ll);
        Ah[e * SA2 + 128 + h] = hh; Al[e * SA2 + 128 + h] = ll;
        Ah[e * SA2 + 144 + h] = 0;  Al[e * SA2 + 144 + h] = 0;
    }
    __syncthreads();

    float4v acc3[2] = {{0,0,0,0},{0,0,0,0}};
    kloop<5, 2, SA2>(Ah, Al, p3h, p3l, acc3, lane, wave);
    {
        const int o = q16;
        float a0 = 0.f, a1 = 0.f, a2 = 0.f;
        matvec3_v<16>(m3_wv + o * 16, B1 + e * SB1, a0, a1, a2);
        float* p2 = B2 + e * SB2 + o * 3;
        p2[0] = a0; p2[1] = a1; p2[2] = a2;
    }
    __syncthreads();

    {
        const int q = lane >> 4;
        #pragma unroll
        for (int i = 0; i < 2; ++i) {
            const int n = (wave * 2 + i) * 16 + (lane & 15);
            const float bias = m3_wsb[n];
            #pragma unroll
            for (int r = 0; r < 4; ++r) {
                const int m = q * 4 + r;
                const int d = sdst[m];
                if (d >= 0) atomicAdd(&agg_s[(size_t)d * 128 + n], (double)(acc3[i][r] + bias));
            }
        }
    }
    #pragma unroll
    for (int it = 0; it < 3; ++it) {
        const int j = q16 + 16 * it;
        const int d = sdst[e];
        if (d >= 0) atomicAdd(&agg_v[(size_t)d * 48 + j], (double)B2[e * SB2 + j]);
    }
    if (tid < 16 && sdst[tid] >= 0) atomicAdd(&cnt[sdst[tid]], 1.0f);
}

// ===========================================================================
// layer_normT: wave processes NE nodes (proven math, verbatim per node)
// ===========================================================================
template<int NE, int SSTR, int VSTR>
__device__ __forceinline__ void layer_normT(float* S, float* V,
    const float* __restrict__ g, const float* __restrict__ b, float* red, int lane)
{
    #pragma unroll
    for (int e = 0; e < NE; ++e) {
        float x0 = S[e * SSTR + lane], x1 = S[e * SSTR + 64 + lane];
        float sum = x0 + x1;
        #pragma unroll
        for (int off = 32; off > 0; off >>= 1) sum += __shfl_xor(sum, off, 64);
        const float mu = sum * (1.f / 128.f);
        const float d0 = x0 - mu, d1 = x1 - mu;
        float vs = d0 * d0 + d1 * d1;
        #pragma unroll
        for (int off = 32; off > 0; off >>= 1) vs += __shfl_xor(vs, off, 64);
        const float rstd = rsqrtf(vs * (1.f / 128.f) + 1e-5f);
        S[e * SSTR + lane]      = d0 * rstd * g[lane]      + b[lane];
        S[e * SSTR + 64 + lane] = d1 * rstd * g[lane + 64] + b[lane + 64];

        if (lane < 16) {
            const float a = V[e * VSTR + lane * 3], bb = V[e * VSTR + lane * 3 + 1],
                        cc = V[e * VSTR + lane * 3 + 2];
            const float vn = fmaxf(a * a + bb * bb + cc * cc, EPSF);
            red[lane]      = vn;
            red[16 + lane] = (vn > 2.f * EPSF) ? 1.f : 0.f;
        }
        __syncthreads();
        float sn = 0.f, sm = 0.f;
        #pragma unroll
        for (int i = 0; i < 16; ++i) { sn += red[i] * red[16 + i]; sm += red[16 + i]; }
        const float rvm = rsqrtf(sn / (EPSF + sm) + EPSF);
        if (lane < 48) V[e * VSTR + lane] = red[16 + lane / 3] * V[e * VSTR + lane] * rvm;
        __syncthreads();
    }
}

// ===========================================================================
// Node kernel: 8 nodes/block, 128 threads, 2 waves (R9-green structure).
// NEW this round: f2 (K=544 -> 128) moves from fp32 VALU GEMM to the proven
// 3-pass split-bf16 MFMA kloop.  FS (fp32 A) replaced by a SEPARATE UB2
// bf16-split A buffer (no overlay): P3 writes relu(fs1) split into
// UB2[0,512); P4 writes vn2 split into UB2[512,544); P5 runs kloop<17,4>
// with MCLAMP=7 (UB2 has 8 rows; lanes 8-15 read copies of rows 0-7 whose
// C rows are discarded).  Epilogue adds acc+bias into S1f rows m<8.
// LDS = 35.6 KB -> 4 blocks/CU (unchanged).
// ===========================================================================
constexpr int NNS  = 132;
constexpr int NNV  = 52;
constexpr int NNH  = 100;
constexpr int NA1n = 168;
constexpr int NA2n = 552;   // f2 A stride (shorts), K=544

__global__ __launch_bounds__(128)
void node_kernel(const float* __restrict__ s, const float* __restrict__ v,
                 const float* __restrict__ f1_wh, const float* __restrict__ f1_wsb,
                 const float* __restrict__ f1_wv,
                 const float* __restrict__ f2_wh, const float* __restrict__ f2_wsb,
                 const float* __restrict__ f2_wv,
                 const float* __restrict__ ln0_g, const float* __restrict__ ln0_b,
                 const float* __restrict__ ln1_g, const float* __restrict__ ln1_b,
                 const unsigned short* __restrict__ pf1h, const unsigned short* __restrict__ pf1l,
                 const unsigned short* __restrict__ pf2h, const unsigned short* __restrict__ pf2l,
                 const double* __restrict__ agg_s, const double* __restrict__ agg_v,
                 const float* __restrict__ cnt,
                 float* __restrict__ out, int N)
{
    __shared__ __align__(16) unsigned short UBh[8 * NA1n], UBl[8 * NA1n];
    __shared__ __align__(16) unsigned short UB2h[8 * NA2n], UB2l[8 * NA2n];
    __shared__ __align__(16) float S1f[8 * NNS];
    __shared__ __align__(16) float V1f[8 * NNV];
    __shared__ __align__(16) float VH[8 * NNH];
    __shared__ __align__(16) float FV[8 * NNH];
    __shared__ float red[2 * 32];

    const int tid = threadIdx.x, lane = tid & 63, wave = tid >> 6;
    const int e = tid & 7, qq = tid >> 3;
    const int n0 = blockIdx.x * 8;

    bool oks[4];
    #pragma unroll
    for (int e4 = 0; e4 < 4; ++e4) {
        const int idx = wave * 4 + e4;
        const int ng = n0 + idx;
        oks[e4] = (ng < N);
        const int n = oks[e4] ? ng : (N - 1);
        const double inv = 1.0 / (double)fmaxf(cnt[n], 1.f);
        if (lane < 32) {
            const float4 a = ((const float4*)(s + (size_t)n * 128))[lane];
            const double2 b0 = ((const double2*)(agg_s + (size_t)n * 128))[2 * lane];
            const double2 b1 = ((const double2*)(agg_s + (size_t)n * 128))[2 * lane + 1];
            float4 r;
            r.x = (float)((double)a.x + b0.x * inv);
            r.y = (float)((double)a.y + b0.y * inv);
            r.z = (float)((double)a.z + b1.x * inv);
            r.w = (float)((double)a.w + b1.y * inv);
            ((float4*)(S1f + idx * NNS))[lane] = r;
        }
        if (lane < 12) {
            const float4 a = ((const float4*)(v + (size_t)n * 48))[lane];
            const double2 b0 = ((const double2*)(agg_v + (size_t)n * 48))[2 * lane];
            const double2 b1 = ((const double2*)(agg_v + (size_t)n * 48))[2 * lane + 1];
            float4 r;
            r.x = (float)((double)a.x + b0.x * inv);
            r.y = (float)((double)a.y + b0.y * inv);
            r.z = (float)((double)a.z + b1.x * inv);
            r.w = (float)((double)a.w + b1.y * inv);
            ((float4*)(V1f + idx * NNV))[lane] = r;
        }
    }
    __syncthreads();

    layer_normT<4, NNS, NNV>(S1f + wave * 4 * NNS, V1f + wave * 4 * NNV,
                             ln0_g, ln0_b, red + wave * 32, lane);

    // P2: split s1 -> f1-A[0,128); vh1 -> VH; vn1 -> f1-A[128,160)
    {
        const float* sp = S1f + e * NNS + qq * 8;
        short8 hv, lv; unsigned short h, l;
        #pragma unroll
        for (int j = 0; j < 8; ++j) { split_bf(sp[j], h, l); hv[j] = h; lv[j] = l; }
        *(short8*)(UBh + e * NA1n + qq * 8) = hv;
        *(short8*)(UBl + e * NA1n + qq * 8) = lv;
    }
    #pragma unroll
    for (int hi = 0; hi < 2; ++hi) {
        const int h = qq + 16 * hi;
        float a0 = 0.f, a1 = 0.f, a2 = 0.f;
        matvec3_v<16>(f1_wh + h * 16, V1f + e * NNV, a0, a1, a2);
        float* o = VH + e * NNH + h * 3;
        o[0] = a0; o[1] = a1; o[2] = a2;
        const float vn = sqrtf(fmaxf(a0 * a0 + a1 * a1 + a2 * a2, EPSF));
        unsigned short hh, ll; split_bf(vn, hh, ll);
        UBh[e * NA1n + 128 + h] = hh; UBl[e * NA1n + 128 + h] = ll;
    }
    __syncthreads();

    // P3: f1 MFMA (K=160, NO=512) -> relu -> split into UB2[0,512) rows m<8;
    //     fv1 -> FV
    {
        float4v acc1[16];
        #pragma unroll
        for (int i = 0; i < 16; ++i) acc1[i] = (float4v){0.f, 0.f, 0.f, 0.f};
        kloop<5, 16, NA1n>(UBh, UBl, pf1h, pf1l, acc1, lane, wave);
        const int q = lane >> 4;
        #pragma unroll
        for (int i = 0; i < 16; ++i) {
            const int n = (wave * 16 + i) * 16 + (lane & 15);
            const float bias = f1_wsb[n];
            #pragma unroll
            for (int r = 0; r < 4; ++r) {
                const int m = q * 4 + r;
                if (m < 8) {
                    const float x = fmaxf(acc1[i][r] + bias, 0.f);
                    unsigned short h, l; split_bf(x, h, l);
                    UB2h[m * NA2n + n] = h; UB2l[m * NA2n + n] = l;
                }
            }
        }
    }
    #pragma unroll
    for (int oi = 0; oi < 2; ++oi) {
        const int o = qq + 16 * oi;
        float a0 = 0.f, a1 = 0.f, a2 = 0.f;
        matvec3_v<32>(f1_wv + o * 32, VH + e * NNH, a0, a1, a2);
        const float nrm = sqrtf(fmaxf(a0 * a0 + a1 * a1 + a2 * a2, EPSF));
        const float sg = 1.f / (1.f + __expf(-nrm));
        float* p2 = FV + e * NNH + o * 3;
        p2[0] = a0 * sg; p2[1] = a1 * sg; p2[2] = a2 * sg;
    }
    __syncthreads();

    // P4: vh2 -> VH (overwrite); vn2 -> split into UB2[512,544)
    #pragma unroll
    for (int hi = 0; hi < 2; ++hi) {
        const int h = qq + 16 * hi;
        float a0 = 0.f, a1 = 0.f, a2 = 0.f;
        matvec3_v<32>(f2_wh + h * 32, FV + e * NNH, a0, a1, a2);
        float* o = VH + e * NNH + h * 3;
        o[0] = a0; o[1] = a1; o[2] = a2;
        const float vn = sqrtf(fmaxf(a0 * a0 + a1 * a1 + a2 * a2, EPSF));
        unsigned short hh, ll; split_bf(vn, hh, ll);
        UB2h[e * NA2n + 512 + h] = hh; UB2l[e * NA2n + 512 + h] = ll;
    }
    __syncthreads();

    // P5: f2 MFMA (K=544, NO=128, 2 waves x 4 tiles, A rows clamped to 8)
    //     -> S1f residual; fv2 -> V1f residual
    {
        float4v acc2[4] = {{0,0,0,0},{0,0,0,0},{0,0,0,0},{0,0,0,0}};
        kloop<17, 4, NA2n, 7>(UB2h, UB2l, pf2h, pf2l, acc2, lane, wave);
        const int q = lane >> 4;
        #pragma unroll
        for (int i = 0; i < 4; ++i) {
            const int n = (wave * 4 + i) * 16 + (lane & 15);
            const float bias = f2_wsb[n];
            #pragma unroll
            for (int r = 0; r < 4; ++r) {
                const int m = q * 4 + r;
                if (m < 8) S1f[m * NNS + n] += acc2[i][r] + bias;
            }
        }
    }
    {
        const int o = qq;
        float a0 = 0.f, a1 = 0.f, a2 = 0.f;
        matvec3_v<32>(f2_wv + o * 32, VH + e * NNH, a0, a1, a2);
        float* p2 = V1f + e * NNV + o * 3;
        p2[0] += a0; p2[1] += a1; p2[2] += a2;
    }
    __syncthreads();

    layer_normT<4, NNS, NNV>(S1f + wave * 4 * NNS, V1f + wave * 4 * NNV,
                             ln1_g, ln1_b, red + wave * 32, lane);

    #pragma unroll
    for (int e4 = 0; e4 < 4; ++e4) {
        if (!oks[e4]) continue;
        const int idx = wave * 4 + e4;
        const int n = n0 + idx;
        if (lane < 32)
            ((float4*)(out + (size_t)n * 128))[lane] = ((const float4*)(S1f + idx * NNS))[lane];
        if (lane < 12)
            ((float4*)(out + (size_t)N * 128 + (size_t)n * 48))[lane] =
                ((const float4*)(V1f + idx * NNV))[lane];
    }
}

// ---------------------------------------------------------------------------
extern "C" void kernel_launch(void* const* d_in, const int* in_sizes, int n_in,
                              void* d_out, int out_size, void* d_ws, size_t ws_size,
                              hipStream_t stream)
{
    const float* s    = (const float*)d_in[0];
    const float* v    = (const float*)d_in[1];
    const int*   eidx = (const int*)d_in[2];
    const float* es   = (const float*)d_in[3];
    const float* ev   = (const float*)d_in[4];
    const float* m1_wh = (const float*)d_in[5];
    const float* m1_wsw = (const float*)d_in[6];
    const float* m1_wsb = (const float*)d_in[7];
    const float* m1_wv = (const float*)d_in[8];
    const float* m2_wh = (const float*)d_in[9];
    const float* m2_wsw = (const float*)d_in[10];
    const float* m2_wsb = (const float*)d_in[11];
    const float* m2_wv = (const float*)d_in[12];
    const float* m3_wh = (const float*)d_in[13];
    const float* m3_wsw = (const float*)d_in[14];
    const float* m3_wsb = (const float*)d_in[15];
    const float* m3_wv = (const float*)d_in[16];
    const float* f1_wh = (const float*)d_in[17];
    const float* f1_wsw = (const float*)d_in[18];
    const float* f1_wsb = (const float*)d_in[19];
    const float* f1_wv = (const float*)d_in[20];
    const float* f2_wh = (const float*)d_in[21];
    const float* f2_wsw = (const float*)d_in[22];
    const float* f2_wsb = (const float*)d_in[23];
    const float* f2_wv = (const float*)d_in[24];
    const float* ln0_g = (const float*)d_in[25];
    const float* ln0_b = (const float*)d_in[26];
    const float* ln1_g = (const float*)d_in[27];
    const float* ln1_b = (const float*)d_in[28];

    const int N = in_sizes[0] / 128;
    const int E = in_sizes[2] / 2;

    double* agg_s = (double*)d_ws;                     // N*128 f64
    double* agg_v = agg_s + (size_t)N * 128;           // N*48  f64
    float* cnt    = (float*)(agg_v + (size_t)N * 48);  // N     f32
    unsigned short* pk =
        (unsigned short*)(((uintptr_t)(cnt + N) + 15) & ~(uintptr_t)15);
    const int S_P1E = 12288, S_M23 = 20480, S_MN = 32768, S_F1 = 81920, S_F2 = 69632;
    unsigned short* p1h = pk;            unsigned short* p1l = p1h + S_P1E;
    unsigned short* p2h = p1l + S_P1E;   unsigned short* p2l = p2h + S_M23;
    unsigned short* p3h = p2l + S_M23;   unsigned short* p3l = p3h + S_M23;
    unsigned short* pnh = p3l + S_M23;   unsigned short* pnl = pnh + S_MN;
    unsigned short* pf1h = pnl + S_MN;   unsigned short* pf1l = pf1h + S_F1;
    unsigned short* pf2h = pf1l + S_F1;  unsigned short* pf2l = pf2h + S_F2;
    float* Pg  = (float*)(((uintptr_t)(pf2l + S_F2) + 15) & ~(uintptr_t)15);
    float* Q1g = Pg + (size_t)N * 256;
    float* Q3g = Q1g + (size_t)N * 100;

    hipMemsetAsync(d_ws, 0,
                   (size_t)N * 176 * sizeof(double) + (size_t)N * sizeof(float),
                   stream);

    pack_m1e<<<dim3((12288 + 255) / 256), dim3(256), 0, stream>>>(m1_wsw, p1h, p1l);
    pack_w<<<dim3((S_M23 + 255) / 256), dim3(256), 0, stream>>>(m2_wsw, p2h, p2l, 128, 144, 5);
    pack_w<<<dim3((S_M23 + 255) / 256), dim3(256), 0, stream>>>(m3_wsw, p3h, p3l, 128, 144, 5);
    pack_m1n<<<dim3((32768 + 255) / 256), dim3(256), 0, stream>>>(m1_wsw, pnh, pnl);
    pack_w<<<dim3((S_F1 + 255) / 256), dim3(256), 0, stream>>>(f1_wsw, pf1h, pf1l, 512, 160, 5);
    pack_w<<<dim3((S_F2 + 255) / 256), dim3(256), 0, stream>>>(f2_wsw, pf2h, pf2l, 128, 544, 17);

    node_pre<<<dim3((N + 15) / 16), dim3(256), 0, stream>>>(
        s, v, m1_wh, m1_wsb, pnh, pnl, Pg, Q1g, Q3g, N);

    edge_kernel<<<dim3((E + 15) / 16), dim3(256), 0, stream>>>(
        eidx, es, ev,
        m1_wh, m1_wv,
        m2_wh, m2_wsb, m2_wv,
        m3_wh, m3_wsb, m3_wv,
        p1h, p1l, p2h, p2l, p3h, p3l,
        Pg, Q1g, Q3g,
        agg_s, agg_v, cnt, E);

    node_kernel<<<dim3((N + 7) / 8), dim3(128), 0, stream>>>(
        s, v,
        f1_wh, f1_wsb, f1_wv,
        f2_wh, f2_wsb, f2_wv,
        ln0_g, ln0_b, ln1_g, ln1_b,
        pf1h, pf1l, pf2h, pf2l,
        agg_s, agg_v, cnt,
        (float*)d_out, N);
}